// Round 23
// baseline (869.092 us; speedup 1.0000x reference)
//
#include <hip/hip_runtime.h>
#include <hip/hip_cooperative_groups.h>
#include <math.h>

namespace cg = cooperative_groups;

#define CCH 256
#define HWP 65536
#define PCI 40   // padded ci stride (shorts) in LDS

typedef short short8 __attribute__((ext_vector_type(8)));
typedef float f32x4 __attribute__((ext_vector_type(4)));
typedef unsigned short us4 __attribute__((ext_vector_type(4)));

__device__ inline unsigned short f2bf(float f) {
  unsigned u = __float_as_uint(f);
  return (unsigned short)((u + 0x7FFFu + ((u >> 16) & 1u)) >> 16);
}
__device__ inline float bf2f(unsigned short s) {
  return __uint_as_float(((unsigned)s) << 16);
}

__device__ inline void mfma_bf16(f32x4& d, short8 a, short8 b) {
  asm volatile("v_mfma_f32_16x16x32_bf16 %0, %1, %2, %0" : "+v"(d) : "v"(a), "v"(b));
}

// ---- ws layout (bytes) ----
static const size_t BUF_B_OFF = 67108864;        // actA @0, actB @64MB
static const size_t TAIL_OFF  = 134217728;
static const size_t KEYS_OFF  = TAIL_OFF;        // unused (keys now in registers)
static const size_t HIST_OFF  = TAIL_OFF + 262144;
static const size_t STATE_OFF = TAIL_OFF + 263168;
static const size_t IDX_OFF   = TAIL_OFF + 263424;
static const size_t EQ_OFF    = TAIL_OFF + 271616;
static const size_t OB_OFF    = 6291456;
static const size_t WBI_OFF   = 8388608;
static const size_t WBO_OFF   = 9437184;
static const size_t SROWS_OFF = 10485760;
static const size_t DQ_OFF    = 12582912;
static const size_t GPART_OFF = 16777216;
static const size_t WT5_OFF   = 20971520;
static const size_t QB_OFF    = 31457280;
static const size_t KB_OFF    = 32505856;
static const size_t VT_OFF    = 33554432;
static const size_t CPK_OFF   = 37748736;
static const size_t DPK_OFF   = 44040192;        // 5 layers x 1048576 shorts -> ends 54525952
static const size_t WTW_OFF   = 54525952;        // bf16 wt_w [256][768] 384KB
static const size_t WPART_OFF = 55050240;        // f32 partials [8][64][256] 512KB
static const size_t XQ0_OFF   = 57671680;        // bf16 stage0 x [64][256]

struct SelState { unsigned int P; int kneed; int nGreater; int nEqual; };

// merged weight packing: conv3 x4, deconv x5, conv5, in_w, out_w, wt_w
__global__ void k_packall(const float* __restrict__ up_cw, const float* __restrict__ up_dw,
                          const float* __restrict__ in_w, const float* __restrict__ out_w,
                          const float* __restrict__ wt_w,
                          short* __restrict__ cpk, short* __restrict__ dpk,
                          short* __restrict__ wB5, short* __restrict__ wBi,
                          short* __restrict__ wBo, short* __restrict__ wBt) {
  int b = blockIdx.x;
  int tid = threadIdx.x;
  if (b < 1024) {
    int layer = b >> 8, co = b & 255, ci = tid;
    const float* wl = up_cw + (size_t)layer * 589824;
    short* wo = cpk + (size_t)layer * 589824;
    for (int tap = 0; tap < 9; ++tap)
      wo[((size_t)(tap * 256 + co) * 256) + ci] = (short)f2bf(wl[((size_t)(co * 256 + ci)) * 9 + tap]);
  } else if (b < 2304) {
    int bb = b - 1024;
    int layer = bb >> 8, co = bb & 255, ci = tid;
    const float* wl = up_dw + (size_t)layer * 1048576;
    for (int pq = 0; pq < 4; ++pq) {
      int p = pq >> 1, q = pq & 1;
      for (int tt = 0; tt < 4; ++tt) {
        int dyi = tt >> 1, dxi = tt & 1;
        int wr = dyi ? (1 - p) : (3 - p);
        int wc = dxi ? (1 - q) : (3 - q);
        dpk[((size_t)layer * 1048576) + ((size_t)((pq * 4 + tt) * 256 + co) * 256) + ci] =
            (short)f2bf(wl[((size_t)(ci * 256 + co)) * 16 + wr * 4 + wc]);
      }
    }
  } else if (b < 2560) {
    int co = b - 2304;
    const float* w5 = up_cw + 2359296;
    for (int kk = tid; kk < 2304; kk += 256) {
      int c = kk / 288, r = kk % 288;
      int e = r >> 5, cl = r & 31;
      wB5[(size_t)co * 2304 + kk] = (short)f2bf(w5[(size_t)co * 2304 + (size_t)(c * 32 + cl) * 9 + e]);
    }
  } else if (b < 3328) {
    int o = b - 2560;
    wBi[(size_t)o * 256 + tid] = (short)f2bf(in_w[(size_t)o * 256 + tid]);
  } else if (b < 3584) {
    int o = b - 3328;
    wBo[(size_t)o * 256 + tid] = (short)f2bf(out_w[(size_t)o * 256 + tid]);
  } else {
    int co = b - 3584;
    for (int kk = tid; kk < 768; kk += 256)
      wBt[(size_t)co * 768 + kk] = (short)f2bf(wt_w[(size_t)co * 768 + kk]);
  }
}

// gate partials + passthrough copy: block = (p-tile 256, c-chunk of 32)
__global__ void k_gatecopy2(const float* __restrict__ down, const float* __restrict__ gw,
                            float* __restrict__ out, float* __restrict__ gpart) {
  int p = blockIdx.x * 256 + threadIdx.x;
  int cc = blockIdx.y;
  float acc = 0.f;
  for (int c = cc * 32; c < cc * 32 + 32; ++c) {
    float v = down[(size_t)c * HWP + p];
    out[(size_t)c * HWP + p] = v;
    acc += v * gw[c];
  }
  gpart[(size_t)cc * HWP + p] = acc;
}

// cooperative exact top-k: keys + 4-round radix select + compact + finalize + gather.
// Replaces 13 small launches (init/gkey/4x(hist,scan)/compact/finalize/gatherq).
// grid 256 x 256; keys held in registers; deterministic (same reduce order as before).
__global__ __launch_bounds__(256) void k_topk(const float* __restrict__ gpart,
                                              const float* __restrict__ down,
                                              unsigned* __restrict__ hist,
                                              SelState* st,
                                              int* __restrict__ idx,
                                              int* __restrict__ eq,
                                              short* __restrict__ dq) {
  cg::grid_group grid = cg::this_grid();
  int t = threadIdx.x;
  int p = blockIdx.x * 256 + t;
  // phase 0: deterministic key from gate partials; block 0 inits hist/state
  float s = 0.f;
  for (int cc = 0; cc < 8; ++cc) s += gpart[(size_t)cc * HWP + p];
  unsigned u = __float_as_uint(s);
  unsigned key = (u & 0x80000000u) ? ~u : (u | 0x80000000u);
  if (blockIdx.x == 0) {
    hist[t] = 0;
    if (t == 0) { st->P = 0u; st->kneed = 2048; st->nGreater = 0; st->nEqual = 0; }
  }
  grid.sync();
  __shared__ unsigned lh[256];
  for (int r = 0; r < 4; ++r) {
    lh[t] = 0;
    __syncthreads();
    unsigned P = st->P;
    bool ok = (r == 0) || ((key >> (32 - 8 * r)) == P);
    if (ok) atomicAdd(&lh[(key >> (24 - 8 * r)) & 255u], 1u);
    __syncthreads();
    if (lh[t]) atomicAdd(&hist[t], lh[t]);
    grid.sync();
    if (blockIdx.x == 0) {
      if (t == 0) {
        int need = st->kneed;
        unsigned cum = 0;
        for (int b = 255; b >= 0; --b) {
          unsigned h = hist[b];
          if (cum + h >= (unsigned)need) {
            st->P = (st->P << 8) | (unsigned)b;
            st->kneed = need - (int)cum;
            break;
          }
          cum += h;
        }
      }
      __syncthreads();
      hist[t] = 0;
    }
    grid.sync();
  }
  // compact
  {
    unsigned P = st->P;
    if (key > P) {
      int pos = atomicAdd(&st->nGreater, 1);
      idx[pos] = p;
    } else if (key == P) {
      int e = atomicAdd(&st->nEqual, 1);
      if (e < 4096) eq[e] = p;
    }
  }
  grid.sync();
  if (blockIdx.x == 0 && t == 0) {
    int n = st->nEqual;
    if (n > 4096) n = 4096;
    for (int i = 1; i < n; ++i) {
      int v = eq[i], j = i - 1;
      while (j >= 0 && eq[j] > v) { eq[j + 1] = eq[j]; --j; }
      eq[j + 1] = v;
    }
    int g = st->nGreater;
    for (int i = 0; i < st->kneed; ++i) idx[g + i] = eq[i];
  }
  grid.sync();
  // gather selected down rows -> bf16 dq[2048][256]; 8 rows per block
#pragma unroll
  for (int jj = 0; jj < 8; ++jj) {
    int j = blockIdx.x * 8 + jj;
    int pj = idx[j];
    dq[(size_t)j * 256 + t] = (short)f2bf(down[(size_t)t * HWP + pj]);
  }
}

// K-split MFMA 1x1 conv 768->256: grid (4 co-tiles, 8 ksplits). f32 partials out.
__global__ __launch_bounds__(256) void k_wtconvP(const float* __restrict__ swint,
                                                 const short* __restrict__ wBt,
                                                 float* __restrict__ wpart) {
  __shared__ short x_s[64 * 40];
  int t = threadIdx.x, l = t & 63, wv = t >> 6;
  int co0 = blockIdx.x * 64;
  int ks = blockIdx.y;
  int kbase = ks * 96;
  f32x4 acc[4];
#pragma unroll
  for (int m = 0; m < 4; ++m) { f32x4 z = {0.f, 0.f, 0.f, 0.f}; acc[m] = z; }
#pragma unroll
  for (int cc = 0; cc < 3; ++cc) {
    int c0 = kbase + cc * 32;
    __syncthreads();
    {
      int ci = t >> 3, pos0 = (t & 7) * 8;
      const float* sp = swint + (size_t)(c0 + ci) * 64 + pos0;
#pragma unroll
      for (int pp = 0; pp < 8; ++pp)
        x_s[(pos0 + pp) * 40 + ci] = (short)f2bf(sp[pp]);
    }
    __syncthreads();
    short8 bfrag = *(const short8*)&x_s[(wv * 16 + (l & 15)) * 40 + (l >> 4) * 8];
#pragma unroll
    for (int m = 0; m < 4; ++m) {
      short8 af = *(const short8*)&wBt[(size_t)(co0 + m * 16 + (l & 15)) * 768 + c0 + (l >> 4) * 8];
      mfma_bf16(acc[m], af, bfrag);
    }
  }
  asm volatile("s_nop 7\n\ts_nop 7" ::);
  int pos = wv * 16 + (l & 15);
#pragma unroll
  for (int m = 0; m < 4; ++m)
#pragma unroll
    for (int r = 0; r < 4; ++r) {
      int co = co0 + m * 16 + (l >> 4) * 4 + r;
      wpart[((size_t)ks * 64 + pos) * 256 + co] = acc[m][r];
    }
}

// deterministic reduce of 8 K-split partials + bias -> bf16 xq0[pos][co]
__global__ void k_wtred(const float* __restrict__ wpart, const float* __restrict__ bias,
                        short* __restrict__ xq0) {
  int pos = blockIdx.x, co = threadIdx.x;
  float s = bias[co];
  for (int ks = 0; ks < 8; ++ks) s += wpart[((size_t)ks * 64 + pos) * 256 + co];
  xq0[(size_t)pos * 256 + co] = (short)f2bf(s);
}

// MFMA deconv 8->16 (stage 0) + bias + relu. grid (4 co-tiles, 4 pq). Packed out.
__global__ __launch_bounds__(256) void k_deconv8M(const short* __restrict__ xq0,
                                                  const short* __restrict__ wpk,
                                                  const float* __restrict__ bias,
                                                  unsigned* __restrict__ yp) {
  __shared__ short x_s[121 * 260];
  int t = threadIdx.x, l = t & 63, wv = t >> 6;
  int co0 = blockIdx.x * 64;
  int pq = blockIdx.y, p = pq >> 1, q = pq & 1;
  const unsigned* xs32 = (const unsigned*)xq0;
  for (int i = t; i < 121 * 128; i += 256) {
    int row = i >> 7, c2 = i & 127;
    int iy = row / 11 - 1, ix = row % 11 - 1;
    unsigned v = 0;
    if (iy >= 0 && iy < 8 && ix >= 0 && ix < 8)
      v = xs32[(size_t)(iy * 8 + ix) * 128 + c2];
    *(unsigned*)&x_s[row * 260 + 2 * c2] = v;
  }
  __syncthreads();
  f32x4 acc[4];
#pragma unroll
  for (int m = 0; m < 4; ++m) { f32x4 z = {0.f, 0.f, 0.f, 0.f}; acc[m] = z; }
  int pos = wv * 16 + (l & 15);
  int ay = pos >> 3, bx = pos & 7;
#pragma unroll
  for (int tt = 0; tt < 4; ++tt) {
    int dyi = tt >> 1, dxi = tt & 1;
    int rowx = (ay + p + dyi) * 11 + (bx + q + dxi);
#pragma unroll
    for (int c0 = 0; c0 < 256; c0 += 32) {
      short8 bfrag = *(const short8*)&x_s[rowx * 260 + c0 + (l >> 4) * 8];
#pragma unroll
      for (int m = 0; m < 4; ++m) {
        short8 af = *(const short8*)&wpk[((size_t)((pq * 4 + tt) * 256 + co0 + m * 16 + (l & 15)) * 256) + c0 + (l >> 4) * 8];
        mfma_bf16(acc[m], af, bfrag);
      }
    }
  }
  asm volatile("s_nop 7\n\ts_nop 7" ::);
  int oy = 2 * ay + p, ox = 2 * bx + q;
#pragma unroll
  for (int m = 0; m < 4; ++m)
#pragma unroll
    for (int r4p = 0; r4p < 2; ++r4p) {
      int cob = co0 + m * 16 + (l >> 4) * 4 + 2 * r4p;
      unsigned pk = (unsigned)f2bf(fmaxf(acc[m][2 * r4p] + bias[cob], 0.f))
                  | ((unsigned)f2bf(fmaxf(acc[m][2 * r4p + 1] + bias[cob + 1], 0.f)) << 16);
      yp[(size_t)(cob >> 1) * 256 + oy * 16 + ox] = pk;
    }
}

// MFMA conv3x3 pad1 + bias, O output rows per block. Weights direct-from-global.
template <int S, int O>
__global__ __launch_bounds__(256) void k_conv3u(const unsigned* __restrict__ xp,
                                                const short* __restrict__ wpk,
                                                const float* __restrict__ bias,
                                                unsigned* __restrict__ yp) {
  constexpr int WPC = (S >= 64) ? 2 : 1;
  constexpr int WCO = 4 / WPC;
  constexpr int COS = 64 / WCO;
  constexpr int MR = COS / 16;
  constexpr int PSP = S / WPC;
  constexpr int NR = PSP / 16;
  constexpr int CBK = (S + 2 + 31) / 32;
  constexpr int RS = O + 2;
  __shared__ short x_s[RS * (S + 2) * PCI];
  unsigned* x_s32 = (unsigned*)x_s;
  int t = threadIdx.x, l = t & 63, wv = t >> 6;
  int wcob = (wv % WCO) * COS;
  int wposb = (wv / WCO) * PSP;
  int row0 = blockIdx.x * O;
  int co0 = blockIdx.y * 64;
  int colb = t & 31, ci2b = t >> 5;
  f32x4 acc[O][MR][NR];
#pragma unroll
  for (int o = 0; o < O; ++o)
#pragma unroll
    for (int m = 0; m < MR; ++m)
#pragma unroll
      for (int n = 0; n < NR; ++n) { f32x4 z = {0.f, 0.f, 0.f, 0.f}; acc[o][m][n] = z; }
  for (int c0 = 0; c0 < CCH; c0 += 32) {
    int cb = c0 >> 1;
    __syncthreads();
#pragma unroll
    for (int r = 0; r < RS; ++r) {
      int gy = row0 - 1 + r;
      bool yok = (gy >= 0 && gy < S);
#pragma unroll
      for (int cbk = 0; cbk < CBK; ++cbk) {
        int col = colb + cbk * 32;
        if (col < S + 2) {
          int gx = col - 1;
          bool ok = yok && (gx >= 0) && (gx < S);
          unsigned v0 = 0, v1 = 0;
          if (ok) {
            size_t gbase = (size_t)(cb + ci2b) * S * S + (size_t)gy * S + gx;
            v0 = xp[gbase];
            v1 = xp[gbase + (size_t)8 * S * S];
          }
          int lb = (r * (S + 2) + col) * (PCI / 2);
          x_s32[lb + ci2b] = v0;
          x_s32[lb + ci2b + 8] = v1;
        }
      }
    }
    __syncthreads();
#pragma unroll
    for (int dyg = 0; dyg < 3; ++dyg)
#pragma unroll
      for (int dx = 0; dx < 3; ++dx) {
        short8 a[MR];
#pragma unroll
        for (int m = 0; m < MR; ++m)
          a[m] = *(const short8*)&wpk[((size_t)((dyg * 3 + dx) * 256 + co0 + wcob + m * 16 + (l & 15)) * 256) + c0 + (l >> 4) * 8];
#pragma unroll
        for (int o = 0; o < O; ++o) {
          short8 b[NR];
#pragma unroll
          for (int n = 0; n < NR; ++n)
            b[n] = *(const short8*)&x_s[((dyg + o) * (S + 2) + wposb + n * 16 + (l & 15) + dx) * PCI + (l >> 4) * 8];
#pragma unroll
          for (int m = 0; m < MR; ++m)
#pragma unroll
            for (int n = 0; n < NR; ++n) mfma_bf16(acc[o][m][n], a[m], b[n]);
        }
      }
  }
  asm volatile("s_nop 7\n\ts_nop 7" ::);
#pragma unroll
  for (int o = 0; o < O; ++o)
#pragma unroll
    for (int m = 0; m < MR; ++m)
#pragma unroll
      for (int n = 0; n < NR; ++n) {
        int cob = co0 + wcob + m * 16 + (l >> 4) * 4;
        int px = wposb + n * 16 + (l & 15);
#pragma unroll
        for (int r4p = 0; r4p < 2; ++r4p) {
          unsigned pk = (unsigned)f2bf(acc[o][m][n][2 * r4p] + bias[cob + 2 * r4p])
                      | ((unsigned)f2bf(acc[o][m][n][2 * r4p + 1] + bias[cob + 2 * r4p + 1]) << 16);
          yp[(size_t)((cob >> 1) + r4p) * S * S + (size_t)(row0 + o) * S + px] = pk;
        }
      }
}

// 512-thread conv3 for S=128 with LDS-staged weights: 8 waves, 2 blocks/CU.
__global__ __launch_bounds__(512) void k_conv3v(const unsigned* __restrict__ xp,
                                                const short* __restrict__ wpk,
                                                const float* __restrict__ bias,
                                                unsigned* __restrict__ yp) {
  constexpr int S = 128;
  constexpr int MR = 2;
  constexpr int PSP = 32;
  constexpr int NR = 2;
  __shared__ short x_s[3 * (S + 2) * PCI];
  __shared__ short w_s[9 * 64 * PCI];
  unsigned* x_s32 = (unsigned*)x_s;
  int t = threadIdx.x, l = t & 63, wv = t >> 6;
  int wcob = (wv & 1) * 32;
  int wposb = (wv >> 1) * PSP;
  int row0 = blockIdx.x;
  int co0 = blockIdx.y * 64;
  int colb = t & 31, ci2b = t >> 5;
  f32x4 acc[MR][NR];
#pragma unroll
  for (int m = 0; m < MR; ++m)
#pragma unroll
    for (int n = 0; n < NR; ++n) { f32x4 z = {0.f, 0.f, 0.f, 0.f}; acc[m][n] = z; }
  for (int c0 = 0; c0 < CCH; c0 += 32) {
    int cb = c0 >> 1;
    __syncthreads();
#pragma unroll
    for (int r = 0; r < 3; ++r) {
      int gy = row0 - 1 + r;
      bool yok = (gy >= 0 && gy < S);
#pragma unroll
      for (int cbk = 0; cbk < 5; ++cbk) {
        int col = colb + cbk * 32;
        if (col < S + 2) {
          int gx = col - 1;
          bool ok = yok && (gx >= 0) && (gx < S);
          unsigned v = 0;
          if (ok)
            v = xp[(size_t)(cb + ci2b) * S * S + (size_t)gy * S + gx];
          x_s32[(r * (S + 2) + col) * (PCI / 2) + ci2b] = v;
        }
      }
    }
    for (int i = t; i < 4608; i += 512) {
      int seg8 = i & 7;
      int rowi = i >> 3;
      int tap = rowi >> 6, co = rowi & 63;
      us4 wv4 = *(const us4*)&wpk[((size_t)(tap * 256 + co0 + co) * 256) + c0 + seg8 * 4];
      *(us4*)&w_s[rowi * PCI + seg8 * 4] = wv4;
    }
    __syncthreads();
#pragma unroll
    for (int dyg = 0; dyg < 3; ++dyg)
#pragma unroll
      for (int dx = 0; dx < 3; ++dx) {
        short8 a[MR];
#pragma unroll
        for (int m = 0; m < MR; ++m)
          a[m] = *(const short8*)&w_s[((dyg * 3 + dx) * 64 + wcob + m * 16 + (l & 15)) * PCI + (l >> 4) * 8];
        short8 b[NR];
#pragma unroll
        for (int n = 0; n < NR; ++n)
          b[n] = *(const short8*)&x_s[(dyg * (S + 2) + wposb + n * 16 + (l & 15) + dx) * PCI + (l >> 4) * 8];
#pragma unroll
        for (int m = 0; m < MR; ++m)
#pragma unroll
          for (int n = 0; n < NR; ++n) mfma_bf16(acc[m][n], a[m], b[n]);
      }
  }
  asm volatile("s_nop 7\n\ts_nop 7" ::);
#pragma unroll
  for (int m = 0; m < MR; ++m)
#pragma unroll
    for (int n = 0; n < NR; ++n) {
      int cob = co0 + wcob + m * 16 + (l >> 4) * 4;
      int px = wposb + n * 16 + (l & 15);
#pragma unroll
      for (int r4p = 0; r4p < 2; ++r4p) {
        unsigned pk = (unsigned)f2bf(acc[m][n][2 * r4p] + bias[cob + 2 * r4p])
                    | ((unsigned)f2bf(acc[m][n][2 * r4p + 1] + bias[cob + 2 * r4p + 1]) << 16);
        yp[(size_t)((cob >> 1) + r4p) * S * S + (size_t)row0 * S + px] = pk;
      }
    }
}

// 512-thread conv3 for S=64 with LDS-staged weights: 8 waves (MR=2, NR=1),
// grid (64, 4). x_s 15.8KB + w_s 46KB = 62KB.
__global__ __launch_bounds__(512) void k_conv3v64(const unsigned* __restrict__ xp,
                                                  const short* __restrict__ wpk,
                                                  const float* __restrict__ bias,
                                                  unsigned* __restrict__ yp) {
  constexpr int S = 64;
  constexpr int MR = 2;
  __shared__ short x_s[3 * (S + 2) * PCI];
  __shared__ short w_s[9 * 64 * PCI];
  unsigned* x_s32 = (unsigned*)x_s;
  int t = threadIdx.x, l = t & 63, wv = t >> 6;
  int wcob = (wv & 1) * 32;
  int wposb = (wv >> 1) * 16;
  int row0 = blockIdx.x;
  int co0 = blockIdx.y * 64;
  int colb = t & 31, ci2b = t >> 5;
  f32x4 acc[MR];
#pragma unroll
  for (int m = 0; m < MR; ++m) { f32x4 z = {0.f, 0.f, 0.f, 0.f}; acc[m] = z; }
  for (int c0 = 0; c0 < CCH; c0 += 32) {
    int cb = c0 >> 1;
    __syncthreads();
#pragma unroll
    for (int r = 0; r < 3; ++r) {
      int gy = row0 - 1 + r;
      bool yok = (gy >= 0 && gy < S);
#pragma unroll
      for (int cbk = 0; cbk < 3; ++cbk) {
        int col = colb + cbk * 32;
        if (col < S + 2) {
          int gx = col - 1;
          bool ok = yok && (gx >= 0) && (gx < S);
          unsigned v = 0;
          if (ok)
            v = xp[(size_t)(cb + ci2b) * S * S + (size_t)gy * S + gx];
          x_s32[(r * (S + 2) + col) * (PCI / 2) + ci2b] = v;
        }
      }
    }
    for (int i = t; i < 4608; i += 512) {
      int seg8 = i & 7;
      int rowi = i >> 3;
      int tap = rowi >> 6, co = rowi & 63;
      us4 wv4 = *(const us4*)&wpk[((size_t)(tap * 256 + co0 + co) * 256) + c0 + seg8 * 4];
      *(us4*)&w_s[rowi * PCI + seg8 * 4] = wv4;
    }
    __syncthreads();
#pragma unroll
    for (int dyg = 0; dyg < 3; ++dyg)
#pragma unroll
      for (int dx = 0; dx < 3; ++dx) {
        short8 a[MR];
#pragma unroll
        for (int m = 0; m < MR; ++m)
          a[m] = *(const short8*)&w_s[((dyg * 3 + dx) * 64 + wcob + m * 16 + (l & 15)) * PCI + (l >> 4) * 8];
        short8 b = *(const short8*)&x_s[(dyg * (S + 2) + wposb + (l & 15) + dx) * PCI + (l >> 4) * 8];
#pragma unroll
        for (int m = 0; m < MR; ++m) mfma_bf16(acc[m], a[m], b);
      }
  }
  asm volatile("s_nop 7\n\ts_nop 7" ::);
#pragma unroll
  for (int m = 0; m < MR; ++m) {
    int cob = co0 + wcob + m * 16 + (l >> 4) * 4;
    int px = wposb + (l & 15);
#pragma unroll
    for (int r4p = 0; r4p < 2; ++r4p) {
      unsigned pk = (unsigned)f2bf(acc[m][2 * r4p] + bias[cob + 2 * r4p])
                  | ((unsigned)f2bf(acc[m][2 * r4p + 1] + bias[cob + 2 * r4p + 1]) << 16);
      yp[(size_t)((cob >> 1) + r4p) * S * S + (size_t)row0 * S + px] = pk;
    }
  }
}

// MFMA deconv4x4 s2 p2 + bias + relu, O input rows + both q parities per block.
// LDS-staged weights (r13 form, 256 threads). Used for S=16,32.
template <int S, int O>
__global__ __launch_bounds__(256) void k_deconvu(const unsigned* __restrict__ xp,
                                                 const short* __restrict__ wpk,
                                                 const float* __restrict__ bias,
                                                 unsigned* __restrict__ yp) {
  constexpr int WPC = (S >= 64) ? 2 : 1;
  constexpr int WCO = 4 / WPC;
  constexpr int COS = 64 / WCO;
  constexpr int MR = COS / 16;
  constexpr int PSP = S / WPC;
  constexpr int NR = PSP / 16;
  constexpr int CBK = (S + 2 + 31) / 32;
  constexpr int RS = O + 1;
  const int SO = 2 * S;
  __shared__ short x_s[RS * (S + 2) * PCI];
  __shared__ short w_s[8 * 64 * PCI];
  unsigned* x_s32 = (unsigned*)x_s;
  int t = threadIdx.x, l = t & 63, wv = t >> 6;
  int wcob = (wv % WCO) * COS;
  int wposb = (wv / WCO) * PSP;
  int row0 = blockIdx.x * O;
  int co0 = blockIdx.y * 64;
  int p = blockIdx.z;
  int colb = t & 31, ci2b = t >> 5;
  f32x4 acc[2][O][MR][NR];
#pragma unroll
  for (int q = 0; q < 2; ++q)
#pragma unroll
    for (int o = 0; o < O; ++o)
#pragma unroll
      for (int m = 0; m < MR; ++m)
#pragma unroll
        for (int n = 0; n < NR; ++n) { f32x4 z = {0.f, 0.f, 0.f, 0.f}; acc[q][o][m][n] = z; }
  for (int c0 = 0; c0 < CCH; c0 += 32) {
    int cb = c0 >> 1;
    __syncthreads();
#pragma unroll
    for (int r = 0; r < RS; ++r) {
      int gy = row0 + p - 1 + r;
      bool yok = (gy >= 0 && gy < S);
#pragma unroll
      for (int cbk = 0; cbk < CBK; ++cbk) {
        int col = colb + cbk * 32;
        if (col < S + 2) {
          int gx = col - 1;
          bool ok = yok && (gx >= 0) && (gx < S);
          unsigned v0 = 0, v1 = 0;
          if (ok) {
            size_t gbase = (size_t)(cb + ci2b) * S * S + (size_t)gy * S + gx;
            v0 = xp[gbase];
            v1 = xp[gbase + (size_t)8 * S * S];
          }
          int lb = (r * (S + 2) + col) * (PCI / 2);
          x_s32[lb + ci2b] = v0;
          x_s32[lb + ci2b + 8] = v1;
        }
      }
    }
    for (int i = t; i < 4096; i += 256) {
      int seg8 = i & 7;
      int rowi = i >> 3;
      int c8 = rowi >> 6, co = rowi & 63;
      int qq = c8 >> 2, tt = c8 & 3;
      us4 wv4 = *(const us4*)&wpk[((size_t)(((2 * p + qq) * 4 + tt) * 256 + co0 + co) * 256) + c0 + seg8 * 4];
      *(us4*)&w_s[rowi * PCI + seg8 * 4] = wv4;
    }
    __syncthreads();
#pragma unroll
    for (int dyi = 0; dyi < 2; ++dyi)
#pragma unroll
      for (int o = 0; o < O; ++o) {
        short8 b[3][NR];
#pragma unroll
        for (int off = 0; off < 3; ++off)
#pragma unroll
          for (int n = 0; n < NR; ++n)
            b[off][n] = *(const short8*)&x_s[((dyi + o) * (S + 2) + wposb + n * 16 + (l & 15) + off) * PCI + (l >> 4) * 8];
#pragma unroll
        for (int q = 0; q < 2; ++q)
#pragma unroll
          for (int dxi = 0; dxi < 2; ++dxi) {
            int c8 = q * 4 + dyi * 2 + dxi;
            short8 a[MR];
#pragma unroll
            for (int m = 0; m < MR; ++m)
              a[m] = *(const short8*)&w_s[(c8 * 64 + wcob + m * 16 + (l & 15)) * PCI + (l >> 4) * 8];
#pragma unroll
            for (int m = 0; m < MR; ++m)
#pragma unroll
              for (int n = 0; n < NR; ++n) mfma_bf16(acc[q][o][m][n], a[m], b[dxi + q][n]);
          }
      }
  }
  asm volatile("s_nop 7\n\ts_nop 7" ::);
#pragma unroll
  for (int o = 0; o < O; ++o) {
    int oy = 2 * (row0 + o) + p;
#pragma unroll
    for (int m = 0; m < MR; ++m)
#pragma unroll
      for (int n = 0; n < NR; ++n) {
        int px = wposb + n * 16 + (l & 15);
#pragma unroll
        for (int r4p = 0; r4p < 2; ++r4p) {
          int cob = co0 + wcob + m * 16 + (l >> 4) * 4 + 2 * r4p;
          float b0 = bias[cob], b1 = bias[cob + 1];
          unsigned pk0 = (unsigned)f2bf(fmaxf(acc[0][o][m][n][2 * r4p] + b0, 0.f))
                       | ((unsigned)f2bf(fmaxf(acc[0][o][m][n][2 * r4p + 1] + b1, 0.f)) << 16);
          unsigned pk1 = (unsigned)f2bf(fmaxf(acc[1][o][m][n][2 * r4p] + b0, 0.f))
                       | ((unsigned)f2bf(fmaxf(acc[1][o][m][n][2 * r4p + 1] + b1, 0.f)) << 16);
          uint2 pk = make_uint2(pk0, pk1);
          *(uint2*)&yp[(size_t)(cob >> 1) * SO * SO + (size_t)oy * SO + 2 * px] = pk;
        }
      }
  }
}

// 512-thread deconv for S=128, O=2: 8 waves/block, 2 blocks/CU.
__global__ __launch_bounds__(512) void k_deconvw(const unsigned* __restrict__ xp,
                                                 const short* __restrict__ wpk,
                                                 const float* __restrict__ bias,
                                                 unsigned* __restrict__ yp) {
  constexpr int S = 128;
  constexpr int O = 2;
  constexpr int MR = 2;
  constexpr int PSP = 32;
  constexpr int NR = 2;
  constexpr int RS = O + 1;
  const int SO = 2 * S;
  __shared__ short x_s[RS * (S + 2) * PCI];
  __shared__ short w_s[8 * 64 * PCI];
  unsigned* x_s32 = (unsigned*)x_s;
  int t = threadIdx.x, l = t & 63, wv = t >> 6;
  int wcob = (wv & 1) * 32;
  int wposb = (wv >> 1) * PSP;
  int row0 = blockIdx.x * O;
  int co0 = blockIdx.y * 64;
  int p = blockIdx.z;
  int colb = t & 31, ci2b = t >> 5;
  f32x4 acc[2][O][MR][NR];
#pragma unroll
  for (int q = 0; q < 2; ++q)
#pragma unroll
    for (int o = 0; o < O; ++o)
#pragma unroll
      for (int m = 0; m < MR; ++m)
#pragma unroll
        for (int n = 0; n < NR; ++n) { f32x4 z = {0.f, 0.f, 0.f, 0.f}; acc[q][o][m][n] = z; }
  for (int c0 = 0; c0 < CCH; c0 += 32) {
    int cb = c0 >> 1;
    __syncthreads();
#pragma unroll
    for (int r = 0; r < RS; ++r) {
      int gy = row0 + p - 1 + r;
      bool yok = (gy >= 0 && gy < S);
#pragma unroll
      for (int cbk = 0; cbk < 5; ++cbk) {
        int col = colb + cbk * 32;
        if (col < S + 2) {
          int gx = col - 1;
          bool ok = yok && (gx >= 0) && (gx < S);
          unsigned v = 0;
          if (ok)
            v = xp[(size_t)(cb + ci2b) * S * S + (size_t)gy * S + gx];
          x_s32[(r * (S + 2) + col) * (PCI / 2) + ci2b] = v;
        }
      }
    }
    for (int i = t; i < 4096; i += 512) {
      int seg8 = i & 7;
      int rowi = i >> 3;
      int c8 = rowi >> 6, co = rowi & 63;
      int qq = c8 >> 2, tt = c8 & 3;
      us4 wv4 = *(const us4*)&wpk[((size_t)(((2 * p + qq) * 4 + tt) * 256 + co0 + co) * 256) + c0 + seg8 * 4];
      *(us4*)&w_s[rowi * PCI + seg8 * 4] = wv4;
    }
    __syncthreads();
#pragma unroll
    for (int dyi = 0; dyi < 2; ++dyi)
#pragma unroll
      for (int o = 0; o < O; ++o) {
        short8 b[3][NR];
#pragma unroll
        for (int off = 0; off < 3; ++off)
#pragma unroll
          for (int n = 0; n < NR; ++n)
            b[off][n] = *(const short8*)&x_s[((dyi + o) * (S + 2) + wposb + n * 16 + (l & 15) + off) * PCI + (l >> 4) * 8];
#pragma unroll
        for (int q = 0; q < 2; ++q)
#pragma unroll
          for (int dxi = 0; dxi < 2; ++dxi) {
            int c8 = q * 4 + dyi * 2 + dxi;
            short8 a[MR];
#pragma unroll
            for (int m = 0; m < MR; ++m)
              a[m] = *(const short8*)&w_s[(c8 * 64 + wcob + m * 16 + (l & 15)) * PCI + (l >> 4) * 8];
#pragma unroll
            for (int m = 0; m < MR; ++m)
#pragma unroll
              for (int n = 0; n < NR; ++n) mfma_bf16(acc[q][o][m][n], a[m], b[dxi + q][n]);
          }
      }
  }
  asm volatile("s_nop 7\n\ts_nop 7" ::);
#pragma unroll
  for (int o = 0; o < O; ++o) {
    int oy = 2 * (row0 + o) + p;
#pragma unroll
    for (int m = 0; m < MR; ++m)
#pragma unroll
      for (int n = 0; n < NR; ++n) {
        int px = wposb + n * 16 + (l & 15);
#pragma unroll
        for (int r4p = 0; r4p < 2; ++r4p) {
          int cob = co0 + wcob + m * 16 + (l >> 4) * 4 + 2 * r4p;
          float b0 = bias[cob], b1 = bias[cob + 1];
          unsigned pk0 = (unsigned)f2bf(fmaxf(acc[0][o][m][n][2 * r4p] + b0, 0.f))
                       | ((unsigned)f2bf(fmaxf(acc[0][o][m][n][2 * r4p + 1] + b1, 0.f)) << 16);
          unsigned pk1 = (unsigned)f2bf(fmaxf(acc[1][o][m][n][2 * r4p] + b0, 0.f))
                       | ((unsigned)f2bf(fmaxf(acc[1][o][m][n][2 * r4p + 1] + b1, 0.f)) << 16);
          uint2 pk = make_uint2(pk0, pk1);
          *(uint2*)&yp[(size_t)(cob >> 1) * SO * SO + (size_t)oy * SO + 2 * px] = pk;
        }
      }
  }
}

// 512-thread deconv for S=64, O=1: 8 waves (MR=2, NR=1), grid (64,4,2).
__global__ __launch_bounds__(512) void k_deconvw64(const unsigned* __restrict__ xp,
                                                   const short* __restrict__ wpk,
                                                   const float* __restrict__ bias,
                                                   unsigned* __restrict__ yp) {
  constexpr int S = 64;
  constexpr int MR = 2;
  const int SO = 2 * S;
  __shared__ short x_s[2 * (S + 2) * PCI];
  __shared__ short w_s[8 * 64 * PCI];
  unsigned* x_s32 = (unsigned*)x_s;
  int t = threadIdx.x, l = t & 63, wv = t >> 6;
  int wcob = (wv & 1) * 32;
  int wposb = (wv >> 1) * 16;
  int row0 = blockIdx.x;
  int co0 = blockIdx.y * 64;
  int p = blockIdx.z;
  int colb = t & 31, ci2b = t >> 5;
  f32x4 acc[2][MR];   // [q][m]
#pragma unroll
  for (int q = 0; q < 2; ++q)
#pragma unroll
    for (int m = 0; m < MR; ++m) { f32x4 z = {0.f, 0.f, 0.f, 0.f}; acc[q][m] = z; }
  for (int c0 = 0; c0 < CCH; c0 += 32) {
    int cb = c0 >> 1;
    __syncthreads();
#pragma unroll
    for (int r = 0; r < 2; ++r) {
      int gy = row0 + p - 1 + r;
      bool yok = (gy >= 0 && gy < S);
#pragma unroll
      for (int cbk = 0; cbk < 3; ++cbk) {
        int col = colb + cbk * 32;
        if (col < S + 2) {
          int gx = col - 1;
          bool ok = yok && (gx >= 0) && (gx < S);
          unsigned v = 0;
          if (ok)
            v = xp[(size_t)(cb + ci2b) * S * S + (size_t)gy * S + gx];
          x_s32[(r * (S + 2) + col) * (PCI / 2) + ci2b] = v;
        }
      }
    }
    for (int i = t; i < 4096; i += 512) {
      int seg8 = i & 7;
      int rowi = i >> 3;
      int c8 = rowi >> 6, co = rowi & 63;
      int qq = c8 >> 2, tt = c8 & 3;
      us4 wv4 = *(const us4*)&wpk[((size_t)(((2 * p + qq) * 4 + tt) * 256 + co0 + co) * 256) + c0 + seg8 * 4];
      *(us4*)&w_s[rowi * PCI + seg8 * 4] = wv4;
    }
    __syncthreads();
#pragma unroll
    for (int dyi = 0; dyi < 2; ++dyi) {
      short8 b[3];
#pragma unroll
      for (int off = 0; off < 3; ++off)
        b[off] = *(const short8*)&x_s[(dyi * (S + 2) + wposb + (l & 15) + off) * PCI + (l >> 4) * 8];
#pragma unroll
      for (int q = 0; q < 2; ++q)
#pragma unroll
        for (int dxi = 0; dxi < 2; ++dxi) {
          int c8 = q * 4 + dyi * 2 + dxi;
          short8 a[MR];
#pragma unroll
          for (int m = 0; m < MR; ++m)
            a[m] = *(const short8*)&w_s[(c8 * 64 + wcob + m * 16 + (l & 15)) * PCI + (l >> 4) * 8];
#pragma unroll
          for (int m = 0; m < MR; ++m) mfma_bf16(acc[q][m], a[m], b[dxi + q]);
        }
    }
  }
  asm volatile("s_nop 7\n\ts_nop 7" ::);
  int oy = 2 * row0 + p;
#pragma unroll
  for (int m = 0; m < MR; ++m) {
    int px = wposb + (l & 15);
#pragma unroll
    for (int r4p = 0; r4p < 2; ++r4p) {
      int cob = co0 + wcob + m * 16 + (l >> 4) * 4 + 2 * r4p;
      float b0 = bias[cob], b1 = bias[cob + 1];
      unsigned pk0 = (unsigned)f2bf(fmaxf(acc[0][m][2 * r4p] + b0, 0.f))
                   | ((unsigned)f2bf(fmaxf(acc[0][m][2 * r4p + 1] + b1, 0.f)) << 16);
      unsigned pk1 = (unsigned)f2bf(fmaxf(acc[1][m][2 * r4p] + b0, 0.f))
                   | ((unsigned)f2bf(fmaxf(acc[1][m][2 * r4p + 1] + b1, 0.f)) << 16);
      uint2 pk = make_uint2(pk0, pk1);
      *(uint2*)&yp[(size_t)(cob >> 1) * SO * SO + (size_t)oy * SO + 2 * px] = pk;
    }
  }
}

// sparse final conv3 via MFMA -> bf16 srows
__global__ __launch_bounds__(256) void k_conv3sM(const unsigned* __restrict__ xp,
                                                 const short* __restrict__ wB,
                                                 const float* __restrict__ bias,
                                                 const int* __restrict__ idx,
                                                 short* __restrict__ outb) {
  __shared__ short a_s[16][296];
  __shared__ int py_s[16], px_s[16];
  int t = threadIdx.x, l = t & 63, wv = t >> 6;
  int j0 = blockIdx.x * 16;
  int co0 = blockIdx.y * 128 + wv * 32;
  if (t < 16) {
    int p = idx[j0 + t];
    py_s[t] = p >> 8;
    px_s[t] = p & 255;
  }
  f32x4 acc[2];
  { f32x4 z = {0.f, 0.f, 0.f, 0.f}; acc[0] = z; acc[1] = z; }
  for (int c = 0; c < 8; ++c) {
    __syncthreads();
    for (int i = t; i < 2304; i += 256) {
      int ci2 = i & 15;
      int je = i >> 4;
      int j = je / 9, e = je % 9;
      int gy = py_s[j] - 1 + e / 3, gx = px_s[j] - 1 + e % 3;
      unsigned v = 0;
      if (gy >= 0 && gy < 256 && gx >= 0 && gx < 256)
        v = xp[(size_t)(c * 16 + ci2) * HWP + gy * 256 + gx];
      *(unsigned*)&a_s[j][e * 32 + 2 * ci2] = v;
    }
    __syncthreads();
#pragma unroll
    for (int s = 0; s < 9; ++s) {
      short8 a = *(const short8*)&a_s[l & 15][s * 32 + (l >> 4) * 8];
      int kg = c * 288 + s * 32 + (l >> 4) * 8;
      short8 b0 = *(const short8*)&wB[(size_t)(co0 + (l & 15)) * 2304 + kg];
      short8 b1 = *(const short8*)&wB[(size_t)(co0 + 16 + (l & 15)) * 2304 + kg];
      mfma_bf16(acc[0], a, b0);
      mfma_bf16(acc[1], a, b1);
    }
  }
  asm volatile("s_nop 7\n\ts_nop 7" ::);
#pragma unroll
  for (int n = 0; n < 2; ++n)
#pragma unroll
    for (int r = 0; r < 4; ++r) {
      int j = j0 + (l >> 4) * 4 + r;
      int co = co0 + n * 16 + (l & 15);
      outb[(size_t)j * 256 + co] = (short)f2bf(acc[n][r] + bias[co]);
    }
}

// MFMA in-projection: grid (128 j-tiles, 12 out-tiles of 64). 0-3=Q, 4-7=K, 8-11=V.
__global__ __launch_bounds__(256) void k_qkv3(const short* __restrict__ dq,
                                              const short* __restrict__ sr,
                                              const short* __restrict__ wBi,
                                              const float* __restrict__ bias,
                                              short* __restrict__ Qb,
                                              short* __restrict__ Kb,
                                              short* __restrict__ Vt) {
  __shared__ short a_s[16 * 264];
  unsigned* a_s32 = (unsigned*)a_s;
  int t = threadIdx.x, l = t & 63, wv = t >> 6;
  int j0 = blockIdx.x * 16;
  int third = blockIdx.y >> 2;
  const unsigned* s32 = (const unsigned*)(third ? sr : dq);
  for (int i = t; i < 2048; i += 256) {
    int row = i >> 7, c2 = i & 127;
    a_s32[row * 132 + c2] = s32[(size_t)(j0 + row) * 128 + c2];
  }
  __syncthreads();
  int cog = blockIdx.y * 64 + wv * 16 + (l & 15);
  f32x4 acc = {0.f, 0.f, 0.f, 0.f};
  const short* brow = wBi + (size_t)cog * 256 + (l >> 4) * 8;
  const short* arow = a_s + (l & 15) * 264 + (l >> 4) * 8;
#pragma unroll
  for (int kc = 0; kc < 8; ++kc) {
    short8 a = *(const short8*)(arow + kc * 32);
    short8 b = *(const short8*)(brow + kc * 32);
    mfma_bf16(acc, a, b);
  }
  asm volatile("s_nop 7\n\ts_nop 7" ::);
  float bv = bias[cog];
  int co = cog & 255;
  int h = co >> 5, d = co & 31;
#pragma unroll
  for (int r = 0; r < 4; ++r) {
    int j = j0 + (l >> 4) * 4 + r;
    short v = (short)f2bf(acc[r] + bv);
    if (third == 0)      Qb[((size_t)h * 2048 + j) * 32 + d] = v;
    else if (third == 1) Kb[((size_t)h * 2048 + j) * 32 + d] = v;
    else                 Vt[((size_t)h * 32 + d) * 2048 + j] = v;
  }
}

// fused flash attention. grid (32 qtiles, 8 h), 4 waves. Writes bf16 Ob.
__global__ __launch_bounds__(256) void k_fattn(const short* __restrict__ Qb,
                                               const short* __restrict__ Kb,
                                               const short* __restrict__ Vt,
                                               short* __restrict__ Ob) {
  __shared__ short P_lds[4][16][136];
  int t = threadIdx.x, l = t & 63, wv = t >> 6;
  int h = blockIdx.y;
  int q0 = blockIdx.x * 64 + wv * 16;
  const short* Qh = Qb + (size_t)h * 2048 * 32;
  const short* Kh = Kb + (size_t)h * 2048 * 32;
  const short* Vh = Vt + (size_t)h * 32 * 2048;
  short8 a_q = *(const short8*)&Qh[(size_t)(q0 + (l & 15)) * 32 + (l >> 4) * 8];
  f32x4 o0 = {0.f, 0.f, 0.f, 0.f}, o1 = {0.f, 0.f, 0.f, 0.f};
  float m_run[4], l_run[4];
#pragma unroll
  for (int r = 0; r < 4; ++r) { m_run[r] = -3e38f; l_run[r] = 0.f; }
  const float scale = 0.17677669529663687f;
  for (int k0 = 0; k0 < 2048; k0 += 128) {
    f32x4 s[8];
#pragma unroll
    for (int kt = 0; kt < 8; ++kt) {
      f32x4 z = {0.f, 0.f, 0.f, 0.f};
      s[kt] = z;
      short8 b = *(const short8*)&Kh[(size_t)(k0 + kt * 16 + (l & 15)) * 32 + (l >> 4) * 8];
      mfma_bf16(s[kt], a_q, b);
    }
    asm volatile("s_nop 7\n\ts_nop 7" ::);
    float tm[4];
#pragma unroll
    for (int r = 0; r < 4; ++r) {
      float mx = s[0][r];
#pragma unroll
      for (int kt = 1; kt < 8; ++kt) mx = fmaxf(mx, s[kt][r]);
      tm[r] = mx * scale;
    }
#pragma unroll
    for (int mask = 1; mask < 16; mask <<= 1)
#pragma unroll
      for (int r = 0; r < 4; ++r) tm[r] = fmaxf(tm[r], __shfl_xor(tm[r], mask));
    float mn[4], al[4], rs[4];
#pragma unroll
    for (int r = 0; r < 4; ++r) {
      mn[r] = fmaxf(m_run[r], tm[r]);
      al[r] = __expf(m_run[r] - mn[r]);
      rs[r] = 0.f;
    }
#pragma unroll
    for (int kt = 0; kt < 8; ++kt)
#pragma unroll
      for (int r = 0; r < 4; ++r) {
        float pv = __expf(s[kt][r] * scale - mn[r]);
        s[kt][r] = pv;
        rs[r] += pv;
      }
#pragma unroll
    for (int mask = 1; mask < 16; mask <<= 1)
#pragma unroll
      for (int r = 0; r < 4; ++r) rs[r] += __shfl_xor(rs[r], mask);
#pragma unroll
    for (int r = 0; r < 4; ++r) {
      l_run[r] = l_run[r] * al[r] + rs[r];
      m_run[r] = mn[r];
      o0[r] *= al[r];
      o1[r] *= al[r];
    }
#pragma unroll
    for (int kt = 0; kt < 8; ++kt)
#pragma unroll
      for (int r = 0; r < 4; ++r)
        P_lds[wv][(l >> 4) * 4 + r][kt * 16 + (l & 15)] = (short)f2bf(s[kt][r]);
#pragma unroll
    for (int kc = 0; kc < 4; ++kc) {
      short8 ap = *(const short8*)&P_lds[wv][l & 15][kc * 32 + (l >> 4) * 8];
      short8 b0 = *(const short8*)&Vh[(size_t)(l & 15) * 2048 + k0 + kc * 32 + (l >> 4) * 8];
      short8 b1 = *(const short8*)&Vh[(size_t)(16 + (l & 15)) * 2048 + k0 + kc * 32 + (l >> 4) * 8];
      mfma_bf16(o0, ap, b0);
      mfma_bf16(o1, ap, b1);
    }
  }
  asm volatile("s_nop 7\n\ts_nop 7" ::);
#pragma unroll
  for (int r = 0; r < 4; ++r) {
    float inv = 1.f / l_run[r];
    int qr = q0 + (l >> 4) * 4 + r;
    Ob[(size_t)qr * 256 + h * 32 + (l & 15)] = (short)f2bf(o0[r] * inv);
    Ob[(size_t)qr * 256 + h * 32 + 16 + (l & 15)] = (short)f2bf(o1[r] * inv);
  }
}

// MFMA out-projection + scatter. grid (128 j-tiles, 4 co-tiles of 64).
__global__ __launch_bounds__(256) void k_outprojM(const short* __restrict__ Ob,
                                                  const short* __restrict__ wBo,
                                                  const float* __restrict__ ob,
                                                  const int* __restrict__ idx,
                                                  float* __restrict__ out) {
  __shared__ short a_s[16 * 264];
  __shared__ int jp[16];
  unsigned* a_s32 = (unsigned*)a_s;
  const unsigned* s32 = (const unsigned*)Ob;
  int t = threadIdx.x, l = t & 63, wv = t >> 6;
  int j0 = blockIdx.x * 16;
  if (t < 16) jp[t] = idx[j0 + t];
  for (int i = t; i < 2048; i += 256) {
    int row = i >> 7, c2 = i & 127;
    a_s32[row * 132 + c2] = s32[(size_t)(j0 + row) * 128 + c2];
  }
  __syncthreads();
  int co = blockIdx.y * 64 + wv * 16 + (l & 15);
  f32x4 acc = {0.f, 0.f, 0.f, 0.f};
  const short* brow = wBo + (size_t)co * 256 + (l >> 4) * 8;
  const short* arow = a_s + (l & 15) * 264 + (l >> 4) * 8;
#pragma unroll
  for (int kc = 0; kc < 8; ++kc) {
    short8 a = *(const short8*)(arow + kc * 32);
    short8 b = *(const short8*)(brow + kc * 32);
    mfma_bf16(acc, a, b);
  }
  asm volatile("s_nop 7\n\ts_nop 7" ::);
  float bv = ob[co];
#pragma unroll
  for (int r = 0; r < 4; ++r) {
    int jl = (l >> 4) * 4 + r;
    out[(size_t)co * HWP + jp[jl]] = acc[r] + bv;
  }
}

extern "C" void kernel_launch(void* const* d_in, const int* in_sizes, int n_in,
                              void* d_out, int out_size, void* d_ws, size_t ws_size,
                              hipStream_t stream) {
  const float* down  = (const float*)d_in[0];
  const float* swint = (const float*)d_in[1];
  const float* wt_w  = (const float*)d_in[2];
  const float* wt_b  = (const float*)d_in[3];
  const float* up_dw = (const float*)d_in[4];
  const float* up_db = (const float*)d_in[5];
  const float* up_cw = (const float*)d_in[6];
  const float* up_cb = (const float*)d_in[7];
  const float* gate_w = (const float*)d_in[8];
  const float* in_w  = (const float*)d_in[10];
  const float* in_b  = (const float*)d_in[11];
  const float* out_w = (const float*)d_in[12];
  const float* out_b = (const float*)d_in[13];
  float* out = (float*)d_out;
  char* ws = (char*)d_ws;

  unsigned* actA = (unsigned*)ws;
  unsigned* actB = (unsigned*)(ws + BUF_B_OFF);
  unsigned int* hist = (unsigned int*)(ws + HIST_OFF);
  SelState* st = (SelState*)(ws + STATE_OFF);
  int* idx = (int*)(ws + IDX_OFF);
  int* eq = (int*)(ws + EQ_OFF);
  short* Ob = (short*)(ws + OB_OFF);
  short* wBi = (short*)(ws + WBI_OFF);
  short* wBo = (short*)(ws + WBO_OFF);
  short* srowsb = (short*)(ws + SROWS_OFF);
  short* dq = (short*)(ws + DQ_OFF);
  float* gpart = (float*)(ws + GPART_OFF);
  short* wB5 = (short*)(ws + WT5_OFF);
  short* Qb = (short*)(ws + QB_OFF);
  short* Kb = (short*)(ws + KB_OFF);
  short* Vt = (short*)(ws + VT_OFF);
  short* cpk = (short*)(ws + CPK_OFF);
  short* dpk = (short*)(ws + DPK_OFF);
  short* wBt = (short*)(ws + WTW_OFF);
  float* wpart = (float*)(ws + WPART_OFF);
  short* xq0 = (short*)(ws + XQ0_OFF);

  // gate partials + passthrough copy
  k_gatecopy2<<<dim3(256, 8), 256, 0, stream>>>(down, gate_w, out, gpart);

  // cooperative exact top-k + gather (replaces 13 launches)
  {
    void* args[] = {(void*)&gpart, (void*)&down, (void*)&hist, (void*)&st,
                    (void*)&idx, (void*)&eq, (void*)&dq};
    hipLaunchCooperativeKernel(k_topk, dim3(256), dim3(256), args, 0u, stream);
  }

  // all weight packs in one launch (conv3 x4, deconv x5, conv5, in_w, out_w, wt_w)
  k_packall<<<3840, 256, 0, stream>>>(up_cw, up_dw, in_w, out_w, wt_w,
                                      cpk, dpk, wB5, wBi, wBo, wBt);

  // stage 0: K-split MFMA 1x1 conv (parallel weight fetch) + reduce, then deconv 8->16
  k_wtconvP<<<dim3(4, 8), 256, 0, stream>>>(swint, wBt, wpart);
  k_wtred<<<64, 256, 0, stream>>>(wpart, wt_b, xq0);
  k_deconv8M<<<dim3(4, 4), 256, 0, stream>>>(xq0, dpk, up_db, actB);

  // upsampler chain: MFMA bf16 implicit-GEMM, packed-bf16 activations (A/B ping-pong)
  k_conv3u<16, 2><<<dim3(8, 4), 256, 0, stream>>>(actB, cpk, up_cb, actA);
  k_deconvu<16, 2><<<dim3(8, 4, 2), 256, 0, stream>>>(actA, dpk + 1048576, up_db + 256, actB);
  k_conv3u<32, 2><<<dim3(16, 4), 256, 0, stream>>>(actB, cpk + 589824, up_cb + 256, actA);
  k_deconvu<32, 2><<<dim3(16, 4, 2), 256, 0, stream>>>(actA, dpk + 2 * 1048576, up_db + 512, actB);
  k_conv3v64<<<dim3(64, 4), 512, 0, stream>>>(actB, cpk + 2 * 589824, up_cb + 512, actA);
  k_deconvw64<<<dim3(64, 4, 2), 512, 0, stream>>>(actA, dpk + 3 * 1048576, up_db + 768, actB);
  k_conv3v<<<dim3(128, 4), 512, 0, stream>>>(actB, cpk + 3 * 589824, up_cb + 768, actA);
  k_deconvw<<<dim3(64, 4, 2), 512, 0, stream>>>(actA, dpk + 4 * 1048576, up_db + 1024, actB);

  // final conv3 via MFMA at the 2048 gathered positions -> bf16 srows
  k_conv3sM<<<dim3(128, 2), 256, 0, stream>>>(actB, wB5, up_cb + 1024, idx, srowsb);

  // attention path: MFMA in-projection, fused flash attention, MFMA out-projection
  k_qkv3<<<dim3(128, 12), 256, 0, stream>>>(dq, srowsb, wBi, in_b, Qb, Kb, Vt);
  k_fattn<<<dim3(32, 8), 256, 0, stream>>>(Qb, Kb, Vt, Ob);
  k_outprojM<<<dim3(128, 4), 256, 0, stream>>>(Ob, wBo, out_b, idx, out);
}

// Round 24
// 626.936 us; speedup vs baseline: 1.3863x; 1.3863x over previous
//
#include <hip/hip_runtime.h>
#include <math.h>

#define CCH 256
#define HWP 65536
#define PCI 40   // padded ci stride (shorts) in LDS

typedef short short8 __attribute__((ext_vector_type(8)));
typedef float f32x4 __attribute__((ext_vector_type(4)));
typedef unsigned short us4 __attribute__((ext_vector_type(4)));

__device__ inline unsigned short f2bf(float f) {
  unsigned u = __float_as_uint(f);
  return (unsigned short)((u + 0x7FFFu + ((u >> 16) & 1u)) >> 16);
}
__device__ inline float bf2f(unsigned short s) {
  return __uint_as_float(((unsigned)s) << 16);
}

__device__ inline void mfma_bf16(f32x4& d, short8 a, short8 b) {
  asm volatile("v_mfma_f32_16x16x32_bf16 %0, %1, %2, %0" : "+v"(d) : "v"(a), "v"(b));
}

// ---- ws layout (bytes) ----
static const size_t BUF_B_OFF = 67108864;        // actA @0, actB @64MB
static const size_t TAIL_OFF  = 134217728;
static const size_t KEYS_OFF  = TAIL_OFF;
static const size_t IDX_OFF   = TAIL_OFF + 263424;
static const size_t EQ_OFF    = TAIL_OFF + 271616;
static const size_t OB_OFF    = 6291456;
static const size_t WBI_OFF   = 8388608;
static const size_t WBO_OFF   = 9437184;
static const size_t SROWS_OFF = 10485760;
static const size_t DQ_OFF    = 12582912;
static const size_t GPART_OFF = 16777216;
static const size_t WT5_OFF   = 20971520;
static const size_t QB_OFF    = 31457280;
static const size_t KB_OFF    = 32505856;
static const size_t VT_OFF    = 33554432;
static const size_t CPK_OFF   = 37748736;
static const size_t DPK_OFF   = 44040192;        // 5 layers x 1048576 shorts -> ends 54525952
static const size_t WTW_OFF   = 54525952;        // bf16 wt_w [256][768] 384KB
static const size_t WPART_OFF = 55050240;        // f32 partials [8][64][256] 512KB
static const size_t XQ0_OFF   = 57671680;        // bf16 stage0 x [64][256]

// merged weight packing: conv3 x4, deconv x5, conv5, in_w, out_w, wt_w
__global__ void k_packall(const float* __restrict__ up_cw, const float* __restrict__ up_dw,
                          const float* __restrict__ in_w, const float* __restrict__ out_w,
                          const float* __restrict__ wt_w,
                          short* __restrict__ cpk, short* __restrict__ dpk,
                          short* __restrict__ wB5, short* __restrict__ wBi,
                          short* __restrict__ wBo, short* __restrict__ wBt) {
  int b = blockIdx.x;
  int tid = threadIdx.x;
  if (b < 1024) {
    int layer = b >> 8, co = b & 255, ci = tid;
    const float* wl = up_cw + (size_t)layer * 589824;
    short* wo = cpk + (size_t)layer * 589824;
    for (int tap = 0; tap < 9; ++tap)
      wo[((size_t)(tap * 256 + co) * 256) + ci] = (short)f2bf(wl[((size_t)(co * 256 + ci)) * 9 + tap]);
  } else if (b < 2304) {
    int bb = b - 1024;
    int layer = bb >> 8, co = bb & 255, ci = tid;
    const float* wl = up_dw + (size_t)layer * 1048576;
    for (int pq = 0; pq < 4; ++pq) {
      int p = pq >> 1, q = pq & 1;
      for (int tt = 0; tt < 4; ++tt) {
        int dyi = tt >> 1, dxi = tt & 1;
        int wr = dyi ? (1 - p) : (3 - p);
        int wc = dxi ? (1 - q) : (3 - q);
        dpk[((size_t)layer * 1048576) + ((size_t)((pq * 4 + tt) * 256 + co) * 256) + ci] =
            (short)f2bf(wl[((size_t)(ci * 256 + co)) * 16 + wr * 4 + wc]);
      }
    }
  } else if (b < 2560) {
    int co = b - 2304;
    const float* w5 = up_cw + 2359296;
    for (int kk = tid; kk < 2304; kk += 256) {
      int c = kk / 288, r = kk % 288;
      int e = r >> 5, cl = r & 31;
      wB5[(size_t)co * 2304 + kk] = (short)f2bf(w5[(size_t)co * 2304 + (size_t)(c * 32 + cl) * 9 + e]);
    }
  } else if (b < 3328) {
    int o = b - 2560;
    wBi[(size_t)o * 256 + tid] = (short)f2bf(in_w[(size_t)o * 256 + tid]);
  } else if (b < 3584) {
    int o = b - 3328;
    wBo[(size_t)o * 256 + tid] = (short)f2bf(out_w[(size_t)o * 256 + tid]);
  } else {
    int co = b - 3584;
    for (int kk = tid; kk < 768; kk += 256)
      wBt[(size_t)co * 768 + kk] = (short)f2bf(wt_w[(size_t)co * 768 + kk]);
  }
}

// gate partials + passthrough copy: block = (p-tile 256, c-chunk of 32)
__global__ void k_gatecopy2(const float* __restrict__ down, const float* __restrict__ gw,
                            float* __restrict__ out, float* __restrict__ gpart) {
  int p = blockIdx.x * 256 + threadIdx.x;
  int cc = blockIdx.y;
  float acc = 0.f;
  for (int c = cc * 32; c < cc * 32 + 32; ++c) {
    float v = down[(size_t)c * HWP + p];
    out[(size_t)c * HWP + p] = v;
    acc += v * gw[c];
  }
  gpart[(size_t)cc * HWP + p] = acc;
}

// deterministic reduce of gate partials -> orderable keys
__global__ void k_gkey(const float* __restrict__ gpart, unsigned* __restrict__ keys) {
  int p = blockIdx.x * 256 + threadIdx.x;
  float s = 0.f;
  for (int cc = 0; cc < 8; ++cc) s += gpart[(size_t)cc * HWP + p];
  unsigned u = __float_as_uint(s);
  keys[p] = (u & 0x80000000u) ? ~u : (u | 0x80000000u);
}

// single-workgroup exact top-k radix select: replaces init/4x(hist,scan)/compact/
// finalize (11 launches). 1024 threads, 64 keys each in registers; LDS histogram;
// __syncthreads-only synchronization (no grid.sync, no multi-launch).
__global__ __launch_bounds__(1024) void k_select1(const unsigned* __restrict__ keys,
                                                  int* __restrict__ idx,
                                                  int* __restrict__ eq) {
  __shared__ unsigned lh[256];
  __shared__ unsigned sP;
  __shared__ int skneed, snG, snE;
  int t = threadIdx.x;
  unsigned key[64];
#pragma unroll
  for (int i = 0; i < 64; ++i) key[i] = keys[i * 1024 + t];
  if (t == 0) { sP = 0u; skneed = 2048; snG = 0; snE = 0; }
  __syncthreads();
  for (int r = 0; r < 4; ++r) {
    if (t < 256) lh[t] = 0;
    __syncthreads();
    unsigned P = sP;
#pragma unroll
    for (int i = 0; i < 64; ++i) {
      bool ok = (r == 0) || ((key[i] >> (32 - 8 * r)) == P);
      if (ok) atomicAdd(&lh[(key[i] >> (24 - 8 * r)) & 255u], 1u);
    }
    __syncthreads();
    if (t == 0) {
      int need = skneed;
      unsigned cum = 0;
      for (int b = 255; b >= 0; --b) {
        unsigned h = lh[b];
        if (cum + h >= (unsigned)need) {
          sP = (sP << 8) | (unsigned)b;
          skneed = need - (int)cum;
          break;
        }
        cum += h;
      }
    }
    __syncthreads();
  }
  // compact (set-equivalent to multi-block version; idx order is arbitrary,
  // scatter is permutation-invariant)
  {
    unsigned P = sP;
#pragma unroll
    for (int i = 0; i < 64; ++i) {
      int p = i * 1024 + t;
      if (key[i] > P) {
        int pos = atomicAdd(&snG, 1);
        idx[pos] = p;
      } else if (key[i] == P) {
        int e = atomicAdd(&snE, 1);
        if (e < 4096) eq[e] = p;
      }
    }
  }
  __syncthreads();
  if (t == 0) {
    int n = snE;
    if (n > 4096) n = 4096;
    for (int i = 1; i < n; ++i) {
      int v = eq[i], j = i - 1;
      while (j >= 0 && eq[j] > v) { eq[j + 1] = eq[j]; --j; }
      eq[j + 1] = v;
    }
    int g = snG;
    for (int i = 0; i < skneed; ++i) idx[g + i] = eq[i];
  }
}

// gather down rows at idx -> bf16 dq[2048][256]
__global__ void k_gatherq(const float* __restrict__ down, const int* __restrict__ idx,
                          short* __restrict__ dq) {
  int j = blockIdx.x, c = threadIdx.x;
  int p = idx[j];
  dq[(size_t)j * 256 + c] = (short)f2bf(down[(size_t)c * HWP + p]);
}

// K-split MFMA 1x1 conv 768->256: grid (4 co-tiles, 8 ksplits). f32 partials out.
__global__ __launch_bounds__(256) void k_wtconvP(const float* __restrict__ swint,
                                                 const short* __restrict__ wBt,
                                                 float* __restrict__ wpart) {
  __shared__ short x_s[64 * 40];
  int t = threadIdx.x, l = t & 63, wv = t >> 6;
  int co0 = blockIdx.x * 64;
  int ks = blockIdx.y;
  int kbase = ks * 96;
  f32x4 acc[4];
#pragma unroll
  for (int m = 0; m < 4; ++m) { f32x4 z = {0.f, 0.f, 0.f, 0.f}; acc[m] = z; }
#pragma unroll
  for (int cc = 0; cc < 3; ++cc) {
    int c0 = kbase + cc * 32;
    __syncthreads();
    {
      int ci = t >> 3, pos0 = (t & 7) * 8;
      const float* sp = swint + (size_t)(c0 + ci) * 64 + pos0;
#pragma unroll
      for (int pp = 0; pp < 8; ++pp)
        x_s[(pos0 + pp) * 40 + ci] = (short)f2bf(sp[pp]);
    }
    __syncthreads();
    short8 bfrag = *(const short8*)&x_s[(wv * 16 + (l & 15)) * 40 + (l >> 4) * 8];
#pragma unroll
    for (int m = 0; m < 4; ++m) {
      short8 af = *(const short8*)&wBt[(size_t)(co0 + m * 16 + (l & 15)) * 768 + c0 + (l >> 4) * 8];
      mfma_bf16(acc[m], af, bfrag);
    }
  }
  asm volatile("s_nop 7\n\ts_nop 7" ::);
  int pos = wv * 16 + (l & 15);
#pragma unroll
  for (int m = 0; m < 4; ++m)
#pragma unroll
    for (int r = 0; r < 4; ++r) {
      int co = co0 + m * 16 + (l >> 4) * 4 + r;
      wpart[((size_t)ks * 64 + pos) * 256 + co] = acc[m][r];
    }
}

// deterministic reduce of 8 K-split partials + bias -> bf16 xq0[pos][co]
__global__ void k_wtred(const float* __restrict__ wpart, const float* __restrict__ bias,
                        short* __restrict__ xq0) {
  int pos = blockIdx.x, co = threadIdx.x;
  float s = bias[co];
  for (int ks = 0; ks < 8; ++ks) s += wpart[((size_t)ks * 64 + pos) * 256 + co];
  xq0[(size_t)pos * 256 + co] = (short)f2bf(s);
}

// MFMA deconv 8->16 (stage 0) + bias + relu. grid (4 co-tiles, 4 pq). Packed out.
__global__ __launch_bounds__(256) void k_deconv8M(const short* __restrict__ xq0,
                                                  const short* __restrict__ wpk,
                                                  const float* __restrict__ bias,
                                                  unsigned* __restrict__ yp) {
  __shared__ short x_s[121 * 260];
  int t = threadIdx.x, l = t & 63, wv = t >> 6;
  int co0 = blockIdx.x * 64;
  int pq = blockIdx.y, p = pq >> 1, q = pq & 1;
  const unsigned* xs32 = (const unsigned*)xq0;
  for (int i = t; i < 121 * 128; i += 256) {
    int row = i >> 7, c2 = i & 127;
    int iy = row / 11 - 1, ix = row % 11 - 1;
    unsigned v = 0;
    if (iy >= 0 && iy < 8 && ix >= 0 && ix < 8)
      v = xs32[(size_t)(iy * 8 + ix) * 128 + c2];
    *(unsigned*)&x_s[row * 260 + 2 * c2] = v;
  }
  __syncthreads();
  f32x4 acc[4];
#pragma unroll
  for (int m = 0; m < 4; ++m) { f32x4 z = {0.f, 0.f, 0.f, 0.f}; acc[m] = z; }
  int pos = wv * 16 + (l & 15);
  int ay = pos >> 3, bx = pos & 7;
#pragma unroll
  for (int tt = 0; tt < 4; ++tt) {
    int dyi = tt >> 1, dxi = tt & 1;
    int rowx = (ay + p + dyi) * 11 + (bx + q + dxi);
#pragma unroll
    for (int c0 = 0; c0 < 256; c0 += 32) {
      short8 bfrag = *(const short8*)&x_s[rowx * 260 + c0 + (l >> 4) * 8];
#pragma unroll
      for (int m = 0; m < 4; ++m) {
        short8 af = *(const short8*)&wpk[((size_t)((pq * 4 + tt) * 256 + co0 + m * 16 + (l & 15)) * 256) + c0 + (l >> 4) * 8];
        mfma_bf16(acc[m], af, bfrag);
      }
    }
  }
  asm volatile("s_nop 7\n\ts_nop 7" ::);
  int oy = 2 * ay + p, ox = 2 * bx + q;
#pragma unroll
  for (int m = 0; m < 4; ++m)
#pragma unroll
    for (int r4p = 0; r4p < 2; ++r4p) {
      int cob = co0 + m * 16 + (l >> 4) * 4 + 2 * r4p;
      unsigned pk = (unsigned)f2bf(fmaxf(acc[m][2 * r4p] + bias[cob], 0.f))
                  | ((unsigned)f2bf(fmaxf(acc[m][2 * r4p + 1] + bias[cob + 1], 0.f)) << 16);
      yp[(size_t)(cob >> 1) * 256 + oy * 16 + ox] = pk;
    }
}

// MFMA conv3x3 pad1 + bias, O output rows per block. Weights direct-from-global.
template <int S, int O>
__global__ __launch_bounds__(256) void k_conv3u(const unsigned* __restrict__ xp,
                                                const short* __restrict__ wpk,
                                                const float* __restrict__ bias,
                                                unsigned* __restrict__ yp) {
  constexpr int WPC = (S >= 64) ? 2 : 1;
  constexpr int WCO = 4 / WPC;
  constexpr int COS = 64 / WCO;
  constexpr int MR = COS / 16;
  constexpr int PSP = S / WPC;
  constexpr int NR = PSP / 16;
  constexpr int CBK = (S + 2 + 31) / 32;
  constexpr int RS = O + 2;
  __shared__ short x_s[RS * (S + 2) * PCI];
  unsigned* x_s32 = (unsigned*)x_s;
  int t = threadIdx.x, l = t & 63, wv = t >> 6;
  int wcob = (wv % WCO) * COS;
  int wposb = (wv / WCO) * PSP;
  int row0 = blockIdx.x * O;
  int co0 = blockIdx.y * 64;
  int colb = t & 31, ci2b = t >> 5;
  f32x4 acc[O][MR][NR];
#pragma unroll
  for (int o = 0; o < O; ++o)
#pragma unroll
    for (int m = 0; m < MR; ++m)
#pragma unroll
      for (int n = 0; n < NR; ++n) { f32x4 z = {0.f, 0.f, 0.f, 0.f}; acc[o][m][n] = z; }
  for (int c0 = 0; c0 < CCH; c0 += 32) {
    int cb = c0 >> 1;
    __syncthreads();
#pragma unroll
    for (int r = 0; r < RS; ++r) {
      int gy = row0 - 1 + r;
      bool yok = (gy >= 0 && gy < S);
#pragma unroll
      for (int cbk = 0; cbk < CBK; ++cbk) {
        int col = colb + cbk * 32;
        if (col < S + 2) {
          int gx = col - 1;
          bool ok = yok && (gx >= 0) && (gx < S);
          unsigned v0 = 0, v1 = 0;
          if (ok) {
            size_t gbase = (size_t)(cb + ci2b) * S * S + (size_t)gy * S + gx;
            v0 = xp[gbase];
            v1 = xp[gbase + (size_t)8 * S * S];
          }
          int lb = (r * (S + 2) + col) * (PCI / 2);
          x_s32[lb + ci2b] = v0;
          x_s32[lb + ci2b + 8] = v1;
        }
      }
    }
    __syncthreads();
#pragma unroll
    for (int dyg = 0; dyg < 3; ++dyg)
#pragma unroll
      for (int dx = 0; dx < 3; ++dx) {
        short8 a[MR];
#pragma unroll
        for (int m = 0; m < MR; ++m)
          a[m] = *(const short8*)&wpk[((size_t)((dyg * 3 + dx) * 256 + co0 + wcob + m * 16 + (l & 15)) * 256) + c0 + (l >> 4) * 8];
#pragma unroll
        for (int o = 0; o < O; ++o) {
          short8 b[NR];
#pragma unroll
          for (int n = 0; n < NR; ++n)
            b[n] = *(const short8*)&x_s[((dyg + o) * (S + 2) + wposb + n * 16 + (l & 15) + dx) * PCI + (l >> 4) * 8];
#pragma unroll
          for (int m = 0; m < MR; ++m)
#pragma unroll
            for (int n = 0; n < NR; ++n) mfma_bf16(acc[o][m][n], a[m], b[n]);
        }
      }
  }
  asm volatile("s_nop 7\n\ts_nop 7" ::);
#pragma unroll
  for (int o = 0; o < O; ++o)
#pragma unroll
    for (int m = 0; m < MR; ++m)
#pragma unroll
      for (int n = 0; n < NR; ++n) {
        int cob = co0 + wcob + m * 16 + (l >> 4) * 4;
        int px = wposb + n * 16 + (l & 15);
#pragma unroll
        for (int r4p = 0; r4p < 2; ++r4p) {
          unsigned pk = (unsigned)f2bf(acc[o][m][n][2 * r4p] + bias[cob + 2 * r4p])
                      | ((unsigned)f2bf(acc[o][m][n][2 * r4p + 1] + bias[cob + 2 * r4p + 1]) << 16);
          yp[(size_t)((cob >> 1) + r4p) * S * S + (size_t)(row0 + o) * S + px] = pk;
        }
      }
}

// 512-thread conv3 for S=128 with LDS-staged weights: 8 waves, 2 blocks/CU.
__global__ __launch_bounds__(512) void k_conv3v(const unsigned* __restrict__ xp,
                                                const short* __restrict__ wpk,
                                                const float* __restrict__ bias,
                                                unsigned* __restrict__ yp) {
  constexpr int S = 128;
  constexpr int MR = 2;
  constexpr int PSP = 32;
  constexpr int NR = 2;
  __shared__ short x_s[3 * (S + 2) * PCI];
  __shared__ short w_s[9 * 64 * PCI];
  unsigned* x_s32 = (unsigned*)x_s;
  int t = threadIdx.x, l = t & 63, wv = t >> 6;
  int wcob = (wv & 1) * 32;
  int wposb = (wv >> 1) * PSP;
  int row0 = blockIdx.x;
  int co0 = blockIdx.y * 64;
  int colb = t & 31, ci2b = t >> 5;
  f32x4 acc[MR][NR];
#pragma unroll
  for (int m = 0; m < MR; ++m)
#pragma unroll
    for (int n = 0; n < NR; ++n) { f32x4 z = {0.f, 0.f, 0.f, 0.f}; acc[m][n] = z; }
  for (int c0 = 0; c0 < CCH; c0 += 32) {
    int cb = c0 >> 1;
    __syncthreads();
#pragma unroll
    for (int r = 0; r < 3; ++r) {
      int gy = row0 - 1 + r;
      bool yok = (gy >= 0 && gy < S);
#pragma unroll
      for (int cbk = 0; cbk < 5; ++cbk) {
        int col = colb + cbk * 32;
        if (col < S + 2) {
          int gx = col - 1;
          bool ok = yok && (gx >= 0) && (gx < S);
          unsigned v = 0;
          if (ok)
            v = xp[(size_t)(cb + ci2b) * S * S + (size_t)gy * S + gx];
          x_s32[(r * (S + 2) + col) * (PCI / 2) + ci2b] = v;
        }
      }
    }
    for (int i = t; i < 4608; i += 512) {
      int seg8 = i & 7;
      int rowi = i >> 3;
      int tap = rowi >> 6, co = rowi & 63;
      us4 wv4 = *(const us4*)&wpk[((size_t)(tap * 256 + co0 + co) * 256) + c0 + seg8 * 4];
      *(us4*)&w_s[rowi * PCI + seg8 * 4] = wv4;
    }
    __syncthreads();
#pragma unroll
    for (int dyg = 0; dyg < 3; ++dyg)
#pragma unroll
      for (int dx = 0; dx < 3; ++dx) {
        short8 a[MR];
#pragma unroll
        for (int m = 0; m < MR; ++m)
          a[m] = *(const short8*)&w_s[((dyg * 3 + dx) * 64 + wcob + m * 16 + (l & 15)) * PCI + (l >> 4) * 8];
        short8 b[NR];
#pragma unroll
        for (int n = 0; n < NR; ++n)
          b[n] = *(const short8*)&x_s[(dyg * (S + 2) + wposb + n * 16 + (l & 15) + dx) * PCI + (l >> 4) * 8];
#pragma unroll
        for (int m = 0; m < MR; ++m)
#pragma unroll
          for (int n = 0; n < NR; ++n) mfma_bf16(acc[m][n], a[m], b[n]);
      }
  }
  asm volatile("s_nop 7\n\ts_nop 7" ::);
#pragma unroll
  for (int m = 0; m < MR; ++m)
#pragma unroll
    for (int n = 0; n < NR; ++n) {
      int cob = co0 + wcob + m * 16 + (l >> 4) * 4;
      int px = wposb + n * 16 + (l & 15);
#pragma unroll
      for (int r4p = 0; r4p < 2; ++r4p) {
        unsigned pk = (unsigned)f2bf(acc[m][n][2 * r4p] + bias[cob + 2 * r4p])
                    | ((unsigned)f2bf(acc[m][n][2 * r4p + 1] + bias[cob + 2 * r4p + 1]) << 16);
        yp[(size_t)((cob >> 1) + r4p) * S * S + (size_t)row0 * S + px] = pk;
      }
    }
}

// 512-thread conv3 for S=64 with LDS-staged weights: 8 waves (MR=2, NR=1),
// grid (64, 4). x_s 15.8KB + w_s 46KB = 62KB.
__global__ __launch_bounds__(512) void k_conv3v64(const unsigned* __restrict__ xp,
                                                  const short* __restrict__ wpk,
                                                  const float* __restrict__ bias,
                                                  unsigned* __restrict__ yp) {
  constexpr int S = 64;
  constexpr int MR = 2;
  __shared__ short x_s[3 * (S + 2) * PCI];
  __shared__ short w_s[9 * 64 * PCI];
  unsigned* x_s32 = (unsigned*)x_s;
  int t = threadIdx.x, l = t & 63, wv = t >> 6;
  int wcob = (wv & 1) * 32;
  int wposb = (wv >> 1) * 16;
  int row0 = blockIdx.x;
  int co0 = blockIdx.y * 64;
  int colb = t & 31, ci2b = t >> 5;
  f32x4 acc[MR];
#pragma unroll
  for (int m = 0; m < MR; ++m) { f32x4 z = {0.f, 0.f, 0.f, 0.f}; acc[m] = z; }
  for (int c0 = 0; c0 < CCH; c0 += 32) {
    int cb = c0 >> 1;
    __syncthreads();
#pragma unroll
    for (int r = 0; r < 3; ++r) {
      int gy = row0 - 1 + r;
      bool yok = (gy >= 0 && gy < S);
#pragma unroll
      for (int cbk = 0; cbk < 3; ++cbk) {
        int col = colb + cbk * 32;
        if (col < S + 2) {
          int gx = col - 1;
          bool ok = yok && (gx >= 0) && (gx < S);
          unsigned v = 0;
          if (ok)
            v = xp[(size_t)(cb + ci2b) * S * S + (size_t)gy * S + gx];
          x_s32[(r * (S + 2) + col) * (PCI / 2) + ci2b] = v;
        }
      }
    }
    for (int i = t; i < 4608; i += 512) {
      int seg8 = i & 7;
      int rowi = i >> 3;
      int tap = rowi >> 6, co = rowi & 63;
      us4 wv4 = *(const us4*)&wpk[((size_t)(tap * 256 + co0 + co) * 256) + c0 + seg8 * 4];
      *(us4*)&w_s[rowi * PCI + seg8 * 4] = wv4;
    }
    __syncthreads();
#pragma unroll
    for (int dyg = 0; dyg < 3; ++dyg)
#pragma unroll
      for (int dx = 0; dx < 3; ++dx) {
        short8 a[MR];
#pragma unroll
        for (int m = 0; m < MR; ++m)
          a[m] = *(const short8*)&w_s[((dyg * 3 + dx) * 64 + wcob + m * 16 + (l & 15)) * PCI + (l >> 4) * 8];
        short8 b = *(const short8*)&x_s[(dyg * (S + 2) + wposb + (l & 15) + dx) * PCI + (l >> 4) * 8];
#pragma unroll
        for (int m = 0; m < MR; ++m) mfma_bf16(acc[m], a[m], b);
      }
  }
  asm volatile("s_nop 7\n\ts_nop 7" ::);
#pragma unroll
  for (int m = 0; m < MR; ++m) {
    int cob = co0 + wcob + m * 16 + (l >> 4) * 4;
    int px = wposb + (l & 15);
#pragma unroll
    for (int r4p = 0; r4p < 2; ++r4p) {
      unsigned pk = (unsigned)f2bf(acc[m][2 * r4p] + bias[cob + 2 * r4p])
                  | ((unsigned)f2bf(acc[m][2 * r4p + 1] + bias[cob + 2 * r4p + 1]) << 16);
      yp[(size_t)((cob >> 1) + r4p) * S * S + (size_t)row0 * S + px] = pk;
    }
  }
}

// MFMA deconv4x4 s2 p2 + bias + relu, O input rows + both q parities per block.
// LDS-staged weights (r13 form, 256 threads). Used for S=16,32.
template <int S, int O>
__global__ __launch_bounds__(256) void k_deconvu(const unsigned* __restrict__ xp,
                                                 const short* __restrict__ wpk,
                                                 const float* __restrict__ bias,
                                                 unsigned* __restrict__ yp) {
  constexpr int WPC = (S >= 64) ? 2 : 1;
  constexpr int WCO = 4 / WPC;
  constexpr int COS = 64 / WCO;
  constexpr int MR = COS / 16;
  constexpr int PSP = S / WPC;
  constexpr int NR = PSP / 16;
  constexpr int CBK = (S + 2 + 31) / 32;
  constexpr int RS = O + 1;
  const int SO = 2 * S;
  __shared__ short x_s[RS * (S + 2) * PCI];
  __shared__ short w_s[8 * 64 * PCI];
  unsigned* x_s32 = (unsigned*)x_s;
  int t = threadIdx.x, l = t & 63, wv = t >> 6;
  int wcob = (wv % WCO) * COS;
  int wposb = (wv / WCO) * PSP;
  int row0 = blockIdx.x * O;
  int co0 = blockIdx.y * 64;
  int p = blockIdx.z;
  int colb = t & 31, ci2b = t >> 5;
  f32x4 acc[2][O][MR][NR];
#pragma unroll
  for (int q = 0; q < 2; ++q)
#pragma unroll
    for (int o = 0; o < O; ++o)
#pragma unroll
      for (int m = 0; m < MR; ++m)
#pragma unroll
        for (int n = 0; n < NR; ++n) { f32x4 z = {0.f, 0.f, 0.f, 0.f}; acc[q][o][m][n] = z; }
  for (int c0 = 0; c0 < CCH; c0 += 32) {
    int cb = c0 >> 1;
    __syncthreads();
#pragma unroll
    for (int r = 0; r < RS; ++r) {
      int gy = row0 + p - 1 + r;
      bool yok = (gy >= 0 && gy < S);
#pragma unroll
      for (int cbk = 0; cbk < CBK; ++cbk) {
        int col = colb + cbk * 32;
        if (col < S + 2) {
          int gx = col - 1;
          bool ok = yok && (gx >= 0) && (gx < S);
          unsigned v0 = 0, v1 = 0;
          if (ok) {
            size_t gbase = (size_t)(cb + ci2b) * S * S + (size_t)gy * S + gx;
            v0 = xp[gbase];
            v1 = xp[gbase + (size_t)8 * S * S];
          }
          int lb = (r * (S + 2) + col) * (PCI / 2);
          x_s32[lb + ci2b] = v0;
          x_s32[lb + ci2b + 8] = v1;
        }
      }
    }
    for (int i = t; i < 4096; i += 256) {
      int seg8 = i & 7;
      int rowi = i >> 3;
      int c8 = rowi >> 6, co = rowi & 63;
      int qq = c8 >> 2, tt = c8 & 3;
      us4 wv4 = *(const us4*)&wpk[((size_t)(((2 * p + qq) * 4 + tt) * 256 + co0 + co) * 256) + c0 + seg8 * 4];
      *(us4*)&w_s[rowi * PCI + seg8 * 4] = wv4;
    }
    __syncthreads();
#pragma unroll
    for (int dyi = 0; dyi < 2; ++dyi)
#pragma unroll
      for (int o = 0; o < O; ++o) {
        short8 b[3][NR];
#pragma unroll
        for (int off = 0; off < 3; ++off)
#pragma unroll
          for (int n = 0; n < NR; ++n)
            b[off][n] = *(const short8*)&x_s[((dyi + o) * (S + 2) + wposb + n * 16 + (l & 15) + off) * PCI + (l >> 4) * 8];
#pragma unroll
        for (int q = 0; q < 2; ++q)
#pragma unroll
          for (int dxi = 0; dxi < 2; ++dxi) {
            int c8 = q * 4 + dyi * 2 + dxi;
            short8 a[MR];
#pragma unroll
            for (int m = 0; m < MR; ++m)
              a[m] = *(const short8*)&w_s[(c8 * 64 + wcob + m * 16 + (l & 15)) * PCI + (l >> 4) * 8];
#pragma unroll
            for (int m = 0; m < MR; ++m)
#pragma unroll
              for (int n = 0; n < NR; ++n) mfma_bf16(acc[q][o][m][n], a[m], b[dxi + q][n]);
          }
      }
  }
  asm volatile("s_nop 7\n\ts_nop 7" ::);
#pragma unroll
  for (int o = 0; o < O; ++o) {
    int oy = 2 * (row0 + o) + p;
#pragma unroll
    for (int m = 0; m < MR; ++m)
#pragma unroll
      for (int n = 0; n < NR; ++n) {
        int px = wposb + n * 16 + (l & 15);
#pragma unroll
        for (int r4p = 0; r4p < 2; ++r4p) {
          int cob = co0 + wcob + m * 16 + (l >> 4) * 4 + 2 * r4p;
          float b0 = bias[cob], b1 = bias[cob + 1];
          unsigned pk0 = (unsigned)f2bf(fmaxf(acc[0][o][m][n][2 * r4p] + b0, 0.f))
                       | ((unsigned)f2bf(fmaxf(acc[0][o][m][n][2 * r4p + 1] + b1, 0.f)) << 16);
          unsigned pk1 = (unsigned)f2bf(fmaxf(acc[1][o][m][n][2 * r4p] + b0, 0.f))
                       | ((unsigned)f2bf(fmaxf(acc[1][o][m][n][2 * r4p + 1] + b1, 0.f)) << 16);
          uint2 pk = make_uint2(pk0, pk1);
          *(uint2*)&yp[(size_t)(cob >> 1) * SO * SO + (size_t)oy * SO + 2 * px] = pk;
        }
      }
  }
}

// 512-thread deconv for S=128, O=2: 8 waves/block, 2 blocks/CU.
__global__ __launch_bounds__(512) void k_deconvw(const unsigned* __restrict__ xp,
                                                 const short* __restrict__ wpk,
                                                 const float* __restrict__ bias,
                                                 unsigned* __restrict__ yp) {
  constexpr int S = 128;
  constexpr int O = 2;
  constexpr int MR = 2;
  constexpr int PSP = 32;
  constexpr int NR = 2;
  constexpr int RS = O + 1;
  const int SO = 2 * S;
  __shared__ short x_s[RS * (S + 2) * PCI];
  __shared__ short w_s[8 * 64 * PCI];
  unsigned* x_s32 = (unsigned*)x_s;
  int t = threadIdx.x, l = t & 63, wv = t >> 6;
  int wcob = (wv & 1) * 32;
  int wposb = (wv >> 1) * PSP;
  int row0 = blockIdx.x * O;
  int co0 = blockIdx.y * 64;
  int p = blockIdx.z;
  int colb = t & 31, ci2b = t >> 5;
  f32x4 acc[2][O][MR][NR];
#pragma unroll
  for (int q = 0; q < 2; ++q)
#pragma unroll
    for (int o = 0; o < O; ++o)
#pragma unroll
      for (int m = 0; m < MR; ++m)
#pragma unroll
        for (int n = 0; n < NR; ++n) { f32x4 z = {0.f, 0.f, 0.f, 0.f}; acc[q][o][m][n] = z; }
  for (int c0 = 0; c0 < CCH; c0 += 32) {
    int cb = c0 >> 1;
    __syncthreads();
#pragma unroll
    for (int r = 0; r < RS; ++r) {
      int gy = row0 + p - 1 + r;
      bool yok = (gy >= 0 && gy < S);
#pragma unroll
      for (int cbk = 0; cbk < 5; ++cbk) {
        int col = colb + cbk * 32;
        if (col < S + 2) {
          int gx = col - 1;
          bool ok = yok && (gx >= 0) && (gx < S);
          unsigned v = 0;
          if (ok)
            v = xp[(size_t)(cb + ci2b) * S * S + (size_t)gy * S + gx];
          x_s32[(r * (S + 2) + col) * (PCI / 2) + ci2b] = v;
        }
      }
    }
    for (int i = t; i < 4096; i += 512) {
      int seg8 = i & 7;
      int rowi = i >> 3;
      int c8 = rowi >> 6, co = rowi & 63;
      int qq = c8 >> 2, tt = c8 & 3;
      us4 wv4 = *(const us4*)&wpk[((size_t)(((2 * p + qq) * 4 + tt) * 256 + co0 + co) * 256) + c0 + seg8 * 4];
      *(us4*)&w_s[rowi * PCI + seg8 * 4] = wv4;
    }
    __syncthreads();
#pragma unroll
    for (int dyi = 0; dyi < 2; ++dyi)
#pragma unroll
      for (int o = 0; o < O; ++o) {
        short8 b[3][NR];
#pragma unroll
        for (int off = 0; off < 3; ++off)
#pragma unroll
          for (int n = 0; n < NR; ++n)
            b[off][n] = *(const short8*)&x_s[((dyi + o) * (S + 2) + wposb + n * 16 + (l & 15) + off) * PCI + (l >> 4) * 8];
#pragma unroll
        for (int q = 0; q < 2; ++q)
#pragma unroll
          for (int dxi = 0; dxi < 2; ++dxi) {
            int c8 = q * 4 + dyi * 2 + dxi;
            short8 a[MR];
#pragma unroll
            for (int m = 0; m < MR; ++m)
              a[m] = *(const short8*)&w_s[(c8 * 64 + wcob + m * 16 + (l & 15)) * PCI + (l >> 4) * 8];
#pragma unroll
            for (int m = 0; m < MR; ++m)
#pragma unroll
              for (int n = 0; n < NR; ++n) mfma_bf16(acc[q][o][m][n], a[m], b[dxi + q][n]);
          }
      }
  }
  asm volatile("s_nop 7\n\ts_nop 7" ::);
#pragma unroll
  for (int o = 0; o < O; ++o) {
    int oy = 2 * (row0 + o) + p;
#pragma unroll
    for (int m = 0; m < MR; ++m)
#pragma unroll
      for (int n = 0; n < NR; ++n) {
        int px = wposb + n * 16 + (l & 15);
#pragma unroll
        for (int r4p = 0; r4p < 2; ++r4p) {
          int cob = co0 + wcob + m * 16 + (l >> 4) * 4 + 2 * r4p;
          float b0 = bias[cob], b1 = bias[cob + 1];
          unsigned pk0 = (unsigned)f2bf(fmaxf(acc[0][o][m][n][2 * r4p] + b0, 0.f))
                       | ((unsigned)f2bf(fmaxf(acc[0][o][m][n][2 * r4p + 1] + b1, 0.f)) << 16);
          unsigned pk1 = (unsigned)f2bf(fmaxf(acc[1][o][m][n][2 * r4p] + b0, 0.f))
                       | ((unsigned)f2bf(fmaxf(acc[1][o][m][n][2 * r4p + 1] + b1, 0.f)) << 16);
          uint2 pk = make_uint2(pk0, pk1);
          *(uint2*)&yp[(size_t)(cob >> 1) * SO * SO + (size_t)oy * SO + 2 * px] = pk;
        }
      }
  }
}

// 512-thread deconv for S=64, O=1: 8 waves (MR=2, NR=1), grid (64,4,2).
__global__ __launch_bounds__(512) void k_deconvw64(const unsigned* __restrict__ xp,
                                                   const short* __restrict__ wpk,
                                                   const float* __restrict__ bias,
                                                   unsigned* __restrict__ yp) {
  constexpr int S = 64;
  constexpr int MR = 2;
  const int SO = 2 * S;
  __shared__ short x_s[2 * (S + 2) * PCI];
  __shared__ short w_s[8 * 64 * PCI];
  unsigned* x_s32 = (unsigned*)x_s;
  int t = threadIdx.x, l = t & 63, wv = t >> 6;
  int wcob = (wv & 1) * 32;
  int wposb = (wv >> 1) * 16;
  int row0 = blockIdx.x;
  int co0 = blockIdx.y * 64;
  int p = blockIdx.z;
  int colb = t & 31, ci2b = t >> 5;
  f32x4 acc[2][MR];   // [q][m]
#pragma unroll
  for (int q = 0; q < 2; ++q)
#pragma unroll
    for (int m = 0; m < MR; ++m) { f32x4 z = {0.f, 0.f, 0.f, 0.f}; acc[q][m] = z; }
  for (int c0 = 0; c0 < CCH; c0 += 32) {
    int cb = c0 >> 1;
    __syncthreads();
#pragma unroll
    for (int r = 0; r < 2; ++r) {
      int gy = row0 + p - 1 + r;
      bool yok = (gy >= 0 && gy < S);
#pragma unroll
      for (int cbk = 0; cbk < 3; ++cbk) {
        int col = colb + cbk * 32;
        if (col < S + 2) {
          int gx = col - 1;
          bool ok = yok && (gx >= 0) && (gx < S);
          unsigned v = 0;
          if (ok)
            v = xp[(size_t)(cb + ci2b) * S * S + (size_t)gy * S + gx];
          x_s32[(r * (S + 2) + col) * (PCI / 2) + ci2b] = v;
        }
      }
    }
    for (int i = t; i < 4096; i += 512) {
      int seg8 = i & 7;
      int rowi = i >> 3;
      int c8 = rowi >> 6, co = rowi & 63;
      int qq = c8 >> 2, tt = c8 & 3;
      us4 wv4 = *(const us4*)&wpk[((size_t)(((2 * p + qq) * 4 + tt) * 256 + co0 + co) * 256) + c0 + seg8 * 4];
      *(us4*)&w_s[rowi * PCI + seg8 * 4] = wv4;
    }
    __syncthreads();
#pragma unroll
    for (int dyi = 0; dyi < 2; ++dyi) {
      short8 b[3];
#pragma unroll
      for (int off = 0; off < 3; ++off)
        b[off] = *(const short8*)&x_s[(dyi * (S + 2) + wposb + (l & 15) + off) * PCI + (l >> 4) * 8];
#pragma unroll
      for (int q = 0; q < 2; ++q)
#pragma unroll
        for (int dxi = 0; dxi < 2; ++dxi) {
          int c8 = q * 4 + dyi * 2 + dxi;
          short8 a[MR];
#pragma unroll
          for (int m = 0; m < MR; ++m)
            a[m] = *(const short8*)&w_s[(c8 * 64 + wcob + m * 16 + (l & 15)) * PCI + (l >> 4) * 8];
#pragma unroll
          for (int m = 0; m < MR; ++m) mfma_bf16(acc[q][m], a[m], b[dxi + q]);
        }
    }
  }
  asm volatile("s_nop 7\n\ts_nop 7" ::);
  int oy = 2 * row0 + p;
#pragma unroll
  for (int m = 0; m < MR; ++m) {
    int px = wposb + (l & 15);
#pragma unroll
    for (int r4p = 0; r4p < 2; ++r4p) {
      int cob = co0 + wcob + m * 16 + (l >> 4) * 4 + 2 * r4p;
      float b0 = bias[cob], b1 = bias[cob + 1];
      unsigned pk0 = (unsigned)f2bf(fmaxf(acc[0][m][2 * r4p] + b0, 0.f))
                   | ((unsigned)f2bf(fmaxf(acc[0][m][2 * r4p + 1] + b1, 0.f)) << 16);
      unsigned pk1 = (unsigned)f2bf(fmaxf(acc[1][m][2 * r4p] + b0, 0.f))
                   | ((unsigned)f2bf(fmaxf(acc[1][m][2 * r4p + 1] + b1, 0.f)) << 16);
      uint2 pk = make_uint2(pk0, pk1);
      *(uint2*)&yp[(size_t)(cob >> 1) * SO * SO + (size_t)oy * SO + 2 * px] = pk;
    }
  }
}

// sparse final conv3 via MFMA -> bf16 srows
__global__ __launch_bounds__(256) void k_conv3sM(const unsigned* __restrict__ xp,
                                                 const short* __restrict__ wB,
                                                 const float* __restrict__ bias,
                                                 const int* __restrict__ idx,
                                                 short* __restrict__ outb) {
  __shared__ short a_s[16][296];
  __shared__ int py_s[16], px_s[16];
  int t = threadIdx.x, l = t & 63, wv = t >> 6;
  int j0 = blockIdx.x * 16;
  int co0 = blockIdx.y * 128 + wv * 32;
  if (t < 16) {
    int p = idx[j0 + t];
    py_s[t] = p >> 8;
    px_s[t] = p & 255;
  }
  f32x4 acc[2];
  { f32x4 z = {0.f, 0.f, 0.f, 0.f}; acc[0] = z; acc[1] = z; }
  for (int c = 0; c < 8; ++c) {
    __syncthreads();
    for (int i = t; i < 2304; i += 256) {
      int ci2 = i & 15;
      int je = i >> 4;
      int j = je / 9, e = je % 9;
      int gy = py_s[j] - 1 + e / 3, gx = px_s[j] - 1 + e % 3;
      unsigned v = 0;
      if (gy >= 0 && gy < 256 && gx >= 0 && gx < 256)
        v = xp[(size_t)(c * 16 + ci2) * HWP + gy * 256 + gx];
      *(unsigned*)&a_s[j][e * 32 + 2 * ci2] = v;
    }
    __syncthreads();
#pragma unroll
    for (int s = 0; s < 9; ++s) {
      short8 a = *(const short8*)&a_s[l & 15][s * 32 + (l >> 4) * 8];
      int kg = c * 288 + s * 32 + (l >> 4) * 8;
      short8 b0 = *(const short8*)&wB[(size_t)(co0 + (l & 15)) * 2304 + kg];
      short8 b1 = *(const short8*)&wB[(size_t)(co0 + 16 + (l & 15)) * 2304 + kg];
      mfma_bf16(acc[0], a, b0);
      mfma_bf16(acc[1], a, b1);
    }
  }
  asm volatile("s_nop 7\n\ts_nop 7" ::);
#pragma unroll
  for (int n = 0; n < 2; ++n)
#pragma unroll
    for (int r = 0; r < 4; ++r) {
      int j = j0 + (l >> 4) * 4 + r;
      int co = co0 + n * 16 + (l & 15);
      outb[(size_t)j * 256 + co] = (short)f2bf(acc[n][r] + bias[co]);
    }
}

// MFMA in-projection: grid (128 j-tiles, 12 out-tiles of 64). 0-3=Q, 4-7=K, 8-11=V.
__global__ __launch_bounds__(256) void k_qkv3(const short* __restrict__ dq,
                                              const short* __restrict__ sr,
                                              const short* __restrict__ wBi,
                                              const float* __restrict__ bias,
                                              short* __restrict__ Qb,
                                              short* __restrict__ Kb,
                                              short* __restrict__ Vt) {
  __shared__ short a_s[16 * 264];
  unsigned* a_s32 = (unsigned*)a_s;
  int t = threadIdx.x, l = t & 63, wv = t >> 6;
  int j0 = blockIdx.x * 16;
  int third = blockIdx.y >> 2;
  const unsigned* s32 = (const unsigned*)(third ? sr : dq);
  for (int i = t; i < 2048; i += 256) {
    int row = i >> 7, c2 = i & 127;
    a_s32[row * 132 + c2] = s32[(size_t)(j0 + row) * 128 + c2];
  }
  __syncthreads();
  int cog = blockIdx.y * 64 + wv * 16 + (l & 15);
  f32x4 acc = {0.f, 0.f, 0.f, 0.f};
  const short* brow = wBi + (size_t)cog * 256 + (l >> 4) * 8;
  const short* arow = a_s + (l & 15) * 264 + (l >> 4) * 8;
#pragma unroll
  for (int kc = 0; kc < 8; ++kc) {
    short8 a = *(const short8*)(arow + kc * 32);
    short8 b = *(const short8*)(brow + kc * 32);
    mfma_bf16(acc, a, b);
  }
  asm volatile("s_nop 7\n\ts_nop 7" ::);
  float bv = bias[cog];
  int co = cog & 255;
  int h = co >> 5, d = co & 31;
#pragma unroll
  for (int r = 0; r < 4; ++r) {
    int j = j0 + (l >> 4) * 4 + r;
    short v = (short)f2bf(acc[r] + bv);
    if (third == 0)      Qb[((size_t)h * 2048 + j) * 32 + d] = v;
    else if (third == 1) Kb[((size_t)h * 2048 + j) * 32 + d] = v;
    else                 Vt[((size_t)h * 32 + d) * 2048 + j] = v;
  }
}

// fused flash attention. grid (32 qtiles, 8 h), 4 waves. Writes bf16 Ob.
__global__ __launch_bounds__(256) void k_fattn(const short* __restrict__ Qb,
                                               const short* __restrict__ Kb,
                                               const short* __restrict__ Vt,
                                               short* __restrict__ Ob) {
  __shared__ short P_lds[4][16][136];
  int t = threadIdx.x, l = t & 63, wv = t >> 6;
  int h = blockIdx.y;
  int q0 = blockIdx.x * 64 + wv * 16;
  const short* Qh = Qb + (size_t)h * 2048 * 32;
  const short* Kh = Kb + (size_t)h * 2048 * 32;
  const short* Vh = Vt + (size_t)h * 32 * 2048;
  short8 a_q = *(const short8*)&Qh[(size_t)(q0 + (l & 15)) * 32 + (l >> 4) * 8];
  f32x4 o0 = {0.f, 0.f, 0.f, 0.f}, o1 = {0.f, 0.f, 0.f, 0.f};
  float m_run[4], l_run[4];
#pragma unroll
  for (int r = 0; r < 4; ++r) { m_run[r] = -3e38f; l_run[r] = 0.f; }
  const float scale = 0.17677669529663687f;
  for (int k0 = 0; k0 < 2048; k0 += 128) {
    f32x4 s[8];
#pragma unroll
    for (int kt = 0; kt < 8; ++kt) {
      f32x4 z = {0.f, 0.f, 0.f, 0.f};
      s[kt] = z;
      short8 b = *(const short8*)&Kh[(size_t)(k0 + kt * 16 + (l & 15)) * 32 + (l >> 4) * 8];
      mfma_bf16(s[kt], a_q, b);
    }
    asm volatile("s_nop 7\n\ts_nop 7" ::);
    float tm[4];
#pragma unroll
    for (int r = 0; r < 4; ++r) {
      float mx = s[0][r];
#pragma unroll
      for (int kt = 1; kt < 8; ++kt) mx = fmaxf(mx, s[kt][r]);
      tm[r] = mx * scale;
    }
#pragma unroll
    for (int mask = 1; mask < 16; mask <<= 1)
#pragma unroll
      for (int r = 0; r < 4; ++r) tm[r] = fmaxf(tm[r], __shfl_xor(tm[r], mask));
    float mn[4], al[4], rs[4];
#pragma unroll
    for (int r = 0; r < 4; ++r) {
      mn[r] = fmaxf(m_run[r], tm[r]);
      al[r] = __expf(m_run[r] - mn[r]);
      rs[r] = 0.f;
    }
#pragma unroll
    for (int kt = 0; kt < 8; ++kt)
#pragma unroll
      for (int r = 0; r < 4; ++r) {
        float pv = __expf(s[kt][r] * scale - mn[r]);
        s[kt][r] = pv;
        rs[r] += pv;
      }
#pragma unroll
    for (int mask = 1; mask < 16; mask <<= 1)
#pragma unroll
      for (int r = 0; r < 4; ++r) rs[r] += __shfl_xor(rs[r], mask);
#pragma unroll
    for (int r = 0; r < 4; ++r) {
      l_run[r] = l_run[r] * al[r] + rs[r];
      m_run[r] = mn[r];
      o0[r] *= al[r];
      o1[r] *= al[r];
    }
#pragma unroll
    for (int kt = 0; kt < 8; ++kt)
#pragma unroll
      for (int r = 0; r < 4; ++r)
        P_lds[wv][(l >> 4) * 4 + r][kt * 16 + (l & 15)] = (short)f2bf(s[kt][r]);
#pragma unroll
    for (int kc = 0; kc < 4; ++kc) {
      short8 ap = *(const short8*)&P_lds[wv][l & 15][kc * 32 + (l >> 4) * 8];
      short8 b0 = *(const short8*)&Vh[(size_t)(l & 15) * 2048 + k0 + kc * 32 + (l >> 4) * 8];
      short8 b1 = *(const short8*)&Vh[(size_t)(16 + (l & 15)) * 2048 + k0 + kc * 32 + (l >> 4) * 8];
      mfma_bf16(o0, ap, b0);
      mfma_bf16(o1, ap, b1);
    }
  }
  asm volatile("s_nop 7\n\ts_nop 7" ::);
#pragma unroll
  for (int r = 0; r < 4; ++r) {
    float inv = 1.f / l_run[r];
    int qr = q0 + (l >> 4) * 4 + r;
    Ob[(size_t)qr * 256 + h * 32 + (l & 15)] = (short)f2bf(o0[r] * inv);
    Ob[(size_t)qr * 256 + h * 32 + 16 + (l & 15)] = (short)f2bf(o1[r] * inv);
  }
}

// MFMA out-projection + scatter. grid (128 j-tiles, 4 co-tiles of 64).
__global__ __launch_bounds__(256) void k_outprojM(const short* __restrict__ Ob,
                                                  const short* __restrict__ wBo,
                                                  const float* __restrict__ ob,
                                                  const int* __restrict__ idx,
                                                  float* __restrict__ out) {
  __shared__ short a_s[16 * 264];
  __shared__ int jp[16];
  unsigned* a_s32 = (unsigned*)a_s;
  const unsigned* s32 = (const unsigned*)Ob;
  int t = threadIdx.x, l = t & 63, wv = t >> 6;
  int j0 = blockIdx.x * 16;
  if (t < 16) jp[t] = idx[j0 + t];
  for (int i = t; i < 2048; i += 256) {
    int row = i >> 7, c2 = i & 127;
    a_s32[row * 132 + c2] = s32[(size_t)(j0 + row) * 128 + c2];
  }
  __syncthreads();
  int co = blockIdx.y * 64 + wv * 16 + (l & 15);
  f32x4 acc = {0.f, 0.f, 0.f, 0.f};
  const short* brow = wBo + (size_t)co * 256 + (l >> 4) * 8;
  const short* arow = a_s + (l & 15) * 264 + (l >> 4) * 8;
#pragma unroll
  for (int kc = 0; kc < 8; ++kc) {
    short8 a = *(const short8*)(arow + kc * 32);
    short8 b = *(const short8*)(brow + kc * 32);
    mfma_bf16(acc, a, b);
  }
  asm volatile("s_nop 7\n\ts_nop 7" ::);
  float bv = ob[co];
#pragma unroll
  for (int r = 0; r < 4; ++r) {
    int jl = (l >> 4) * 4 + r;
    out[(size_t)co * HWP + jp[jl]] = acc[r] + bv;
  }
}

extern "C" void kernel_launch(void* const* d_in, const int* in_sizes, int n_in,
                              void* d_out, int out_size, void* d_ws, size_t ws_size,
                              hipStream_t stream) {
  const float* down  = (const float*)d_in[0];
  const float* swint = (const float*)d_in[1];
  const float* wt_w  = (const float*)d_in[2];
  const float* wt_b  = (const float*)d_in[3];
  const float* up_dw = (const float*)d_in[4];
  const float* up_db = (const float*)d_in[5];
  const float* up_cw = (const float*)d_in[6];
  const float* up_cb = (const float*)d_in[7];
  const float* gate_w = (const float*)d_in[8];
  const float* in_w  = (const float*)d_in[10];
  const float* in_b  = (const float*)d_in[11];
  const float* out_w = (const float*)d_in[12];
  const float* out_b = (const float*)d_in[13];
  float* out = (float*)d_out;
  char* ws = (char*)d_ws;

  unsigned* actA = (unsigned*)ws;
  unsigned* actB = (unsigned*)(ws + BUF_B_OFF);
  unsigned int* keys = (unsigned int*)(ws + KEYS_OFF);
  int* idx = (int*)(ws + IDX_OFF);
  int* eq = (int*)(ws + EQ_OFF);
  short* Ob = (short*)(ws + OB_OFF);
  short* wBi = (short*)(ws + WBI_OFF);
  short* wBo = (short*)(ws + WBO_OFF);
  short* srowsb = (short*)(ws + SROWS_OFF);
  short* dq = (short*)(ws + DQ_OFF);
  float* gpart = (float*)(ws + GPART_OFF);
  short* wB5 = (short*)(ws + WT5_OFF);
  short* Qb = (short*)(ws + QB_OFF);
  short* Kb = (short*)(ws + KB_OFF);
  short* Vt = (short*)(ws + VT_OFF);
  short* cpk = (short*)(ws + CPK_OFF);
  short* dpk = (short*)(ws + DPK_OFF);
  short* wBt = (short*)(ws + WTW_OFF);
  float* wpart = (float*)(ws + WPART_OFF);
  short* xq0 = (short*)(ws + XQ0_OFF);

  // gate partials + passthrough copy, keys, single-block exact top-k, gather
  k_gatecopy2<<<dim3(256, 8), 256, 0, stream>>>(down, gate_w, out, gpart);
  k_gkey<<<256, 256, 0, stream>>>(gpart, keys);
  k_select1<<<1, 1024, 0, stream>>>(keys, idx, eq);
  k_gatherq<<<2048, 256, 0, stream>>>(down, idx, dq);

  // all weight packs in one launch (conv3 x4, deconv x5, conv5, in_w, out_w, wt_w)
  k_packall<<<3840, 256, 0, stream>>>(up_cw, up_dw, in_w, out_w, wt_w,
                                      cpk, dpk, wB5, wBi, wBo, wBt);

  // stage 0: K-split MFMA 1x1 conv (parallel weight fetch) + reduce, then deconv 8->16
  k_wtconvP<<<dim3(4, 8), 256, 0, stream>>>(swint, wBt, wpart);
  k_wtred<<<64, 256, 0, stream>>>(wpart, wt_b, xq0);
  k_deconv8M<<<dim3(4, 4), 256, 0, stream>>>(xq0, dpk, up_db, actB);

  // upsampler chain: MFMA bf16 implicit-GEMM, packed-bf16 activations (A/B ping-pong)
  k_conv3u<16, 2><<<dim3(8, 4), 256, 0, stream>>>(actB, cpk, up_cb, actA);
  k_deconvu<16, 2><<<dim3(8, 4, 2), 256, 0, stream>>>(actA, dpk + 1048576, up_db + 256, actB);
  k_conv3u<32, 2><<<dim3(16, 4), 256, 0, stream>>>(actB, cpk + 589824, up_cb + 256, actA);
  k_deconvu<32, 2><<<dim3(16, 4, 2), 256, 0, stream>>>(actA, dpk + 2 * 1048576, up_db + 512, actB);
  k_conv3v64<<<dim3(64, 4), 512, 0, stream>>>(actB, cpk + 2 * 589824, up_cb + 512, actA);
  k_deconvw64<<<dim3(64, 4, 2), 512, 0, stream>>>(actA, dpk + 3 * 1048576, up_db + 768, actB);
  k_conv3v<<<dim3(128, 4), 512, 0, stream>>>(actB, cpk + 3 * 589824, up_cb + 768, actA);
  k_deconvw<<<dim3(64, 4, 2), 512, 0, stream>>>(actA, dpk + 4 * 1048576, up_db + 1024, actB);

  // final conv3 via MFMA at the 2048 gathered positions -> bf16 srows
  k_conv3sM<<<dim3(128, 2), 256, 0, stream>>>(actB, wB5, up_cb + 1024, idx, srowsb);

  // attention path: MFMA in-projection, fused flash attention, MFMA out-projection
  k_qkv3<<<dim3(128, 12), 256, 0, stream>>>(dq, srowsb, wBi, in_b, Qb, Kb, Vt);
  k_fattn<<<dim3(32, 8), 256, 0, stream>>>(Qb, Kb, Vt, Ob);
  k_outprojM<<<dim3(128, 4), 256, 0, stream>>>(Ob, wBo, out_b, idx, out);
}

// Round 25
// 615.146 us; speedup vs baseline: 1.4128x; 1.0192x over previous
//
#include <hip/hip_runtime.h>
#include <math.h>

#define CCH 256
#define HWP 65536
#define PCI 40   // padded ci stride (shorts) in LDS

typedef short short8 __attribute__((ext_vector_type(8)));
typedef float f32x4 __attribute__((ext_vector_type(4)));
typedef unsigned short us4 __attribute__((ext_vector_type(4)));

__device__ inline unsigned short f2bf(float f) {
  unsigned u = __float_as_uint(f);
  return (unsigned short)((u + 0x7FFFu + ((u >> 16) & 1u)) >> 16);
}
__device__ inline float bf2f(unsigned short s) {
  return __uint_as_float(((unsigned)s) << 16);
}

__device__ inline void mfma_bf16(f32x4& d, short8 a, short8 b) {
  asm volatile("v_mfma_f32_16x16x32_bf16 %0, %1, %2, %0" : "+v"(d) : "v"(a), "v"(b));
}

// ---- ws layout (bytes) ----
static const size_t BUF_B_OFF = 67108864;        // actA @0, actB @64MB
static const size_t TAIL_OFF  = 134217728;
static const size_t KEYS_OFF  = TAIL_OFF;
static const size_t HIST_OFF  = TAIL_OFF + 262144;
static const size_t IDX_OFF   = TAIL_OFF + 263424;
static const size_t EQ_OFF    = TAIL_OFF + 271616;
static const size_t OB_OFF    = 6291456;
static const size_t WBI_OFF   = 8388608;
static const size_t WBO_OFF   = 9437184;
static const size_t SROWS_OFF = 10485760;
static const size_t DQ_OFF    = 12582912;
static const size_t GPART_OFF = 16777216;
static const size_t WT5_OFF   = 20971520;
static const size_t QB_OFF    = 31457280;
static const size_t KB_OFF    = 32505856;
static const size_t VT_OFF    = 33554432;
static const size_t CPK_OFF   = 37748736;
static const size_t DPK_OFF   = 44040192;        // 5 layers x 1048576 shorts -> ends 54525952
static const size_t WTW_OFF   = 54525952;        // bf16 wt_w [256][768] 384KB
static const size_t WPART_OFF = 55050240;        // f32 partials [8][64][256] 512KB
static const size_t XQ0_OFF   = 57671680;        // bf16 stage0 x [64][256]

// merged weight packing: conv3 x4, deconv x5, conv5, in_w, out_w, wt_w
__global__ void k_packall(const float* __restrict__ up_cw, const float* __restrict__ up_dw,
                          const float* __restrict__ in_w, const float* __restrict__ out_w,
                          const float* __restrict__ wt_w,
                          short* __restrict__ cpk, short* __restrict__ dpk,
                          short* __restrict__ wB5, short* __restrict__ wBi,
                          short* __restrict__ wBo, short* __restrict__ wBt) {
  int b = blockIdx.x;
  int tid = threadIdx.x;
  if (b < 1024) {
    int layer = b >> 8, co = b & 255, ci = tid;
    const float* wl = up_cw + (size_t)layer * 589824;
    short* wo = cpk + (size_t)layer * 589824;
    for (int tap = 0; tap < 9; ++tap)
      wo[((size_t)(tap * 256 + co) * 256) + ci] = (short)f2bf(wl[((size_t)(co * 256 + ci)) * 9 + tap]);
  } else if (b < 2304) {
    int bb = b - 1024;
    int layer = bb >> 8, co = bb & 255, ci = tid;
    const float* wl = up_dw + (size_t)layer * 1048576;
    for (int pq = 0; pq < 4; ++pq) {
      int p = pq >> 1, q = pq & 1;
      for (int tt = 0; tt < 4; ++tt) {
        int dyi = tt >> 1, dxi = tt & 1;
        int wr = dyi ? (1 - p) : (3 - p);
        int wc = dxi ? (1 - q) : (3 - q);
        dpk[((size_t)layer * 1048576) + ((size_t)((pq * 4 + tt) * 256 + co) * 256) + ci] =
            (short)f2bf(wl[((size_t)(ci * 256 + co)) * 16 + wr * 4 + wc]);
      }
    }
  } else if (b < 2560) {
    int co = b - 2304;
    const float* w5 = up_cw + 2359296;
    for (int kk = tid; kk < 2304; kk += 256) {
      int c = kk / 288, r = kk % 288;
      int e = r >> 5, cl = r & 31;
      wB5[(size_t)co * 2304 + kk] = (short)f2bf(w5[(size_t)co * 2304 + (size_t)(c * 32 + cl) * 9 + e]);
    }
  } else if (b < 3328) {
    int o = b - 2560;
    wBi[(size_t)o * 256 + tid] = (short)f2bf(in_w[(size_t)o * 256 + tid]);
  } else if (b < 3584) {
    int o = b - 3328;
    wBo[(size_t)o * 256 + tid] = (short)f2bf(out_w[(size_t)o * 256 + tid]);
  } else {
    int co = b - 3584;
    for (int kk = tid; kk < 768; kk += 256)
      wBt[(size_t)co * 768 + kk] = (short)f2bf(wt_w[(size_t)co * 768 + kk]);
  }
}

// gate partials + passthrough copy; block (0,0) zeroes the r0 histogram.
__global__ void k_gatecopy2(const float* __restrict__ down, const float* __restrict__ gw,
                            float* __restrict__ out, float* __restrict__ gpart,
                            unsigned* __restrict__ hist) {
  if (blockIdx.x == 0 && blockIdx.y == 0) hist[threadIdx.x] = 0;
  int p = blockIdx.x * 256 + threadIdx.x;
  int cc = blockIdx.y;
  float acc = 0.f;
  for (int c = cc * 32; c < cc * 32 + 32; ++c) {
    float v = down[(size_t)c * HWP + p];
    out[(size_t)c * HWP + p] = v;
    acc += v * gw[c];
  }
  gpart[(size_t)cc * HWP + p] = acc;
}

// deterministic key reduce + fused round-0 histogram (per-block LDS, 256 blocks)
__global__ void k_gkey(const float* __restrict__ gpart, unsigned* __restrict__ keys,
                       unsigned* __restrict__ hist) {
  __shared__ unsigned lh[256];
  int t = threadIdx.x;
  lh[t] = 0;
  int p = blockIdx.x * 256 + t;
  float s = 0.f;
  for (int cc = 0; cc < 8; ++cc) s += gpart[(size_t)cc * HWP + p];
  unsigned u = __float_as_uint(s);
  unsigned key = (u & 0x80000000u) ? ~u : (u | 0x80000000u);
  keys[p] = key;
  __syncthreads();
  atomicAdd(&lh[key >> 24], 1u);
  __syncthreads();
  if (lh[t]) atomicAdd(&hist[t], lh[t]);
}

// single-block top-k finish: r0 scan from precomputed hist, rounds 1-3 (filtered,
// low-contention), compact, finalize. 1024 threads, 64 keys/thread in registers.
__global__ __launch_bounds__(1024) void k_select1b(const unsigned* __restrict__ keys,
                                                   const unsigned* __restrict__ hist,
                                                   int* __restrict__ idx,
                                                   int* __restrict__ eq) {
  __shared__ unsigned lh[256];
  __shared__ unsigned sP;
  __shared__ int skneed, snG, snE;
  int t = threadIdx.x;
  unsigned key[64];
#pragma unroll
  for (int i = 0; i < 64; ++i) key[i] = keys[i * 1024 + t];
  if (t < 256) lh[t] = hist[t];
  if (t == 0) { snG = 0; snE = 0; }
  __syncthreads();
  if (t == 0) {
    int need = 2048;
    unsigned cum = 0;
    for (int b = 255; b >= 0; --b) {
      unsigned h = lh[b];
      if (cum + h >= (unsigned)need) {
        sP = (unsigned)b;
        skneed = need - (int)cum;
        break;
      }
      cum += h;
    }
  }
  __syncthreads();
  for (int r = 1; r < 4; ++r) {
    if (t < 256) lh[t] = 0;
    __syncthreads();
    unsigned P = sP;
#pragma unroll
    for (int i = 0; i < 64; ++i) {
      if ((key[i] >> (32 - 8 * r)) == P)
        atomicAdd(&lh[(key[i] >> (24 - 8 * r)) & 255u], 1u);
    }
    __syncthreads();
    if (t == 0) {
      int need = skneed;
      unsigned cum = 0;
      for (int b = 255; b >= 0; --b) {
        unsigned h = lh[b];
        if (cum + h >= (unsigned)need) {
          sP = (sP << 8) | (unsigned)b;
          skneed = need - (int)cum;
          break;
        }
        cum += h;
      }
    }
    __syncthreads();
  }
  // compact (set-equivalent; idx order arbitrary, scatter permutation-invariant)
  {
    unsigned P = sP;
#pragma unroll
    for (int i = 0; i < 64; ++i) {
      int p = i * 1024 + t;
      if (key[i] > P) {
        int pos = atomicAdd(&snG, 1);
        idx[pos] = p;
      } else if (key[i] == P) {
        int e = atomicAdd(&snE, 1);
        if (e < 4096) eq[e] = p;
      }
    }
  }
  __syncthreads();
  if (t == 0) {
    int n = snE;
    if (n > 4096) n = 4096;
    for (int i = 1; i < n; ++i) {
      int v = eq[i], j = i - 1;
      while (j >= 0 && eq[j] > v) { eq[j + 1] = eq[j]; --j; }
      eq[j + 1] = v;
    }
    int g = snG;
    for (int i = 0; i < skneed; ++i) idx[g + i] = eq[i];
  }
}

// gather down rows at idx -> bf16 dq[2048][256]
__global__ void k_gatherq(const float* __restrict__ down, const int* __restrict__ idx,
                          short* __restrict__ dq) {
  int j = blockIdx.x, c = threadIdx.x;
  int p = idx[j];
  dq[(size_t)j * 256 + c] = (short)f2bf(down[(size_t)c * HWP + p]);
}

// K-split MFMA 1x1 conv 768->256: grid (4 co-tiles, 8 ksplits). f32 partials out.
__global__ __launch_bounds__(256) void k_wtconvP(const float* __restrict__ swint,
                                                 const short* __restrict__ wBt,
                                                 float* __restrict__ wpart) {
  __shared__ short x_s[64 * 40];
  int t = threadIdx.x, l = t & 63, wv = t >> 6;
  int co0 = blockIdx.x * 64;
  int ks = blockIdx.y;
  int kbase = ks * 96;
  f32x4 acc[4];
#pragma unroll
  for (int m = 0; m < 4; ++m) { f32x4 z = {0.f, 0.f, 0.f, 0.f}; acc[m] = z; }
#pragma unroll
  for (int cc = 0; cc < 3; ++cc) {
    int c0 = kbase + cc * 32;
    __syncthreads();
    {
      int ci = t >> 3, pos0 = (t & 7) * 8;
      const float* sp = swint + (size_t)(c0 + ci) * 64 + pos0;
#pragma unroll
      for (int pp = 0; pp < 8; ++pp)
        x_s[(pos0 + pp) * 40 + ci] = (short)f2bf(sp[pp]);
    }
    __syncthreads();
    short8 bfrag = *(const short8*)&x_s[(wv * 16 + (l & 15)) * 40 + (l >> 4) * 8];
#pragma unroll
    for (int m = 0; m < 4; ++m) {
      short8 af = *(const short8*)&wBt[(size_t)(co0 + m * 16 + (l & 15)) * 768 + c0 + (l >> 4) * 8];
      mfma_bf16(acc[m], af, bfrag);
    }
  }
  asm volatile("s_nop 7\n\ts_nop 7" ::);
  int pos = wv * 16 + (l & 15);
#pragma unroll
  for (int m = 0; m < 4; ++m)
#pragma unroll
    for (int r = 0; r < 4; ++r) {
      int co = co0 + m * 16 + (l >> 4) * 4 + r;
      wpart[((size_t)ks * 64 + pos) * 256 + co] = acc[m][r];
    }
}

// deterministic reduce of 8 K-split partials + bias -> bf16 xq0[pos][co]
__global__ void k_wtred(const float* __restrict__ wpart, const float* __restrict__ bias,
                        short* __restrict__ xq0) {
  int pos = blockIdx.x, co = threadIdx.x;
  float s = bias[co];
  for (int ks = 0; ks < 8; ++ks) s += wpart[((size_t)ks * 64 + pos) * 256 + co];
  xq0[(size_t)pos * 256 + co] = (short)f2bf(s);
}

// MFMA deconv 8->16 (stage 0) + bias + relu. grid (4 co-tiles, 4 pq). Packed out.
__global__ __launch_bounds__(256) void k_deconv8M(const short* __restrict__ xq0,
                                                  const short* __restrict__ wpk,
                                                  const float* __restrict__ bias,
                                                  unsigned* __restrict__ yp) {
  __shared__ short x_s[121 * 260];
  int t = threadIdx.x, l = t & 63, wv = t >> 6;
  int co0 = blockIdx.x * 64;
  int pq = blockIdx.y, p = pq >> 1, q = pq & 1;
  const unsigned* xs32 = (const unsigned*)xq0;
  for (int i = t; i < 121 * 128; i += 256) {
    int row = i >> 7, c2 = i & 127;
    int iy = row / 11 - 1, ix = row % 11 - 1;
    unsigned v = 0;
    if (iy >= 0 && iy < 8 && ix >= 0 && ix < 8)
      v = xs32[(size_t)(iy * 8 + ix) * 128 + c2];
    *(unsigned*)&x_s[row * 260 + 2 * c2] = v;
  }
  __syncthreads();
  f32x4 acc[4];
#pragma unroll
  for (int m = 0; m < 4; ++m) { f32x4 z = {0.f, 0.f, 0.f, 0.f}; acc[m] = z; }
  int pos = wv * 16 + (l & 15);
  int ay = pos >> 3, bx = pos & 7;
#pragma unroll
  for (int tt = 0; tt < 4; ++tt) {
    int dyi = tt >> 1, dxi = tt & 1;
    int rowx = (ay + p + dyi) * 11 + (bx + q + dxi);
#pragma unroll
    for (int c0 = 0; c0 < 256; c0 += 32) {
      short8 bfrag = *(const short8*)&x_s[rowx * 260 + c0 + (l >> 4) * 8];
#pragma unroll
      for (int m = 0; m < 4; ++m) {
        short8 af = *(const short8*)&wpk[((size_t)((pq * 4 + tt) * 256 + co0 + m * 16 + (l & 15)) * 256) + c0 + (l >> 4) * 8];
        mfma_bf16(acc[m], af, bfrag);
      }
    }
  }
  asm volatile("s_nop 7\n\ts_nop 7" ::);
  int oy = 2 * ay + p, ox = 2 * bx + q;
#pragma unroll
  for (int m = 0; m < 4; ++m)
#pragma unroll
    for (int r4p = 0; r4p < 2; ++r4p) {
      int cob = co0 + m * 16 + (l >> 4) * 4 + 2 * r4p;
      unsigned pk = (unsigned)f2bf(fmaxf(acc[m][2 * r4p] + bias[cob], 0.f))
                  | ((unsigned)f2bf(fmaxf(acc[m][2 * r4p + 1] + bias[cob + 1], 0.f)) << 16);
      yp[(size_t)(cob >> 1) * 256 + oy * 16 + ox] = pk;
    }
}

// MFMA conv3x3 pad1 + bias, O output rows per block. Weights direct-from-global.
template <int S, int O>
__global__ __launch_bounds__(256) void k_conv3u(const unsigned* __restrict__ xp,
                                                const short* __restrict__ wpk,
                                                const float* __restrict__ bias,
                                                unsigned* __restrict__ yp) {
  constexpr int WPC = (S >= 64) ? 2 : 1;
  constexpr int WCO = 4 / WPC;
  constexpr int COS = 64 / WCO;
  constexpr int MR = COS / 16;
  constexpr int PSP = S / WPC;
  constexpr int NR = PSP / 16;
  constexpr int CBK = (S + 2 + 31) / 32;
  constexpr int RS = O + 2;
  __shared__ short x_s[RS * (S + 2) * PCI];
  unsigned* x_s32 = (unsigned*)x_s;
  int t = threadIdx.x, l = t & 63, wv = t >> 6;
  int wcob = (wv % WCO) * COS;
  int wposb = (wv / WCO) * PSP;
  int row0 = blockIdx.x * O;
  int co0 = blockIdx.y * 64;
  int colb = t & 31, ci2b = t >> 5;
  f32x4 acc[O][MR][NR];
#pragma unroll
  for (int o = 0; o < O; ++o)
#pragma unroll
    for (int m = 0; m < MR; ++m)
#pragma unroll
      for (int n = 0; n < NR; ++n) { f32x4 z = {0.f, 0.f, 0.f, 0.f}; acc[o][m][n] = z; }
  for (int c0 = 0; c0 < CCH; c0 += 32) {
    int cb = c0 >> 1;
    __syncthreads();
#pragma unroll
    for (int r = 0; r < RS; ++r) {
      int gy = row0 - 1 + r;
      bool yok = (gy >= 0 && gy < S);
#pragma unroll
      for (int cbk = 0; cbk < CBK; ++cbk) {
        int col = colb + cbk * 32;
        if (col < S + 2) {
          int gx = col - 1;
          bool ok = yok && (gx >= 0) && (gx < S);
          unsigned v0 = 0, v1 = 0;
          if (ok) {
            size_t gbase = (size_t)(cb + ci2b) * S * S + (size_t)gy * S + gx;
            v0 = xp[gbase];
            v1 = xp[gbase + (size_t)8 * S * S];
          }
          int lb = (r * (S + 2) + col) * (PCI / 2);
          x_s32[lb + ci2b] = v0;
          x_s32[lb + ci2b + 8] = v1;
        }
      }
    }
    __syncthreads();
#pragma unroll
    for (int dyg = 0; dyg < 3; ++dyg)
#pragma unroll
      for (int dx = 0; dx < 3; ++dx) {
        short8 a[MR];
#pragma unroll
        for (int m = 0; m < MR; ++m)
          a[m] = *(const short8*)&wpk[((size_t)((dyg * 3 + dx) * 256 + co0 + wcob + m * 16 + (l & 15)) * 256) + c0 + (l >> 4) * 8];
#pragma unroll
        for (int o = 0; o < O; ++o) {
          short8 b[NR];
#pragma unroll
          for (int n = 0; n < NR; ++n)
            b[n] = *(const short8*)&x_s[((dyg + o) * (S + 2) + wposb + n * 16 + (l & 15) + dx) * PCI + (l >> 4) * 8];
#pragma unroll
          for (int m = 0; m < MR; ++m)
#pragma unroll
            for (int n = 0; n < NR; ++n) mfma_bf16(acc[o][m][n], a[m], b[n]);
        }
      }
  }
  asm volatile("s_nop 7\n\ts_nop 7" ::);
#pragma unroll
  for (int o = 0; o < O; ++o)
#pragma unroll
    for (int m = 0; m < MR; ++m)
#pragma unroll
      for (int n = 0; n < NR; ++n) {
        int cob = co0 + wcob + m * 16 + (l >> 4) * 4;
        int px = wposb + n * 16 + (l & 15);
#pragma unroll
        for (int r4p = 0; r4p < 2; ++r4p) {
          unsigned pk = (unsigned)f2bf(acc[o][m][n][2 * r4p] + bias[cob + 2 * r4p])
                      | ((unsigned)f2bf(acc[o][m][n][2 * r4p + 1] + bias[cob + 2 * r4p + 1]) << 16);
          yp[(size_t)((cob >> 1) + r4p) * S * S + (size_t)(row0 + o) * S + px] = pk;
        }
      }
}

// 512-thread conv3 for S=128 with LDS-staged weights: 8 waves, 2 blocks/CU.
__global__ __launch_bounds__(512) void k_conv3v(const unsigned* __restrict__ xp,
                                                const short* __restrict__ wpk,
                                                const float* __restrict__ bias,
                                                unsigned* __restrict__ yp) {
  constexpr int S = 128;
  constexpr int MR = 2;
  constexpr int PSP = 32;
  constexpr int NR = 2;
  __shared__ short x_s[3 * (S + 2) * PCI];
  __shared__ short w_s[9 * 64 * PCI];
  unsigned* x_s32 = (unsigned*)x_s;
  int t = threadIdx.x, l = t & 63, wv = t >> 6;
  int wcob = (wv & 1) * 32;
  int wposb = (wv >> 1) * PSP;
  int row0 = blockIdx.x;
  int co0 = blockIdx.y * 64;
  int colb = t & 31, ci2b = t >> 5;
  f32x4 acc[MR][NR];
#pragma unroll
  for (int m = 0; m < MR; ++m)
#pragma unroll
    for (int n = 0; n < NR; ++n) { f32x4 z = {0.f, 0.f, 0.f, 0.f}; acc[m][n] = z; }
  for (int c0 = 0; c0 < CCH; c0 += 32) {
    int cb = c0 >> 1;
    __syncthreads();
#pragma unroll
    for (int r = 0; r < 3; ++r) {
      int gy = row0 - 1 + r;
      bool yok = (gy >= 0 && gy < S);
#pragma unroll
      for (int cbk = 0; cbk < 5; ++cbk) {
        int col = colb + cbk * 32;
        if (col < S + 2) {
          int gx = col - 1;
          bool ok = yok && (gx >= 0) && (gx < S);
          unsigned v = 0;
          if (ok)
            v = xp[(size_t)(cb + ci2b) * S * S + (size_t)gy * S + gx];
          x_s32[(r * (S + 2) + col) * (PCI / 2) + ci2b] = v;
        }
      }
    }
    for (int i = t; i < 4608; i += 512) {
      int seg8 = i & 7;
      int rowi = i >> 3;
      int tap = rowi >> 6, co = rowi & 63;
      us4 wv4 = *(const us4*)&wpk[((size_t)(tap * 256 + co0 + co) * 256) + c0 + seg8 * 4];
      *(us4*)&w_s[rowi * PCI + seg8 * 4] = wv4;
    }
    __syncthreads();
#pragma unroll
    for (int dyg = 0; dyg < 3; ++dyg)
#pragma unroll
      for (int dx = 0; dx < 3; ++dx) {
        short8 a[MR];
#pragma unroll
        for (int m = 0; m < MR; ++m)
          a[m] = *(const short8*)&w_s[((dyg * 3 + dx) * 64 + wcob + m * 16 + (l & 15)) * PCI + (l >> 4) * 8];
        short8 b[NR];
#pragma unroll
        for (int n = 0; n < NR; ++n)
          b[n] = *(const short8*)&x_s[(dyg * (S + 2) + wposb + n * 16 + (l & 15) + dx) * PCI + (l >> 4) * 8];
#pragma unroll
        for (int m = 0; m < MR; ++m)
#pragma unroll
          for (int n = 0; n < NR; ++n) mfma_bf16(acc[m][n], a[m], b[n]);
      }
  }
  asm volatile("s_nop 7\n\ts_nop 7" ::);
#pragma unroll
  for (int m = 0; m < MR; ++m)
#pragma unroll
    for (int n = 0; n < NR; ++n) {
      int cob = co0 + wcob + m * 16 + (l >> 4) * 4;
      int px = wposb + n * 16 + (l & 15);
#pragma unroll
      for (int r4p = 0; r4p < 2; ++r4p) {
        unsigned pk = (unsigned)f2bf(acc[m][n][2 * r4p] + bias[cob + 2 * r4p])
                    | ((unsigned)f2bf(acc[m][n][2 * r4p + 1] + bias[cob + 2 * r4p + 1]) << 16);
        yp[(size_t)((cob >> 1) + r4p) * S * S + (size_t)row0 * S + px] = pk;
      }
    }
}

// 512-thread conv3 for S=64 with LDS-staged weights: 8 waves (MR=2, NR=1),
// grid (64, 4). x_s 15.8KB + w_s 46KB = 62KB.
__global__ __launch_bounds__(512) void k_conv3v64(const unsigned* __restrict__ xp,
                                                  const short* __restrict__ wpk,
                                                  const float* __restrict__ bias,
                                                  unsigned* __restrict__ yp) {
  constexpr int S = 64;
  constexpr int MR = 2;
  __shared__ short x_s[3 * (S + 2) * PCI];
  __shared__ short w_s[9 * 64 * PCI];
  unsigned* x_s32 = (unsigned*)x_s;
  int t = threadIdx.x, l = t & 63, wv = t >> 6;
  int wcob = (wv & 1) * 32;
  int wposb = (wv >> 1) * 16;
  int row0 = blockIdx.x;
  int co0 = blockIdx.y * 64;
  int colb = t & 31, ci2b = t >> 5;
  f32x4 acc[MR];
#pragma unroll
  for (int m = 0; m < MR; ++m) { f32x4 z = {0.f, 0.f, 0.f, 0.f}; acc[m] = z; }
  for (int c0 = 0; c0 < CCH; c0 += 32) {
    int cb = c0 >> 1;
    __syncthreads();
#pragma unroll
    for (int r = 0; r < 3; ++r) {
      int gy = row0 - 1 + r;
      bool yok = (gy >= 0 && gy < S);
#pragma unroll
      for (int cbk = 0; cbk < 3; ++cbk) {
        int col = colb + cbk * 32;
        if (col < S + 2) {
          int gx = col - 1;
          bool ok = yok && (gx >= 0) && (gx < S);
          unsigned v = 0;
          if (ok)
            v = xp[(size_t)(cb + ci2b) * S * S + (size_t)gy * S + gx];
          x_s32[(r * (S + 2) + col) * (PCI / 2) + ci2b] = v;
        }
      }
    }
    for (int i = t; i < 4608; i += 512) {
      int seg8 = i & 7;
      int rowi = i >> 3;
      int tap = rowi >> 6, co = rowi & 63;
      us4 wv4 = *(const us4*)&wpk[((size_t)(tap * 256 + co0 + co) * 256) + c0 + seg8 * 4];
      *(us4*)&w_s[rowi * PCI + seg8 * 4] = wv4;
    }
    __syncthreads();
#pragma unroll
    for (int dyg = 0; dyg < 3; ++dyg)
#pragma unroll
      for (int dx = 0; dx < 3; ++dx) {
        short8 a[MR];
#pragma unroll
        for (int m = 0; m < MR; ++m)
          a[m] = *(const short8*)&w_s[((dyg * 3 + dx) * 64 + wcob + m * 16 + (l & 15)) * PCI + (l >> 4) * 8];
        short8 b = *(const short8*)&x_s[(dyg * (S + 2) + wposb + (l & 15) + dx) * PCI + (l >> 4) * 8];
#pragma unroll
        for (int m = 0; m < MR; ++m) mfma_bf16(acc[m], a[m], b);
      }
  }
  asm volatile("s_nop 7\n\ts_nop 7" ::);
#pragma unroll
  for (int m = 0; m < MR; ++m) {
    int cob = co0 + wcob + m * 16 + (l >> 4) * 4;
    int px = wposb + (l & 15);
#pragma unroll
    for (int r4p = 0; r4p < 2; ++r4p) {
      unsigned pk = (unsigned)f2bf(acc[m][2 * r4p] + bias[cob + 2 * r4p])
                  | ((unsigned)f2bf(acc[m][2 * r4p + 1] + bias[cob + 2 * r4p + 1]) << 16);
      yp[(size_t)((cob >> 1) + r4p) * S * S + (size_t)row0 * S + px] = pk;
    }
  }
}

// MFMA deconv4x4 s2 p2 + bias + relu, O input rows + both q parities per block.
// LDS-staged weights (r13 form, 256 threads). Used for S=16,32.
template <int S, int O>
__global__ __launch_bounds__(256) void k_deconvu(const unsigned* __restrict__ xp,
                                                 const short* __restrict__ wpk,
                                                 const float* __restrict__ bias,
                                                 unsigned* __restrict__ yp) {
  constexpr int WPC = (S >= 64) ? 2 : 1;
  constexpr int WCO = 4 / WPC;
  constexpr int COS = 64 / WCO;
  constexpr int MR = COS / 16;
  constexpr int PSP = S / WPC;
  constexpr int NR = PSP / 16;
  constexpr int CBK = (S + 2 + 31) / 32;
  constexpr int RS = O + 1;
  const int SO = 2 * S;
  __shared__ short x_s[RS * (S + 2) * PCI];
  __shared__ short w_s[8 * 64 * PCI];
  unsigned* x_s32 = (unsigned*)x_s;
  int t = threadIdx.x, l = t & 63, wv = t >> 6;
  int wcob = (wv % WCO) * COS;
  int wposb = (wv / WCO) * PSP;
  int row0 = blockIdx.x * O;
  int co0 = blockIdx.y * 64;
  int p = blockIdx.z;
  int colb = t & 31, ci2b = t >> 5;
  f32x4 acc[2][O][MR][NR];
#pragma unroll
  for (int q = 0; q < 2; ++q)
#pragma unroll
    for (int o = 0; o < O; ++o)
#pragma unroll
      for (int m = 0; m < MR; ++m)
#pragma unroll
        for (int n = 0; n < NR; ++n) { f32x4 z = {0.f, 0.f, 0.f, 0.f}; acc[q][o][m][n] = z; }
  for (int c0 = 0; c0 < CCH; c0 += 32) {
    int cb = c0 >> 1;
    __syncthreads();
#pragma unroll
    for (int r = 0; r < RS; ++r) {
      int gy = row0 + p - 1 + r;
      bool yok = (gy >= 0 && gy < S);
#pragma unroll
      for (int cbk = 0; cbk < CBK; ++cbk) {
        int col = colb + cbk * 32;
        if (col < S + 2) {
          int gx = col - 1;
          bool ok = yok && (gx >= 0) && (gx < S);
          unsigned v0 = 0, v1 = 0;
          if (ok) {
            size_t gbase = (size_t)(cb + ci2b) * S * S + (size_t)gy * S + gx;
            v0 = xp[gbase];
            v1 = xp[gbase + (size_t)8 * S * S];
          }
          int lb = (r * (S + 2) + col) * (PCI / 2);
          x_s32[lb + ci2b] = v0;
          x_s32[lb + ci2b + 8] = v1;
        }
      }
    }
    for (int i = t; i < 4096; i += 256) {
      int seg8 = i & 7;
      int rowi = i >> 3;
      int c8 = rowi >> 6, co = rowi & 63;
      int qq = c8 >> 2, tt = c8 & 3;
      us4 wv4 = *(const us4*)&wpk[((size_t)(((2 * p + qq) * 4 + tt) * 256 + co0 + co) * 256) + c0 + seg8 * 4];
      *(us4*)&w_s[rowi * PCI + seg8 * 4] = wv4;
    }
    __syncthreads();
#pragma unroll
    for (int dyi = 0; dyi < 2; ++dyi)
#pragma unroll
      for (int o = 0; o < O; ++o) {
        short8 b[3][NR];
#pragma unroll
        for (int off = 0; off < 3; ++off)
#pragma unroll
          for (int n = 0; n < NR; ++n)
            b[off][n] = *(const short8*)&x_s[((dyi + o) * (S + 2) + wposb + n * 16 + (l & 15) + off) * PCI + (l >> 4) * 8];
#pragma unroll
        for (int q = 0; q < 2; ++q)
#pragma unroll
          for (int dxi = 0; dxi < 2; ++dxi) {
            int c8 = q * 4 + dyi * 2 + dxi;
            short8 a[MR];
#pragma unroll
            for (int m = 0; m < MR; ++m)
              a[m] = *(const short8*)&w_s[(c8 * 64 + wcob + m * 16 + (l & 15)) * PCI + (l >> 4) * 8];
#pragma unroll
            for (int m = 0; m < MR; ++m)
#pragma unroll
              for (int n = 0; n < NR; ++n) mfma_bf16(acc[q][o][m][n], a[m], b[dxi + q][n]);
          }
      }
  }
  asm volatile("s_nop 7\n\ts_nop 7" ::);
#pragma unroll
  for (int o = 0; o < O; ++o) {
    int oy = 2 * (row0 + o) + p;
#pragma unroll
    for (int m = 0; m < MR; ++m)
#pragma unroll
      for (int n = 0; n < NR; ++n) {
        int px = wposb + n * 16 + (l & 15);
#pragma unroll
        for (int r4p = 0; r4p < 2; ++r4p) {
          int cob = co0 + wcob + m * 16 + (l >> 4) * 4 + 2 * r4p;
          float b0 = bias[cob], b1 = bias[cob + 1];
          unsigned pk0 = (unsigned)f2bf(fmaxf(acc[0][o][m][n][2 * r4p] + b0, 0.f))
                       | ((unsigned)f2bf(fmaxf(acc[0][o][m][n][2 * r4p + 1] + b1, 0.f)) << 16);
          unsigned pk1 = (unsigned)f2bf(fmaxf(acc[1][o][m][n][2 * r4p] + b0, 0.f))
                       | ((unsigned)f2bf(fmaxf(acc[1][o][m][n][2 * r4p + 1] + b1, 0.f)) << 16);
          uint2 pk = make_uint2(pk0, pk1);
          *(uint2*)&yp[(size_t)(cob >> 1) * SO * SO + (size_t)oy * SO + 2 * px] = pk;
        }
      }
  }
}

// 512-thread deconv for S=128, O=2: 8 waves/block, 2 blocks/CU.
__global__ __launch_bounds__(512) void k_deconvw(const unsigned* __restrict__ xp,
                                                 const short* __restrict__ wpk,
                                                 const float* __restrict__ bias,
                                                 unsigned* __restrict__ yp) {
  constexpr int S = 128;
  constexpr int O = 2;
  constexpr int MR = 2;
  constexpr int PSP = 32;
  constexpr int NR = 2;
  constexpr int RS = O + 1;
  const int SO = 2 * S;
  __shared__ short x_s[RS * (S + 2) * PCI];
  __shared__ short w_s[8 * 64 * PCI];
  unsigned* x_s32 = (unsigned*)x_s;
  int t = threadIdx.x, l = t & 63, wv = t >> 6;
  int wcob = (wv & 1) * 32;
  int wposb = (wv >> 1) * PSP;
  int row0 = blockIdx.x * O;
  int co0 = blockIdx.y * 64;
  int p = blockIdx.z;
  int colb = t & 31, ci2b = t >> 5;
  f32x4 acc[2][O][MR][NR];
#pragma unroll
  for (int q = 0; q < 2; ++q)
#pragma unroll
    for (int o = 0; o < O; ++o)
#pragma unroll
      for (int m = 0; m < MR; ++m)
#pragma unroll
        for (int n = 0; n < NR; ++n) { f32x4 z = {0.f, 0.f, 0.f, 0.f}; acc[q][o][m][n] = z; }
  for (int c0 = 0; c0 < CCH; c0 += 32) {
    int cb = c0 >> 1;
    __syncthreads();
#pragma unroll
    for (int r = 0; r < RS; ++r) {
      int gy = row0 + p - 1 + r;
      bool yok = (gy >= 0 && gy < S);
#pragma unroll
      for (int cbk = 0; cbk < 5; ++cbk) {
        int col = colb + cbk * 32;
        if (col < S + 2) {
          int gx = col - 1;
          bool ok = yok && (gx >= 0) && (gx < S);
          unsigned v = 0;
          if (ok)
            v = xp[(size_t)(cb + ci2b) * S * S + (size_t)gy * S + gx];
          x_s32[(r * (S + 2) + col) * (PCI / 2) + ci2b] = v;
        }
      }
    }
    for (int i = t; i < 4096; i += 512) {
      int seg8 = i & 7;
      int rowi = i >> 3;
      int c8 = rowi >> 6, co = rowi & 63;
      int qq = c8 >> 2, tt = c8 & 3;
      us4 wv4 = *(const us4*)&wpk[((size_t)(((2 * p + qq) * 4 + tt) * 256 + co0 + co) * 256) + c0 + seg8 * 4];
      *(us4*)&w_s[rowi * PCI + seg8 * 4] = wv4;
    }
    __syncthreads();
#pragma unroll
    for (int dyi = 0; dyi < 2; ++dyi)
#pragma unroll
      for (int o = 0; o < O; ++o) {
        short8 b[3][NR];
#pragma unroll
        for (int off = 0; off < 3; ++off)
#pragma unroll
          for (int n = 0; n < NR; ++n)
            b[off][n] = *(const short8*)&x_s[((dyi + o) * (S + 2) + wposb + n * 16 + (l & 15) + off) * PCI + (l >> 4) * 8];
#pragma unroll
        for (int q = 0; q < 2; ++q)
#pragma unroll
          for (int dxi = 0; dxi < 2; ++dxi) {
            int c8 = q * 4 + dyi * 2 + dxi;
            short8 a[MR];
#pragma unroll
            for (int m = 0; m < MR; ++m)
              a[m] = *(const short8*)&w_s[(c8 * 64 + wcob + m * 16 + (l & 15)) * PCI + (l >> 4) * 8];
#pragma unroll
            for (int m = 0; m < MR; ++m)
#pragma unroll
              for (int n = 0; n < NR; ++n) mfma_bf16(acc[q][o][m][n], a[m], b[dxi + q][n]);
          }
      }
  }
  asm volatile("s_nop 7\n\ts_nop 7" ::);
#pragma unroll
  for (int o = 0; o < O; ++o) {
    int oy = 2 * (row0 + o) + p;
#pragma unroll
    for (int m = 0; m < MR; ++m)
#pragma unroll
      for (int n = 0; n < NR; ++n) {
        int px = wposb + n * 16 + (l & 15);
#pragma unroll
        for (int r4p = 0; r4p < 2; ++r4p) {
          int cob = co0 + wcob + m * 16 + (l >> 4) * 4 + 2 * r4p;
          float b0 = bias[cob], b1 = bias[cob + 1];
          unsigned pk0 = (unsigned)f2bf(fmaxf(acc[0][o][m][n][2 * r4p] + b0, 0.f))
                       | ((unsigned)f2bf(fmaxf(acc[0][o][m][n][2 * r4p + 1] + b1, 0.f)) << 16);
          unsigned pk1 = (unsigned)f2bf(fmaxf(acc[1][o][m][n][2 * r4p] + b0, 0.f))
                       | ((unsigned)f2bf(fmaxf(acc[1][o][m][n][2 * r4p + 1] + b1, 0.f)) << 16);
          uint2 pk = make_uint2(pk0, pk1);
          *(uint2*)&yp[(size_t)(cob >> 1) * SO * SO + (size_t)oy * SO + 2 * px] = pk;
        }
      }
  }
}

// 512-thread deconv for S=64, O=1: 8 waves (MR=2, NR=1), grid (64,4,2).
__global__ __launch_bounds__(512) void k_deconvw64(const unsigned* __restrict__ xp,
                                                   const short* __restrict__ wpk,
                                                   const float* __restrict__ bias,
                                                   unsigned* __restrict__ yp) {
  constexpr int S = 64;
  constexpr int MR = 2;
  const int SO = 2 * S;
  __shared__ short x_s[2 * (S + 2) * PCI];
  __shared__ short w_s[8 * 64 * PCI];
  unsigned* x_s32 = (unsigned*)x_s;
  int t = threadIdx.x, l = t & 63, wv = t >> 6;
  int wcob = (wv & 1) * 32;
  int wposb = (wv >> 1) * 16;
  int row0 = blockIdx.x;
  int co0 = blockIdx.y * 64;
  int p = blockIdx.z;
  int colb = t & 31, ci2b = t >> 5;
  f32x4 acc[2][MR];   // [q][m]
#pragma unroll
  for (int q = 0; q < 2; ++q)
#pragma unroll
    for (int m = 0; m < MR; ++m) { f32x4 z = {0.f, 0.f, 0.f, 0.f}; acc[q][m] = z; }
  for (int c0 = 0; c0 < CCH; c0 += 32) {
    int cb = c0 >> 1;
    __syncthreads();
#pragma unroll
    for (int r = 0; r < 2; ++r) {
      int gy = row0 + p - 1 + r;
      bool yok = (gy >= 0 && gy < S);
#pragma unroll
      for (int cbk = 0; cbk < 3; ++cbk) {
        int col = colb + cbk * 32;
        if (col < S + 2) {
          int gx = col - 1;
          bool ok = yok && (gx >= 0) && (gx < S);
          unsigned v = 0;
          if (ok)
            v = xp[(size_t)(cb + ci2b) * S * S + (size_t)gy * S + gx];
          x_s32[(r * (S + 2) + col) * (PCI / 2) + ci2b] = v;
        }
      }
    }
    for (int i = t; i < 4096; i += 512) {
      int seg8 = i & 7;
      int rowi = i >> 3;
      int c8 = rowi >> 6, co = rowi & 63;
      int qq = c8 >> 2, tt = c8 & 3;
      us4 wv4 = *(const us4*)&wpk[((size_t)(((2 * p + qq) * 4 + tt) * 256 + co0 + co) * 256) + c0 + seg8 * 4];
      *(us4*)&w_s[rowi * PCI + seg8 * 4] = wv4;
    }
    __syncthreads();
#pragma unroll
    for (int dyi = 0; dyi < 2; ++dyi) {
      short8 b[3];
#pragma unroll
      for (int off = 0; off < 3; ++off)
        b[off] = *(const short8*)&x_s[(dyi * (S + 2) + wposb + (l & 15) + off) * PCI + (l >> 4) * 8];
#pragma unroll
      for (int q = 0; q < 2; ++q)
#pragma unroll
        for (int dxi = 0; dxi < 2; ++dxi) {
          int c8 = q * 4 + dyi * 2 + dxi;
          short8 a[MR];
#pragma unroll
          for (int m = 0; m < MR; ++m)
            a[m] = *(const short8*)&w_s[(c8 * 64 + wcob + m * 16 + (l & 15)) * PCI + (l >> 4) * 8];
#pragma unroll
          for (int m = 0; m < MR; ++m) mfma_bf16(acc[q][m], a[m], b[dxi + q]);
        }
    }
  }
  asm volatile("s_nop 7\n\ts_nop 7" ::);
  int oy = 2 * row0 + p;
#pragma unroll
  for (int m = 0; m < MR; ++m) {
    int px = wposb + (l & 15);
#pragma unroll
    for (int r4p = 0; r4p < 2; ++r4p) {
      int cob = co0 + wcob + m * 16 + (l >> 4) * 4 + 2 * r4p;
      float b0 = bias[cob], b1 = bias[cob + 1];
      unsigned pk0 = (unsigned)f2bf(fmaxf(acc[0][m][2 * r4p] + b0, 0.f))
                   | ((unsigned)f2bf(fmaxf(acc[0][m][2 * r4p + 1] + b1, 0.f)) << 16);
      unsigned pk1 = (unsigned)f2bf(fmaxf(acc[1][m][2 * r4p] + b0, 0.f))
                   | ((unsigned)f2bf(fmaxf(acc[1][m][2 * r4p + 1] + b1, 0.f)) << 16);
      uint2 pk = make_uint2(pk0, pk1);
      *(uint2*)&yp[(size_t)(cob >> 1) * SO * SO + (size_t)oy * SO + 2 * px] = pk;
    }
  }
}

// sparse final conv3 via MFMA -> bf16 srows
__global__ __launch_bounds__(256) void k_conv3sM(const unsigned* __restrict__ xp,
                                                 const short* __restrict__ wB,
                                                 const float* __restrict__ bias,
                                                 const int* __restrict__ idx,
                                                 short* __restrict__ outb) {
  __shared__ short a_s[16][296];
  __shared__ int py_s[16], px_s[16];
  int t = threadIdx.x, l = t & 63, wv = t >> 6;
  int j0 = blockIdx.x * 16;
  int co0 = blockIdx.y * 128 + wv * 32;
  if (t < 16) {
    int p = idx[j0 + t];
    py_s[t] = p >> 8;
    px_s[t] = p & 255;
  }
  f32x4 acc[2];
  { f32x4 z = {0.f, 0.f, 0.f, 0.f}; acc[0] = z; acc[1] = z; }
  for (int c = 0; c < 8; ++c) {
    __syncthreads();
    for (int i = t; i < 2304; i += 256) {
      int ci2 = i & 15;
      int je = i >> 4;
      int j = je / 9, e = je % 9;
      int gy = py_s[j] - 1 + e / 3, gx = px_s[j] - 1 + e % 3;
      unsigned v = 0;
      if (gy >= 0 && gy < 256 && gx >= 0 && gx < 256)
        v = xp[(size_t)(c * 16 + ci2) * HWP + gy * 256 + gx];
      *(unsigned*)&a_s[j][e * 32 + 2 * ci2] = v;
    }
    __syncthreads();
#pragma unroll
    for (int s = 0; s < 9; ++s) {
      short8 a = *(const short8*)&a_s[l & 15][s * 32 + (l >> 4) * 8];
      int kg = c * 288 + s * 32 + (l >> 4) * 8;
      short8 b0 = *(const short8*)&wB[(size_t)(co0 + (l & 15)) * 2304 + kg];
      short8 b1 = *(const short8*)&wB[(size_t)(co0 + 16 + (l & 15)) * 2304 + kg];
      mfma_bf16(acc[0], a, b0);
      mfma_bf16(acc[1], a, b1);
    }
  }
  asm volatile("s_nop 7\n\ts_nop 7" ::);
#pragma unroll
  for (int n = 0; n < 2; ++n)
#pragma unroll
    for (int r = 0; r < 4; ++r) {
      int j = j0 + (l >> 4) * 4 + r;
      int co = co0 + n * 16 + (l & 15);
      outb[(size_t)j * 256 + co] = (short)f2bf(acc[n][r] + bias[co]);
    }
}

// MFMA in-projection: grid (128 j-tiles, 12 out-tiles of 64). 0-3=Q, 4-7=K, 8-11=V.
__global__ __launch_bounds__(256) void k_qkv3(const short* __restrict__ dq,
                                              const short* __restrict__ sr,
                                              const short* __restrict__ wBi,
                                              const float* __restrict__ bias,
                                              short* __restrict__ Qb,
                                              short* __restrict__ Kb,
                                              short* __restrict__ Vt) {
  __shared__ short a_s[16 * 264];
  unsigned* a_s32 = (unsigned*)a_s;
  int t = threadIdx.x, l = t & 63, wv = t >> 6;
  int j0 = blockIdx.x * 16;
  int third = blockIdx.y >> 2;
  const unsigned* s32 = (const unsigned*)(third ? sr : dq);
  for (int i = t; i < 2048; i += 256) {
    int row = i >> 7, c2 = i & 127;
    a_s32[row * 132 + c2] = s32[(size_t)(j0 + row) * 128 + c2];
  }
  __syncthreads();
  int cog = blockIdx.y * 64 + wv * 16 + (l & 15);
  f32x4 acc = {0.f, 0.f, 0.f, 0.f};
  const short* brow = wBi + (size_t)cog * 256 + (l >> 4) * 8;
  const short* arow = a_s + (l & 15) * 264 + (l >> 4) * 8;
#pragma unroll
  for (int kc = 0; kc < 8; ++kc) {
    short8 a = *(const short8*)(arow + kc * 32);
    short8 b = *(const short8*)(brow + kc * 32);
    mfma_bf16(acc, a, b);
  }
  asm volatile("s_nop 7\n\ts_nop 7" ::);
  float bv = bias[cog];
  int co = cog & 255;
  int h = co >> 5, d = co & 31;
#pragma unroll
  for (int r = 0; r < 4; ++r) {
    int j = j0 + (l >> 4) * 4 + r;
    short v = (short)f2bf(acc[r] + bv);
    if (third == 0)      Qb[((size_t)h * 2048 + j) * 32 + d] = v;
    else if (third == 1) Kb[((size_t)h * 2048 + j) * 32 + d] = v;
    else                 Vt[((size_t)h * 32 + d) * 2048 + j] = v;
  }
}

// fused flash attention. grid (32 qtiles, 8 h), 4 waves. Writes bf16 Ob.
__global__ __launch_bounds__(256) void k_fattn(const short* __restrict__ Qb,
                                               const short* __restrict__ Kb,
                                               const short* __restrict__ Vt,
                                               short* __restrict__ Ob) {
  __shared__ short P_lds[4][16][136];
  int t = threadIdx.x, l = t & 63, wv = t >> 6;
  int h = blockIdx.y;
  int q0 = blockIdx.x * 64 + wv * 16;
  const short* Qh = Qb + (size_t)h * 2048 * 32;
  const short* Kh = Kb + (size_t)h * 2048 * 32;
  const short* Vh = Vt + (size_t)h * 32 * 2048;
  short8 a_q = *(const short8*)&Qh[(size_t)(q0 + (l & 15)) * 32 + (l >> 4) * 8];
  f32x4 o0 = {0.f, 0.f, 0.f, 0.f}, o1 = {0.f, 0.f, 0.f, 0.f};
  float m_run[4], l_run[4];
#pragma unroll
  for (int r = 0; r < 4; ++r) { m_run[r] = -3e38f; l_run[r] = 0.f; }
  const float scale = 0.17677669529663687f;
  for (int k0 = 0; k0 < 2048; k0 += 128) {
    f32x4 s[8];
#pragma unroll
    for (int kt = 0; kt < 8; ++kt) {
      f32x4 z = {0.f, 0.f, 0.f, 0.f};
      s[kt] = z;
      short8 b = *(const short8*)&Kh[(size_t)(k0 + kt * 16 + (l & 15)) * 32 + (l >> 4) * 8];
      mfma_bf16(s[kt], a_q, b);
    }
    asm volatile("s_nop 7\n\ts_nop 7" ::);
    float tm[4];
#pragma unroll
    for (int r = 0; r < 4; ++r) {
      float mx = s[0][r];
#pragma unroll
      for (int kt = 1; kt < 8; ++kt) mx = fmaxf(mx, s[kt][r]);
      tm[r] = mx * scale;
    }
#pragma unroll
    for (int mask = 1; mask < 16; mask <<= 1)
#pragma unroll
      for (int r = 0; r < 4; ++r) tm[r] = fmaxf(tm[r], __shfl_xor(tm[r], mask));
    float mn[4], al[4], rs[4];
#pragma unroll
    for (int r = 0; r < 4; ++r) {
      mn[r] = fmaxf(m_run[r], tm[r]);
      al[r] = __expf(m_run[r] - mn[r]);
      rs[r] = 0.f;
    }
#pragma unroll
    for (int kt = 0; kt < 8; ++kt)
#pragma unroll
      for (int r = 0; r < 4; ++r) {
        float pv = __expf(s[kt][r] * scale - mn[r]);
        s[kt][r] = pv;
        rs[r] += pv;
      }
#pragma unroll
    for (int mask = 1; mask < 16; mask <<= 1)
#pragma unroll
      for (int r = 0; r < 4; ++r) rs[r] += __shfl_xor(rs[r], mask);
#pragma unroll
    for (int r = 0; r < 4; ++r) {
      l_run[r] = l_run[r] * al[r] + rs[r];
      m_run[r] = mn[r];
      o0[r] *= al[r];
      o1[r] *= al[r];
    }
#pragma unroll
    for (int kt = 0; kt < 8; ++kt)
#pragma unroll
      for (int r = 0; r < 4; ++r)
        P_lds[wv][(l >> 4) * 4 + r][kt * 16 + (l & 15)] = (short)f2bf(s[kt][r]);
#pragma unroll
    for (int kc = 0; kc < 4; ++kc) {
      short8 ap = *(const short8*)&P_lds[wv][l & 15][kc * 32 + (l >> 4) * 8];
      short8 b0 = *(const short8*)&Vh[(size_t)(l & 15) * 2048 + k0 + kc * 32 + (l >> 4) * 8];
      short8 b1 = *(const short8*)&Vh[(size_t)(16 + (l & 15)) * 2048 + k0 + kc * 32 + (l >> 4) * 8];
      mfma_bf16(o0, ap, b0);
      mfma_bf16(o1, ap, b1);
    }
  }
  asm volatile("s_nop 7\n\ts_nop 7" ::);
#pragma unroll
  for (int r = 0; r < 4; ++r) {
    float inv = 1.f / l_run[r];
    int qr = q0 + (l >> 4) * 4 + r;
    Ob[(size_t)qr * 256 + h * 32 + (l & 15)] = (short)f2bf(o0[r] * inv);
    Ob[(size_t)qr * 256 + h * 32 + 16 + (l & 15)] = (short)f2bf(o1[r] * inv);
  }
}

// MFMA out-projection + scatter. grid (128 j-tiles, 4 co-tiles of 64).
__global__ __launch_bounds__(256) void k_outprojM(const short* __restrict__ Ob,
                                                  const short* __restrict__ wBo,
                                                  const float* __restrict__ ob,
                                                  const int* __restrict__ idx,
                                                  float* __restrict__ out) {
  __shared__ short a_s[16 * 264];
  __shared__ int jp[16];
  unsigned* a_s32 = (unsigned*)a_s;
  const unsigned* s32 = (const unsigned*)Ob;
  int t = threadIdx.x, l = t & 63, wv = t >> 6;
  int j0 = blockIdx.x * 16;
  if (t < 16) jp[t] = idx[j0 + t];
  for (int i = t; i < 2048; i += 256) {
    int row = i >> 7, c2 = i & 127;
    a_s32[row * 132 + c2] = s32[(size_t)(j0 + row) * 128 + c2];
  }
  __syncthreads();
  int co = blockIdx.y * 64 + wv * 16 + (l & 15);
  f32x4 acc = {0.f, 0.f, 0.f, 0.f};
  const short* brow = wBo + (size_t)co * 256 + (l >> 4) * 8;
  const short* arow = a_s + (l & 15) * 264 + (l >> 4) * 8;
#pragma unroll
  for (int kc = 0; kc < 8; ++kc) {
    short8 a = *(const short8*)(arow + kc * 32);
    short8 b = *(const short8*)(brow + kc * 32);
    mfma_bf16(acc, a, b);
  }
  asm volatile("s_nop 7\n\ts_nop 7" ::);
  float bv = ob[co];
#pragma unroll
  for (int r = 0; r < 4; ++r) {
    int jl = (l >> 4) * 4 + r;
    out[(size_t)co * HWP + jp[jl]] = acc[r] + bv;
  }
}

extern "C" void kernel_launch(void* const* d_in, const int* in_sizes, int n_in,
                              void* d_out, int out_size, void* d_ws, size_t ws_size,
                              hipStream_t stream) {
  const float* down  = (const float*)d_in[0];
  const float* swint = (const float*)d_in[1];
  const float* wt_w  = (const float*)d_in[2];
  const float* wt_b  = (const float*)d_in[3];
  const float* up_dw = (const float*)d_in[4];
  const float* up_db = (const float*)d_in[5];
  const float* up_cw = (const float*)d_in[6];
  const float* up_cb = (const float*)d_in[7];
  const float* gate_w = (const float*)d_in[8];
  const float* in_w  = (const float*)d_in[10];
  const float* in_b  = (const float*)d_in[11];
  const float* out_w = (const float*)d_in[12];
  const float* out_b = (const float*)d_in[13];
  float* out = (float*)d_out;
  char* ws = (char*)d_ws;

  unsigned* actA = (unsigned*)ws;
  unsigned* actB = (unsigned*)(ws + BUF_B_OFF);
  unsigned int* keys = (unsigned int*)(ws + KEYS_OFF);
  unsigned int* hist = (unsigned int*)(ws + HIST_OFF);
  int* idx = (int*)(ws + IDX_OFF);
  int* eq = (int*)(ws + EQ_OFF);
  short* Ob = (short*)(ws + OB_OFF);
  short* wBi = (short*)(ws + WBI_OFF);
  short* wBo = (short*)(ws + WBO_OFF);
  short* srowsb = (short*)(ws + SROWS_OFF);
  short* dq = (short*)(ws + DQ_OFF);
  float* gpart = (float*)(ws + GPART_OFF);
  short* wB5 = (short*)(ws + WT5_OFF);
  short* Qb = (short*)(ws + QB_OFF);
  short* Kb = (short*)(ws + KB_OFF);
  short* Vt = (short*)(ws + VT_OFF);
  short* cpk = (short*)(ws + CPK_OFF);
  short* dpk = (short*)(ws + DPK_OFF);
  short* wBt = (short*)(ws + WTW_OFF);
  float* wpart = (float*)(ws + WPART_OFF);
  short* xq0 = (short*)(ws + XQ0_OFF);

  // gate partials + copy (zeroes hist), keys + fused r0 hist, 1-block select, gather
  k_gatecopy2<<<dim3(256, 8), 256, 0, stream>>>(down, gate_w, out, gpart, hist);
  k_gkey<<<256, 256, 0, stream>>>(gpart, keys, hist);
  k_select1b<<<1, 1024, 0, stream>>>(keys, hist, idx, eq);
  k_gatherq<<<2048, 256, 0, stream>>>(down, idx, dq);

  // all weight packs in one launch (conv3 x4, deconv x5, conv5, in_w, out_w, wt_w)
  k_packall<<<3840, 256, 0, stream>>>(up_cw, up_dw, in_w, out_w, wt_w,
                                      cpk, dpk, wB5, wBi, wBo, wBt);

  // stage 0: K-split MFMA 1x1 conv (parallel weight fetch) + reduce, then deconv 8->16
  k_wtconvP<<<dim3(4, 8), 256, 0, stream>>>(swint, wBt, wpart);
  k_wtred<<<64, 256, 0, stream>>>(wpart, wt_b, xq0);
  k_deconv8M<<<dim3(4, 4), 256, 0, stream>>>(xq0, dpk, up_db, actB);

  // upsampler chain: MFMA bf16 implicit-GEMM, packed-bf16 activations (A/B ping-pong)
  k_conv3u<16, 2><<<dim3(8, 4), 256, 0, stream>>>(actB, cpk, up_cb, actA);
  k_deconvu<16, 2><<<dim3(8, 4, 2), 256, 0, stream>>>(actA, dpk + 1048576, up_db + 256, actB);
  k_conv3u<32, 2><<<dim3(16, 4), 256, 0, stream>>>(actB, cpk + 589824, up_cb + 256, actA);
  k_deconvu<32, 2><<<dim3(16, 4, 2), 256, 0, stream>>>(actA, dpk + 2 * 1048576, up_db + 512, actB);
  k_conv3v64<<<dim3(64, 4), 512, 0, stream>>>(actB, cpk + 2 * 589824, up_cb + 512, actA);
  k_deconvw64<<<dim3(64, 4, 2), 512, 0, stream>>>(actA, dpk + 3 * 1048576, up_db + 768, actB);
  k_conv3v<<<dim3(128, 4), 512, 0, stream>>>(actB, cpk + 3 * 589824, up_cb + 768, actA);
  k_deconvw<<<dim3(64, 4, 2), 512, 0, stream>>>(actA, dpk + 4 * 1048576, up_db + 1024, actB);

  // final conv3 via MFMA at the 2048 gathered positions -> bf16 srows
  k_conv3sM<<<dim3(128, 2), 256, 0, stream>>>(actB, wB5, up_cb + 1024, idx, srowsb);

  // attention path: MFMA in-projection, fused flash attention, MFMA out-projection
  k_qkv3<<<dim3(128, 12), 256, 0, stream>>>(dq, srowsb, wBi, in_b, Qb, Kb, Vt);
  k_fattn<<<dim3(32, 8), 256, 0, stream>>>(Qb, Kb, Vt, Ob);
  k_outprojM<<<dim3(128, 4), 256, 0, stream>>>(Ob, wBo, out_b, idx, out);
}

// Round 26
// 601.199 us; speedup vs baseline: 1.4456x; 1.0232x over previous
//
#include <hip/hip_runtime.h>
#include <math.h>

#define CCH 256
#define HWP 65536
#define PCI 40   // padded ci stride (shorts) in LDS

typedef short short8 __attribute__((ext_vector_type(8)));
typedef float f32x4 __attribute__((ext_vector_type(4)));
typedef unsigned short us4 __attribute__((ext_vector_type(4)));

__device__ inline unsigned short f2bf(float f) {
  unsigned u = __float_as_uint(f);
  return (unsigned short)((u + 0x7FFFu + ((u >> 16) & 1u)) >> 16);
}
__device__ inline float bf2f(unsigned short s) {
  return __uint_as_float(((unsigned)s) << 16);
}

__device__ inline void mfma_bf16(f32x4& d, short8 a, short8 b) {
  asm volatile("v_mfma_f32_16x16x32_bf16 %0, %1, %2, %0" : "+v"(d) : "v"(a), "v"(b));
}

// ---- ws layout (bytes) ----
static const size_t BUF_B_OFF = 67108864;        // actA @0, actB @64MB
static const size_t TAIL_OFF  = 134217728;
static const size_t KEYS_OFF  = TAIL_OFF;
static const size_t HIST_OFF  = TAIL_OFF + 262144;
static const size_t IDX_OFF   = TAIL_OFF + 263424;
static const size_t EQ_OFF    = TAIL_OFF + 271616;
static const size_t OB_OFF    = 6291456;
static const size_t WBI_OFF   = 8388608;
static const size_t WBO_OFF   = 9437184;
static const size_t SROWS_OFF = 10485760;
static const size_t DQ_OFF    = 12582912;
static const size_t GPART_OFF = 16777216;
static const size_t WT5_OFF   = 20971520;
static const size_t QB_OFF    = 31457280;
static const size_t KB_OFF    = 32505856;
static const size_t VT_OFF    = 33554432;
static const size_t CPK_OFF   = 37748736;
static const size_t DPK_OFF   = 44040192;        // 5 layers x 1048576 shorts -> ends 54525952
static const size_t WTW_OFF   = 54525952;        // bf16 wt_w [256][768] 384KB
static const size_t WPART_OFF = 55050240;        // f32 partials [8][64][256] 512KB
static const size_t XQ0_OFF   = 57671680;        // bf16 stage0 x [64][256]

// merged weight packing: conv3 x4, deconv x5, conv5, in_w, out_w, wt_w
__global__ void k_packall(const float* __restrict__ up_cw, const float* __restrict__ up_dw,
                          const float* __restrict__ in_w, const float* __restrict__ out_w,
                          const float* __restrict__ wt_w,
                          short* __restrict__ cpk, short* __restrict__ dpk,
                          short* __restrict__ wB5, short* __restrict__ wBi,
                          short* __restrict__ wBo, short* __restrict__ wBt) {
  int b = blockIdx.x;
  int tid = threadIdx.x;
  if (b < 1024) {
    int layer = b >> 8, co = b & 255, ci = tid;
    const float* wl = up_cw + (size_t)layer * 589824;
    short* wo = cpk + (size_t)layer * 589824;
    for (int tap = 0; tap < 9; ++tap)
      wo[((size_t)(tap * 256 + co) * 256) + ci] = (short)f2bf(wl[((size_t)(co * 256 + ci)) * 9 + tap]);
  } else if (b < 2304) {
    int bb = b - 1024;
    int layer = bb >> 8, co = bb & 255, ci = tid;
    const float* wl = up_dw + (size_t)layer * 1048576;
    for (int pq = 0; pq < 4; ++pq) {
      int p = pq >> 1, q = pq & 1;
      for (int tt = 0; tt < 4; ++tt) {
        int dyi = tt >> 1, dxi = tt & 1;
        int wr = dyi ? (1 - p) : (3 - p);
        int wc = dxi ? (1 - q) : (3 - q);
        dpk[((size_t)layer * 1048576) + ((size_t)((pq * 4 + tt) * 256 + co) * 256) + ci] =
            (short)f2bf(wl[((size_t)(ci * 256 + co)) * 16 + wr * 4 + wc]);
      }
    }
  } else if (b < 2560) {
    int co = b - 2304;
    const float* w5 = up_cw + 2359296;
    for (int kk = tid; kk < 2304; kk += 256) {
      int c = kk / 288, r = kk % 288;
      int e = r >> 5, cl = r & 31;
      wB5[(size_t)co * 2304 + kk] = (short)f2bf(w5[(size_t)co * 2304 + (size_t)(c * 32 + cl) * 9 + e]);
    }
  } else if (b < 3328) {
    int o = b - 2560;
    wBi[(size_t)o * 256 + tid] = (short)f2bf(in_w[(size_t)o * 256 + tid]);
  } else if (b < 3584) {
    int o = b - 3328;
    wBo[(size_t)o * 256 + tid] = (short)f2bf(out_w[(size_t)o * 256 + tid]);
  } else {
    int co = b - 3584;
    for (int kk = tid; kk < 768; kk += 256)
      wBt[(size_t)co * 768 + kk] = (short)f2bf(wt_w[(size_t)co * 768 + kk]);
  }
}

// gate partials + passthrough copy; block (0,0) zeroes the r0 histogram.
__global__ void k_gatecopy2(const float* __restrict__ down, const float* __restrict__ gw,
                            float* __restrict__ out, float* __restrict__ gpart,
                            unsigned* __restrict__ hist) {
  if (blockIdx.x == 0 && blockIdx.y == 0) hist[threadIdx.x] = 0;
  int p = blockIdx.x * 256 + threadIdx.x;
  int cc = blockIdx.y;
  float acc = 0.f;
  for (int c = cc * 32; c < cc * 32 + 32; ++c) {
    float v = down[(size_t)c * HWP + p];
    out[(size_t)c * HWP + p] = v;
    acc += v * gw[c];
  }
  gpart[(size_t)cc * HWP + p] = acc;
}

// deterministic key reduce + fused round-0 histogram (per-block LDS, 256 blocks)
__global__ void k_gkey(const float* __restrict__ gpart, unsigned* __restrict__ keys,
                       unsigned* __restrict__ hist) {
  __shared__ unsigned lh[256];
  int t = threadIdx.x;
  lh[t] = 0;
  int p = blockIdx.x * 256 + t;
  float s = 0.f;
  for (int cc = 0; cc < 8; ++cc) s += gpart[(size_t)cc * HWP + p];
  unsigned u = __float_as_uint(s);
  unsigned key = (u & 0x80000000u) ? ~u : (u | 0x80000000u);
  keys[p] = key;
  __syncthreads();
  atomicAdd(&lh[key >> 24], 1u);
  __syncthreads();
  if (lh[t]) atomicAdd(&hist[t], lh[t]);
}

// single-block top-k finish v2: parallel suffix-sum pivot scan (no serial 256-loop),
// keys re-read from L2 per phase (no 64-register array / scratch spill).
__global__ __launch_bounds__(1024) void k_select2(const unsigned* __restrict__ keys,
                                                  const unsigned* __restrict__ hist,
                                                  int* __restrict__ idx,
                                                  int* __restrict__ eq) {
  __shared__ unsigned lh[256];
  __shared__ unsigned sS[256];
  __shared__ unsigned sP;
  __shared__ int skneed, snG, snE;
  int t = threadIdx.x;
  if (t == 0) { sP = 0u; skneed = 2048; snG = 0; snE = 0; }
  __syncthreads();
  for (int r = 0; r < 4; ++r) {
    // histogram for this round
    if (r == 0) {
      if (t < 256) lh[t] = hist[t];
      __syncthreads();
    } else {
      if (t < 256) lh[t] = 0;
      __syncthreads();
      unsigned P = sP;
      for (int i = 0; i < 64; ++i) {
        unsigned key = keys[i * 1024 + t];
        if ((key >> (32 - 8 * r)) == P)
          atomicAdd(&lh[(key >> (24 - 8 * r)) & 255u], 1u);
      }
      __syncthreads();
    }
    // parallel suffix sum S[b] = sum_{b'>=b} lh[b'] (Hillis-Steele, 8 steps)
    if (t < 256) sS[t] = lh[t];
    __syncthreads();
    for (int off = 1; off < 256; off <<= 1) {
      unsigned add = 0;
      if (t < 256 && t + off < 256) add = sS[t + off];
      __syncthreads();
      if (t < 256) sS[t] += add;
      __syncthreads();
    }
    // pivot: unique b with S[b] >= need > S[b+1]  (same semantics as serial scan:
    // cum = S[b+1], condition cum + h[b] >= need, new kneed = need - cum)
    if (t < 256) {
      int need = skneed;
      int Sb = (int)sS[t];
      int Sb1 = (t == 255) ? 0 : (int)sS[t + 1];
      if (Sb >= need && Sb1 < need) {
        sP = (sP << 8) | (unsigned)t;
        skneed = need - Sb1;
      }
    }
    __syncthreads();
  }
  // compact (set-equivalent; idx order arbitrary, scatter permutation-invariant)
  {
    unsigned P = sP;
    for (int i = 0; i < 64; ++i) {
      int p = i * 1024 + t;
      unsigned key = keys[p];
      if (key > P) {
        int pos = atomicAdd(&snG, 1);
        idx[pos] = p;
      } else if (key == P) {
        int e = atomicAdd(&snE, 1);
        if (e < 4096) eq[e] = p;
      }
    }
  }
  __syncthreads();
  if (t == 0) {
    int n = snE;
    if (n > 4096) n = 4096;
    for (int i = 1; i < n; ++i) {
      int v = eq[i], j = i - 1;
      while (j >= 0 && eq[j] > v) { eq[j + 1] = eq[j]; --j; }
      eq[j + 1] = v;
    }
    int g = snG;
    for (int i = 0; i < skneed; ++i) idx[g + i] = eq[i];
  }
}

// gather down rows at idx -> bf16 dq[2048][256]
__global__ void k_gatherq(const float* __restrict__ down, const int* __restrict__ idx,
                          short* __restrict__ dq) {
  int j = blockIdx.x, c = threadIdx.x;
  int p = idx[j];
  dq[(size_t)j * 256 + c] = (short)f2bf(down[(size_t)c * HWP + p]);
}

// K-split MFMA 1x1 conv 768->256: grid (4 co-tiles, 8 ksplits). f32 partials out.
__global__ __launch_bounds__(256) void k_wtconvP(const float* __restrict__ swint,
                                                 const short* __restrict__ wBt,
                                                 float* __restrict__ wpart) {
  __shared__ short x_s[64 * 40];
  int t = threadIdx.x, l = t & 63, wv = t >> 6;
  int co0 = blockIdx.x * 64;
  int ks = blockIdx.y;
  int kbase = ks * 96;
  f32x4 acc[4];
#pragma unroll
  for (int m = 0; m < 4; ++m) { f32x4 z = {0.f, 0.f, 0.f, 0.f}; acc[m] = z; }
#pragma unroll
  for (int cc = 0; cc < 3; ++cc) {
    int c0 = kbase + cc * 32;
    __syncthreads();
    {
      int ci = t >> 3, pos0 = (t & 7) * 8;
      const float* sp = swint + (size_t)(c0 + ci) * 64 + pos0;
#pragma unroll
      for (int pp = 0; pp < 8; ++pp)
        x_s[(pos0 + pp) * 40 + ci] = (short)f2bf(sp[pp]);
    }
    __syncthreads();
    short8 bfrag = *(const short8*)&x_s[(wv * 16 + (l & 15)) * 40 + (l >> 4) * 8];
#pragma unroll
    for (int m = 0; m < 4; ++m) {
      short8 af = *(const short8*)&wBt[(size_t)(co0 + m * 16 + (l & 15)) * 768 + c0 + (l >> 4) * 8];
      mfma_bf16(acc[m], af, bfrag);
    }
  }
  asm volatile("s_nop 7\n\ts_nop 7" ::);
  int pos = wv * 16 + (l & 15);
#pragma unroll
  for (int m = 0; m < 4; ++m)
#pragma unroll
    for (int r = 0; r < 4; ++r) {
      int co = co0 + m * 16 + (l >> 4) * 4 + r;
      wpart[((size_t)ks * 64 + pos) * 256 + co] = acc[m][r];
    }
}

// deterministic reduce of 8 K-split partials + bias -> bf16 xq0[pos][co]
__global__ void k_wtred(const float* __restrict__ wpart, const float* __restrict__ bias,
                        short* __restrict__ xq0) {
  int pos = blockIdx.x, co = threadIdx.x;
  float s = bias[co];
  for (int ks = 0; ks < 8; ++ks) s += wpart[((size_t)ks * 64 + pos) * 256 + co];
  xq0[(size_t)pos * 256 + co] = (short)f2bf(s);
}

// MFMA deconv 8->16 (stage 0) + bias + relu. grid (4 co-tiles, 4 pq). Packed out.
__global__ __launch_bounds__(256) void k_deconv8M(const short* __restrict__ xq0,
                                                  const short* __restrict__ wpk,
                                                  const float* __restrict__ bias,
                                                  unsigned* __restrict__ yp) {
  __shared__ short x_s[121 * 260];
  int t = threadIdx.x, l = t & 63, wv = t >> 6;
  int co0 = blockIdx.x * 64;
  int pq = blockIdx.y, p = pq >> 1, q = pq & 1;
  const unsigned* xs32 = (const unsigned*)xq0;
  for (int i = t; i < 121 * 128; i += 256) {
    int row = i >> 7, c2 = i & 127;
    int iy = row / 11 - 1, ix = row % 11 - 1;
    unsigned v = 0;
    if (iy >= 0 && iy < 8 && ix >= 0 && ix < 8)
      v = xs32[(size_t)(iy * 8 + ix) * 128 + c2];
    *(unsigned*)&x_s[row * 260 + 2 * c2] = v;
  }
  __syncthreads();
  f32x4 acc[4];
#pragma unroll
  for (int m = 0; m < 4; ++m) { f32x4 z = {0.f, 0.f, 0.f, 0.f}; acc[m] = z; }
  int pos = wv * 16 + (l & 15);
  int ay = pos >> 3, bx = pos & 7;
#pragma unroll
  for (int tt = 0; tt < 4; ++tt) {
    int dyi = tt >> 1, dxi = tt & 1;
    int rowx = (ay + p + dyi) * 11 + (bx + q + dxi);
#pragma unroll
    for (int c0 = 0; c0 < 256; c0 += 32) {
      short8 bfrag = *(const short8*)&x_s[rowx * 260 + c0 + (l >> 4) * 8];
#pragma unroll
      for (int m = 0; m < 4; ++m) {
        short8 af = *(const short8*)&wpk[((size_t)((pq * 4 + tt) * 256 + co0 + m * 16 + (l & 15)) * 256) + c0 + (l >> 4) * 8];
        mfma_bf16(acc[m], af, bfrag);
      }
    }
  }
  asm volatile("s_nop 7\n\ts_nop 7" ::);
  int oy = 2 * ay + p, ox = 2 * bx + q;
#pragma unroll
  for (int m = 0; m < 4; ++m)
#pragma unroll
    for (int r4p = 0; r4p < 2; ++r4p) {
      int cob = co0 + m * 16 + (l >> 4) * 4 + 2 * r4p;
      unsigned pk = (unsigned)f2bf(fmaxf(acc[m][2 * r4p] + bias[cob], 0.f))
                  | ((unsigned)f2bf(fmaxf(acc[m][2 * r4p + 1] + bias[cob + 1], 0.f)) << 16);
      yp[(size_t)(cob >> 1) * 256 + oy * 16 + ox] = pk;
    }
}

// MFMA conv3x3 pad1 + bias, O output rows per block. Weights direct-from-global.
template <int S, int O>
__global__ __launch_bounds__(256) void k_conv3u(const unsigned* __restrict__ xp,
                                                const short* __restrict__ wpk,
                                                const float* __restrict__ bias,
                                                unsigned* __restrict__ yp) {
  constexpr int WPC = (S >= 64) ? 2 : 1;
  constexpr int WCO = 4 / WPC;
  constexpr int COS = 64 / WCO;
  constexpr int MR = COS / 16;
  constexpr int PSP = S / WPC;
  constexpr int NR = PSP / 16;
  constexpr int CBK = (S + 2 + 31) / 32;
  constexpr int RS = O + 2;
  __shared__ short x_s[RS * (S + 2) * PCI];
  unsigned* x_s32 = (unsigned*)x_s;
  int t = threadIdx.x, l = t & 63, wv = t >> 6;
  int wcob = (wv % WCO) * COS;
  int wposb = (wv / WCO) * PSP;
  int row0 = blockIdx.x * O;
  int co0 = blockIdx.y * 64;
  int colb = t & 31, ci2b = t >> 5;
  f32x4 acc[O][MR][NR];
#pragma unroll
  for (int o = 0; o < O; ++o)
#pragma unroll
    for (int m = 0; m < MR; ++m)
#pragma unroll
      for (int n = 0; n < NR; ++n) { f32x4 z = {0.f, 0.f, 0.f, 0.f}; acc[o][m][n] = z; }
  for (int c0 = 0; c0 < CCH; c0 += 32) {
    int cb = c0 >> 1;
    __syncthreads();
#pragma unroll
    for (int r = 0; r < RS; ++r) {
      int gy = row0 - 1 + r;
      bool yok = (gy >= 0 && gy < S);
#pragma unroll
      for (int cbk = 0; cbk < CBK; ++cbk) {
        int col = colb + cbk * 32;
        if (col < S + 2) {
          int gx = col - 1;
          bool ok = yok && (gx >= 0) && (gx < S);
          unsigned v0 = 0, v1 = 0;
          if (ok) {
            size_t gbase = (size_t)(cb + ci2b) * S * S + (size_t)gy * S + gx;
            v0 = xp[gbase];
            v1 = xp[gbase + (size_t)8 * S * S];
          }
          int lb = (r * (S + 2) + col) * (PCI / 2);
          x_s32[lb + ci2b] = v0;
          x_s32[lb + ci2b + 8] = v1;
        }
      }
    }
    __syncthreads();
#pragma unroll
    for (int dyg = 0; dyg < 3; ++dyg)
#pragma unroll
      for (int dx = 0; dx < 3; ++dx) {
        short8 a[MR];
#pragma unroll
        for (int m = 0; m < MR; ++m)
          a[m] = *(const short8*)&wpk[((size_t)((dyg * 3 + dx) * 256 + co0 + wcob + m * 16 + (l & 15)) * 256) + c0 + (l >> 4) * 8];
#pragma unroll
        for (int o = 0; o < O; ++o) {
          short8 b[NR];
#pragma unroll
          for (int n = 0; n < NR; ++n)
            b[n] = *(const short8*)&x_s[((dyg + o) * (S + 2) + wposb + n * 16 + (l & 15) + dx) * PCI + (l >> 4) * 8];
#pragma unroll
          for (int m = 0; m < MR; ++m)
#pragma unroll
            for (int n = 0; n < NR; ++n) mfma_bf16(acc[o][m][n], a[m], b[n]);
        }
      }
  }
  asm volatile("s_nop 7\n\ts_nop 7" ::);
#pragma unroll
  for (int o = 0; o < O; ++o)
#pragma unroll
    for (int m = 0; m < MR; ++m)
#pragma unroll
      for (int n = 0; n < NR; ++n) {
        int cob = co0 + wcob + m * 16 + (l >> 4) * 4;
        int px = wposb + n * 16 + (l & 15);
#pragma unroll
        for (int r4p = 0; r4p < 2; ++r4p) {
          unsigned pk = (unsigned)f2bf(acc[o][m][n][2 * r4p] + bias[cob + 2 * r4p])
                      | ((unsigned)f2bf(acc[o][m][n][2 * r4p + 1] + bias[cob + 2 * r4p + 1]) << 16);
          yp[(size_t)((cob >> 1) + r4p) * S * S + (size_t)(row0 + o) * S + px] = pk;
        }
      }
}

// 512-thread conv3 for S=128 with LDS-staged weights: 8 waves, 2 blocks/CU.
__global__ __launch_bounds__(512) void k_conv3v(const unsigned* __restrict__ xp,
                                                const short* __restrict__ wpk,
                                                const float* __restrict__ bias,
                                                unsigned* __restrict__ yp) {
  constexpr int S = 128;
  constexpr int MR = 2;
  constexpr int PSP = 32;
  constexpr int NR = 2;
  __shared__ short x_s[3 * (S + 2) * PCI];
  __shared__ short w_s[9 * 64 * PCI];
  unsigned* x_s32 = (unsigned*)x_s;
  int t = threadIdx.x, l = t & 63, wv = t >> 6;
  int wcob = (wv & 1) * 32;
  int wposb = (wv >> 1) * PSP;
  int row0 = blockIdx.x;
  int co0 = blockIdx.y * 64;
  int colb = t & 31, ci2b = t >> 5;
  f32x4 acc[MR][NR];
#pragma unroll
  for (int m = 0; m < MR; ++m)
#pragma unroll
    for (int n = 0; n < NR; ++n) { f32x4 z = {0.f, 0.f, 0.f, 0.f}; acc[m][n] = z; }
  for (int c0 = 0; c0 < CCH; c0 += 32) {
    int cb = c0 >> 1;
    __syncthreads();
#pragma unroll
    for (int r = 0; r < 3; ++r) {
      int gy = row0 - 1 + r;
      bool yok = (gy >= 0 && gy < S);
#pragma unroll
      for (int cbk = 0; cbk < 5; ++cbk) {
        int col = colb + cbk * 32;
        if (col < S + 2) {
          int gx = col - 1;
          bool ok = yok && (gx >= 0) && (gx < S);
          unsigned v = 0;
          if (ok)
            v = xp[(size_t)(cb + ci2b) * S * S + (size_t)gy * S + gx];
          x_s32[(r * (S + 2) + col) * (PCI / 2) + ci2b] = v;
        }
      }
    }
    for (int i = t; i < 4608; i += 512) {
      int seg8 = i & 7;
      int rowi = i >> 3;
      int tap = rowi >> 6, co = rowi & 63;
      us4 wv4 = *(const us4*)&wpk[((size_t)(tap * 256 + co0 + co) * 256) + c0 + seg8 * 4];
      *(us4*)&w_s[rowi * PCI + seg8 * 4] = wv4;
    }
    __syncthreads();
#pragma unroll
    for (int dyg = 0; dyg < 3; ++dyg)
#pragma unroll
      for (int dx = 0; dx < 3; ++dx) {
        short8 a[MR];
#pragma unroll
        for (int m = 0; m < MR; ++m)
          a[m] = *(const short8*)&w_s[((dyg * 3 + dx) * 64 + wcob + m * 16 + (l & 15)) * PCI + (l >> 4) * 8];
        short8 b[NR];
#pragma unroll
        for (int n = 0; n < NR; ++n)
          b[n] = *(const short8*)&x_s[(dyg * (S + 2) + wposb + n * 16 + (l & 15) + dx) * PCI + (l >> 4) * 8];
#pragma unroll
        for (int m = 0; m < MR; ++m)
#pragma unroll
          for (int n = 0; n < NR; ++n) mfma_bf16(acc[m][n], a[m], b[n]);
      }
  }
  asm volatile("s_nop 7\n\ts_nop 7" ::);
#pragma unroll
  for (int m = 0; m < MR; ++m)
#pragma unroll
    for (int n = 0; n < NR; ++n) {
      int cob = co0 + wcob + m * 16 + (l >> 4) * 4;
      int px = wposb + n * 16 + (l & 15);
#pragma unroll
      for (int r4p = 0; r4p < 2; ++r4p) {
        unsigned pk = (unsigned)f2bf(acc[m][n][2 * r4p] + bias[cob + 2 * r4p])
                    | ((unsigned)f2bf(acc[m][n][2 * r4p + 1] + bias[cob + 2 * r4p + 1]) << 16);
        yp[(size_t)((cob >> 1) + r4p) * S * S + (size_t)row0 * S + px] = pk;
      }
    }
}

// 512-thread conv3 for S=64 with LDS-staged weights: 8 waves (MR=2, NR=1),
// grid (64, 4). x_s 15.8KB + w_s 46KB = 62KB.
__global__ __launch_bounds__(512) void k_conv3v64(const unsigned* __restrict__ xp,
                                                  const short* __restrict__ wpk,
                                                  const float* __restrict__ bias,
                                                  unsigned* __restrict__ yp) {
  constexpr int S = 64;
  constexpr int MR = 2;
  __shared__ short x_s[3 * (S + 2) * PCI];
  __shared__ short w_s[9 * 64 * PCI];
  unsigned* x_s32 = (unsigned*)x_s;
  int t = threadIdx.x, l = t & 63, wv = t >> 6;
  int wcob = (wv & 1) * 32;
  int wposb = (wv >> 1) * 16;
  int row0 = blockIdx.x;
  int co0 = blockIdx.y * 64;
  int colb = t & 31, ci2b = t >> 5;
  f32x4 acc[MR];
#pragma unroll
  for (int m = 0; m < MR; ++m) { f32x4 z = {0.f, 0.f, 0.f, 0.f}; acc[m] = z; }
  for (int c0 = 0; c0 < CCH; c0 += 32) {
    int cb = c0 >> 1;
    __syncthreads();
#pragma unroll
    for (int r = 0; r < 3; ++r) {
      int gy = row0 - 1 + r;
      bool yok = (gy >= 0 && gy < S);
#pragma unroll
      for (int cbk = 0; cbk < 3; ++cbk) {
        int col = colb + cbk * 32;
        if (col < S + 2) {
          int gx = col - 1;
          bool ok = yok && (gx >= 0) && (gx < S);
          unsigned v = 0;
          if (ok)
            v = xp[(size_t)(cb + ci2b) * S * S + (size_t)gy * S + gx];
          x_s32[(r * (S + 2) + col) * (PCI / 2) + ci2b] = v;
        }
      }
    }
    for (int i = t; i < 4608; i += 512) {
      int seg8 = i & 7;
      int rowi = i >> 3;
      int tap = rowi >> 6, co = rowi & 63;
      us4 wv4 = *(const us4*)&wpk[((size_t)(tap * 256 + co0 + co) * 256) + c0 + seg8 * 4];
      *(us4*)&w_s[rowi * PCI + seg8 * 4] = wv4;
    }
    __syncthreads();
#pragma unroll
    for (int dyg = 0; dyg < 3; ++dyg)
#pragma unroll
      for (int dx = 0; dx < 3; ++dx) {
        short8 a[MR];
#pragma unroll
        for (int m = 0; m < MR; ++m)
          a[m] = *(const short8*)&w_s[((dyg * 3 + dx) * 64 + wcob + m * 16 + (l & 15)) * PCI + (l >> 4) * 8];
        short8 b = *(const short8*)&x_s[(dyg * (S + 2) + wposb + (l & 15) + dx) * PCI + (l >> 4) * 8];
#pragma unroll
        for (int m = 0; m < MR; ++m) mfma_bf16(acc[m], a[m], b);
      }
  }
  asm volatile("s_nop 7\n\ts_nop 7" ::);
#pragma unroll
  for (int m = 0; m < MR; ++m) {
    int cob = co0 + wcob + m * 16 + (l >> 4) * 4;
    int px = wposb + (l & 15);
#pragma unroll
    for (int r4p = 0; r4p < 2; ++r4p) {
      unsigned pk = (unsigned)f2bf(acc[m][2 * r4p] + bias[cob + 2 * r4p])
                  | ((unsigned)f2bf(acc[m][2 * r4p + 1] + bias[cob + 2 * r4p + 1]) << 16);
      yp[(size_t)((cob >> 1) + r4p) * S * S + (size_t)row0 * S + px] = pk;
    }
  }
}

// MFMA deconv4x4 s2 p2 + bias + relu, O input rows + both q parities per block.
// LDS-staged weights (r13 form, 256 threads). Used for S=16,32.
template <int S, int O>
__global__ __launch_bounds__(256) void k_deconvu(const unsigned* __restrict__ xp,
                                                 const short* __restrict__ wpk,
                                                 const float* __restrict__ bias,
                                                 unsigned* __restrict__ yp) {
  constexpr int WPC = (S >= 64) ? 2 : 1;
  constexpr int WCO = 4 / WPC;
  constexpr int COS = 64 / WCO;
  constexpr int MR = COS / 16;
  constexpr int PSP = S / WPC;
  constexpr int NR = PSP / 16;
  constexpr int CBK = (S + 2 + 31) / 32;
  constexpr int RS = O + 1;
  const int SO = 2 * S;
  __shared__ short x_s[RS * (S + 2) * PCI];
  __shared__ short w_s[8 * 64 * PCI];
  unsigned* x_s32 = (unsigned*)x_s;
  int t = threadIdx.x, l = t & 63, wv = t >> 6;
  int wcob = (wv % WCO) * COS;
  int wposb = (wv / WCO) * PSP;
  int row0 = blockIdx.x * O;
  int co0 = blockIdx.y * 64;
  int p = blockIdx.z;
  int colb = t & 31, ci2b = t >> 5;
  f32x4 acc[2][O][MR][NR];
#pragma unroll
  for (int q = 0; q < 2; ++q)
#pragma unroll
    for (int o = 0; o < O; ++o)
#pragma unroll
      for (int m = 0; m < MR; ++m)
#pragma unroll
        for (int n = 0; n < NR; ++n) { f32x4 z = {0.f, 0.f, 0.f, 0.f}; acc[q][o][m][n] = z; }
  for (int c0 = 0; c0 < CCH; c0 += 32) {
    int cb = c0 >> 1;
    __syncthreads();
#pragma unroll
    for (int r = 0; r < RS; ++r) {
      int gy = row0 + p - 1 + r;
      bool yok = (gy >= 0 && gy < S);
#pragma unroll
      for (int cbk = 0; cbk < CBK; ++cbk) {
        int col = colb + cbk * 32;
        if (col < S + 2) {
          int gx = col - 1;
          bool ok = yok && (gx >= 0) && (gx < S);
          unsigned v0 = 0, v1 = 0;
          if (ok) {
            size_t gbase = (size_t)(cb + ci2b) * S * S + (size_t)gy * S + gx;
            v0 = xp[gbase];
            v1 = xp[gbase + (size_t)8 * S * S];
          }
          int lb = (r * (S + 2) + col) * (PCI / 2);
          x_s32[lb + ci2b] = v0;
          x_s32[lb + ci2b + 8] = v1;
        }
      }
    }
    for (int i = t; i < 4096; i += 256) {
      int seg8 = i & 7;
      int rowi = i >> 3;
      int c8 = rowi >> 6, co = rowi & 63;
      int qq = c8 >> 2, tt = c8 & 3;
      us4 wv4 = *(const us4*)&wpk[((size_t)(((2 * p + qq) * 4 + tt) * 256 + co0 + co) * 256) + c0 + seg8 * 4];
      *(us4*)&w_s[rowi * PCI + seg8 * 4] = wv4;
    }
    __syncthreads();
#pragma unroll
    for (int dyi = 0; dyi < 2; ++dyi)
#pragma unroll
      for (int o = 0; o < O; ++o) {
        short8 b[3][NR];
#pragma unroll
        for (int off = 0; off < 3; ++off)
#pragma unroll
          for (int n = 0; n < NR; ++n)
            b[off][n] = *(const short8*)&x_s[((dyi + o) * (S + 2) + wposb + n * 16 + (l & 15) + off) * PCI + (l >> 4) * 8];
#pragma unroll
        for (int q = 0; q < 2; ++q)
#pragma unroll
          for (int dxi = 0; dxi < 2; ++dxi) {
            int c8 = q * 4 + dyi * 2 + dxi;
            short8 a[MR];
#pragma unroll
            for (int m = 0; m < MR; ++m)
              a[m] = *(const short8*)&w_s[(c8 * 64 + wcob + m * 16 + (l & 15)) * PCI + (l >> 4) * 8];
#pragma unroll
            for (int m = 0; m < MR; ++m)
#pragma unroll
              for (int n = 0; n < NR; ++n) mfma_bf16(acc[q][o][m][n], a[m], b[dxi + q][n]);
          }
      }
  }
  asm volatile("s_nop 7\n\ts_nop 7" ::);
#pragma unroll
  for (int o = 0; o < O; ++o) {
    int oy = 2 * (row0 + o) + p;
#pragma unroll
    for (int m = 0; m < MR; ++m)
#pragma unroll
      for (int n = 0; n < NR; ++n) {
        int px = wposb + n * 16 + (l & 15);
#pragma unroll
        for (int r4p = 0; r4p < 2; ++r4p) {
          int cob = co0 + wcob + m * 16 + (l >> 4) * 4 + 2 * r4p;
          float b0 = bias[cob], b1 = bias[cob + 1];
          unsigned pk0 = (unsigned)f2bf(fmaxf(acc[0][o][m][n][2 * r4p] + b0, 0.f))
                       | ((unsigned)f2bf(fmaxf(acc[0][o][m][n][2 * r4p + 1] + b1, 0.f)) << 16);
          unsigned pk1 = (unsigned)f2bf(fmaxf(acc[1][o][m][n][2 * r4p] + b0, 0.f))
                       | ((unsigned)f2bf(fmaxf(acc[1][o][m][n][2 * r4p + 1] + b1, 0.f)) << 16);
          uint2 pk = make_uint2(pk0, pk1);
          *(uint2*)&yp[(size_t)(cob >> 1) * SO * SO + (size_t)oy * SO + 2 * px] = pk;
        }
      }
  }
}

// 512-thread deconv for S=128, O=2: 8 waves/block, 2 blocks/CU.
__global__ __launch_bounds__(512) void k_deconvw(const unsigned* __restrict__ xp,
                                                 const short* __restrict__ wpk,
                                                 const float* __restrict__ bias,
                                                 unsigned* __restrict__ yp) {
  constexpr int S = 128;
  constexpr int O = 2;
  constexpr int MR = 2;
  constexpr int PSP = 32;
  constexpr int NR = 2;
  constexpr int RS = O + 1;
  const int SO = 2 * S;
  __shared__ short x_s[RS * (S + 2) * PCI];
  __shared__ short w_s[8 * 64 * PCI];
  unsigned* x_s32 = (unsigned*)x_s;
  int t = threadIdx.x, l = t & 63, wv = t >> 6;
  int wcob = (wv & 1) * 32;
  int wposb = (wv >> 1) * PSP;
  int row0 = blockIdx.x * O;
  int co0 = blockIdx.y * 64;
  int p = blockIdx.z;
  int colb = t & 31, ci2b = t >> 5;
  f32x4 acc[2][O][MR][NR];
#pragma unroll
  for (int q = 0; q < 2; ++q)
#pragma unroll
    for (int o = 0; o < O; ++o)
#pragma unroll
      for (int m = 0; m < MR; ++m)
#pragma unroll
        for (int n = 0; n < NR; ++n) { f32x4 z = {0.f, 0.f, 0.f, 0.f}; acc[q][o][m][n] = z; }
  for (int c0 = 0; c0 < CCH; c0 += 32) {
    int cb = c0 >> 1;
    __syncthreads();
#pragma unroll
    for (int r = 0; r < RS; ++r) {
      int gy = row0 + p - 1 + r;
      bool yok = (gy >= 0 && gy < S);
#pragma unroll
      for (int cbk = 0; cbk < 5; ++cbk) {
        int col = colb + cbk * 32;
        if (col < S + 2) {
          int gx = col - 1;
          bool ok = yok && (gx >= 0) && (gx < S);
          unsigned v = 0;
          if (ok)
            v = xp[(size_t)(cb + ci2b) * S * S + (size_t)gy * S + gx];
          x_s32[(r * (S + 2) + col) * (PCI / 2) + ci2b] = v;
        }
      }
    }
    for (int i = t; i < 4096; i += 512) {
      int seg8 = i & 7;
      int rowi = i >> 3;
      int c8 = rowi >> 6, co = rowi & 63;
      int qq = c8 >> 2, tt = c8 & 3;
      us4 wv4 = *(const us4*)&wpk[((size_t)(((2 * p + qq) * 4 + tt) * 256 + co0 + co) * 256) + c0 + seg8 * 4];
      *(us4*)&w_s[rowi * PCI + seg8 * 4] = wv4;
    }
    __syncthreads();
#pragma unroll
    for (int dyi = 0; dyi < 2; ++dyi)
#pragma unroll
      for (int o = 0; o < O; ++o) {
        short8 b[3][NR];
#pragma unroll
        for (int off = 0; off < 3; ++off)
#pragma unroll
          for (int n = 0; n < NR; ++n)
            b[off][n] = *(const short8*)&x_s[((dyi + o) * (S + 2) + wposb + n * 16 + (l & 15) + off) * PCI + (l >> 4) * 8];
#pragma unroll
        for (int q = 0; q < 2; ++q)
#pragma unroll
          for (int dxi = 0; dxi < 2; ++dxi) {
            int c8 = q * 4 + dyi * 2 + dxi;
            short8 a[MR];
#pragma unroll
            for (int m = 0; m < MR; ++m)
              a[m] = *(const short8*)&w_s[(c8 * 64 + wcob + m * 16 + (l & 15)) * PCI + (l >> 4) * 8];
#pragma unroll
            for (int m = 0; m < MR; ++m)
#pragma unroll
              for (int n = 0; n < NR; ++n) mfma_bf16(acc[q][o][m][n], a[m], b[dxi + q][n]);
          }
      }
  }
  asm volatile("s_nop 7\n\ts_nop 7" ::);
#pragma unroll
  for (int o = 0; o < O; ++o) {
    int oy = 2 * (row0 + o) + p;
#pragma unroll
    for (int m = 0; m < MR; ++m)
#pragma unroll
      for (int n = 0; n < NR; ++n) {
        int px = wposb + n * 16 + (l & 15);
#pragma unroll
        for (int r4p = 0; r4p < 2; ++r4p) {
          int cob = co0 + wcob + m * 16 + (l >> 4) * 4 + 2 * r4p;
          float b0 = bias[cob], b1 = bias[cob + 1];
          unsigned pk0 = (unsigned)f2bf(fmaxf(acc[0][o][m][n][2 * r4p] + b0, 0.f))
                       | ((unsigned)f2bf(fmaxf(acc[0][o][m][n][2 * r4p + 1] + b1, 0.f)) << 16);
          unsigned pk1 = (unsigned)f2bf(fmaxf(acc[1][o][m][n][2 * r4p] + b0, 0.f))
                       | ((unsigned)f2bf(fmaxf(acc[1][o][m][n][2 * r4p + 1] + b1, 0.f)) << 16);
          uint2 pk = make_uint2(pk0, pk1);
          *(uint2*)&yp[(size_t)(cob >> 1) * SO * SO + (size_t)oy * SO + 2 * px] = pk;
        }
      }
  }
}

// 512-thread deconv for S=64, O=1: 8 waves (MR=2, NR=1), grid (64,4,2).
__global__ __launch_bounds__(512) void k_deconvw64(const unsigned* __restrict__ xp,
                                                   const short* __restrict__ wpk,
                                                   const float* __restrict__ bias,
                                                   unsigned* __restrict__ yp) {
  constexpr int S = 64;
  constexpr int MR = 2;
  const int SO = 2 * S;
  __shared__ short x_s[2 * (S + 2) * PCI];
  __shared__ short w_s[8 * 64 * PCI];
  unsigned* x_s32 = (unsigned*)x_s;
  int t = threadIdx.x, l = t & 63, wv = t >> 6;
  int wcob = (wv & 1) * 32;
  int wposb = (wv >> 1) * 16;
  int row0 = blockIdx.x;
  int co0 = blockIdx.y * 64;
  int p = blockIdx.z;
  int colb = t & 31, ci2b = t >> 5;
  f32x4 acc[2][MR];   // [q][m]
#pragma unroll
  for (int q = 0; q < 2; ++q)
#pragma unroll
    for (int m = 0; m < MR; ++m) { f32x4 z = {0.f, 0.f, 0.f, 0.f}; acc[q][m] = z; }
  for (int c0 = 0; c0 < CCH; c0 += 32) {
    int cb = c0 >> 1;
    __syncthreads();
#pragma unroll
    for (int r = 0; r < 2; ++r) {
      int gy = row0 + p - 1 + r;
      bool yok = (gy >= 0 && gy < S);
#pragma unroll
      for (int cbk = 0; cbk < 3; ++cbk) {
        int col = colb + cbk * 32;
        if (col < S + 2) {
          int gx = col - 1;
          bool ok = yok && (gx >= 0) && (gx < S);
          unsigned v = 0;
          if (ok)
            v = xp[(size_t)(cb + ci2b) * S * S + (size_t)gy * S + gx];
          x_s32[(r * (S + 2) + col) * (PCI / 2) + ci2b] = v;
        }
      }
    }
    for (int i = t; i < 4096; i += 512) {
      int seg8 = i & 7;
      int rowi = i >> 3;
      int c8 = rowi >> 6, co = rowi & 63;
      int qq = c8 >> 2, tt = c8 & 3;
      us4 wv4 = *(const us4*)&wpk[((size_t)(((2 * p + qq) * 4 + tt) * 256 + co0 + co) * 256) + c0 + seg8 * 4];
      *(us4*)&w_s[rowi * PCI + seg8 * 4] = wv4;
    }
    __syncthreads();
#pragma unroll
    for (int dyi = 0; dyi < 2; ++dyi) {
      short8 b[3];
#pragma unroll
      for (int off = 0; off < 3; ++off)
        b[off] = *(const short8*)&x_s[(dyi * (S + 2) + wposb + (l & 15) + off) * PCI + (l >> 4) * 8];
#pragma unroll
      for (int q = 0; q < 2; ++q)
#pragma unroll
        for (int dxi = 0; dxi < 2; ++dxi) {
          int c8 = q * 4 + dyi * 2 + dxi;
          short8 a[MR];
#pragma unroll
          for (int m = 0; m < MR; ++m)
            a[m] = *(const short8*)&w_s[(c8 * 64 + wcob + m * 16 + (l & 15)) * PCI + (l >> 4) * 8];
#pragma unroll
          for (int m = 0; m < MR; ++m) mfma_bf16(acc[q][m], a[m], b[dxi + q]);
        }
    }
  }
  asm volatile("s_nop 7\n\ts_nop 7" ::);
  int oy = 2 * row0 + p;
#pragma unroll
  for (int m = 0; m < MR; ++m) {
    int px = wposb + (l & 15);
#pragma unroll
    for (int r4p = 0; r4p < 2; ++r4p) {
      int cob = co0 + wcob + m * 16 + (l >> 4) * 4 + 2 * r4p;
      float b0 = bias[cob], b1 = bias[cob + 1];
      unsigned pk0 = (unsigned)f2bf(fmaxf(acc[0][m][2 * r4p] + b0, 0.f))
                   | ((unsigned)f2bf(fmaxf(acc[0][m][2 * r4p + 1] + b1, 0.f)) << 16);
      unsigned pk1 = (unsigned)f2bf(fmaxf(acc[1][m][2 * r4p] + b0, 0.f))
                   | ((unsigned)f2bf(fmaxf(acc[1][m][2 * r4p + 1] + b1, 0.f)) << 16);
      uint2 pk = make_uint2(pk0, pk1);
      *(uint2*)&yp[(size_t)(cob >> 1) * SO * SO + (size_t)oy * SO + 2 * px] = pk;
    }
  }
}

// sparse final conv3 via MFMA -> bf16 srows
__global__ __launch_bounds__(256) void k_conv3sM(const unsigned* __restrict__ xp,
                                                 const short* __restrict__ wB,
                                                 const float* __restrict__ bias,
                                                 const int* __restrict__ idx,
                                                 short* __restrict__ outb) {
  __shared__ short a_s[16][296];
  __shared__ int py_s[16], px_s[16];
  int t = threadIdx.x, l = t & 63, wv = t >> 6;
  int j0 = blockIdx.x * 16;
  int co0 = blockIdx.y * 128 + wv * 32;
  if (t < 16) {
    int p = idx[j0 + t];
    py_s[t] = p >> 8;
    px_s[t] = p & 255;
  }
  f32x4 acc[2];
  { f32x4 z = {0.f, 0.f, 0.f, 0.f}; acc[0] = z; acc[1] = z; }
  for (int c = 0; c < 8; ++c) {
    __syncthreads();
    for (int i = t; i < 2304; i += 256) {
      int ci2 = i & 15;
      int je = i >> 4;
      int j = je / 9, e = je % 9;
      int gy = py_s[j] - 1 + e / 3, gx = px_s[j] - 1 + e % 3;
      unsigned v = 0;
      if (gy >= 0 && gy < 256 && gx >= 0 && gx < 256)
        v = xp[(size_t)(c * 16 + ci2) * HWP + gy * 256 + gx];
      *(unsigned*)&a_s[j][e * 32 + 2 * ci2] = v;
    }
    __syncthreads();
#pragma unroll
    for (int s = 0; s < 9; ++s) {
      short8 a = *(const short8*)&a_s[l & 15][s * 32 + (l >> 4) * 8];
      int kg = c * 288 + s * 32 + (l >> 4) * 8;
      short8 b0 = *(const short8*)&wB[(size_t)(co0 + (l & 15)) * 2304 + kg];
      short8 b1 = *(const short8*)&wB[(size_t)(co0 + 16 + (l & 15)) * 2304 + kg];
      mfma_bf16(acc[0], a, b0);
      mfma_bf16(acc[1], a, b1);
    }
  }
  asm volatile("s_nop 7\n\ts_nop 7" ::);
#pragma unroll
  for (int n = 0; n < 2; ++n)
#pragma unroll
    for (int r = 0; r < 4; ++r) {
      int j = j0 + (l >> 4) * 4 + r;
      int co = co0 + n * 16 + (l & 15);
      outb[(size_t)j * 256 + co] = (short)f2bf(acc[n][r] + bias[co]);
    }
}

// MFMA in-projection: grid (128 j-tiles, 12 out-tiles of 64). 0-3=Q, 4-7=K, 8-11=V.
__global__ __launch_bounds__(256) void k_qkv3(const short* __restrict__ dq,
                                              const short* __restrict__ sr,
                                              const short* __restrict__ wBi,
                                              const float* __restrict__ bias,
                                              short* __restrict__ Qb,
                                              short* __restrict__ Kb,
                                              short* __restrict__ Vt) {
  __shared__ short a_s[16 * 264];
  unsigned* a_s32 = (unsigned*)a_s;
  int t = threadIdx.x, l = t & 63, wv = t >> 6;
  int j0 = blockIdx.x * 16;
  int third = blockIdx.y >> 2;
  const unsigned* s32 = (const unsigned*)(third ? sr : dq);
  for (int i = t; i < 2048; i += 256) {
    int row = i >> 7, c2 = i & 127;
    a_s32[row * 132 + c2] = s32[(size_t)(j0 + row) * 128 + c2];
  }
  __syncthreads();
  int cog = blockIdx.y * 64 + wv * 16 + (l & 15);
  f32x4 acc = {0.f, 0.f, 0.f, 0.f};
  const short* brow = wBi + (size_t)cog * 256 + (l >> 4) * 8;
  const short* arow = a_s + (l & 15) * 264 + (l >> 4) * 8;
#pragma unroll
  for (int kc = 0; kc < 8; ++kc) {
    short8 a = *(const short8*)(arow + kc * 32);
    short8 b = *(const short8*)(brow + kc * 32);
    mfma_bf16(acc, a, b);
  }
  asm volatile("s_nop 7\n\ts_nop 7" ::);
  float bv = bias[cog];
  int co = cog & 255;
  int h = co >> 5, d = co & 31;
#pragma unroll
  for (int r = 0; r < 4; ++r) {
    int j = j0 + (l >> 4) * 4 + r;
    short v = (short)f2bf(acc[r] + bv);
    if (third == 0)      Qb[((size_t)h * 2048 + j) * 32 + d] = v;
    else if (third == 1) Kb[((size_t)h * 2048 + j) * 32 + d] = v;
    else                 Vt[((size_t)h * 32 + d) * 2048 + j] = v;
  }
}

// fused flash attention. grid (32 qtiles, 8 h), 4 waves. Writes bf16 Ob.
__global__ __launch_bounds__(256) void k_fattn(const short* __restrict__ Qb,
                                               const short* __restrict__ Kb,
                                               const short* __restrict__ Vt,
                                               short* __restrict__ Ob) {
  __shared__ short P_lds[4][16][136];
  int t = threadIdx.x, l = t & 63, wv = t >> 6;
  int h = blockIdx.y;
  int q0 = blockIdx.x * 64 + wv * 16;
  const short* Qh = Qb + (size_t)h * 2048 * 32;
  const short* Kh = Kb + (size_t)h * 2048 * 32;
  const short* Vh = Vt + (size_t)h * 32 * 2048;
  short8 a_q = *(const short8*)&Qh[(size_t)(q0 + (l & 15)) * 32 + (l >> 4) * 8];
  f32x4 o0 = {0.f, 0.f, 0.f, 0.f}, o1 = {0.f, 0.f, 0.f, 0.f};
  float m_run[4], l_run[4];
#pragma unroll
  for (int r = 0; r < 4; ++r) { m_run[r] = -3e38f; l_run[r] = 0.f; }
  const float scale = 0.17677669529663687f;
  for (int k0 = 0; k0 < 2048; k0 += 128) {
    f32x4 s[8];
#pragma unroll
    for (int kt = 0; kt < 8; ++kt) {
      f32x4 z = {0.f, 0.f, 0.f, 0.f};
      s[kt] = z;
      short8 b = *(const short8*)&Kh[(size_t)(k0 + kt * 16 + (l & 15)) * 32 + (l >> 4) * 8];
      mfma_bf16(s[kt], a_q, b);
    }
    asm volatile("s_nop 7\n\ts_nop 7" ::);
    float tm[4];
#pragma unroll
    for (int r = 0; r < 4; ++r) {
      float mx = s[0][r];
#pragma unroll
      for (int kt = 1; kt < 8; ++kt) mx = fmaxf(mx, s[kt][r]);
      tm[r] = mx * scale;
    }
#pragma unroll
    for (int mask = 1; mask < 16; mask <<= 1)
#pragma unroll
      for (int r = 0; r < 4; ++r) tm[r] = fmaxf(tm[r], __shfl_xor(tm[r], mask));
    float mn[4], al[4], rs[4];
#pragma unroll
    for (int r = 0; r < 4; ++r) {
      mn[r] = fmaxf(m_run[r], tm[r]);
      al[r] = __expf(m_run[r] - mn[r]);
      rs[r] = 0.f;
    }
#pragma unroll
    for (int kt = 0; kt < 8; ++kt)
#pragma unroll
      for (int r = 0; r < 4; ++r) {
        float pv = __expf(s[kt][r] * scale - mn[r]);
        s[kt][r] = pv;
        rs[r] += pv;
      }
#pragma unroll
    for (int mask = 1; mask < 16; mask <<= 1)
#pragma unroll
      for (int r = 0; r < 4; ++r) rs[r] += __shfl_xor(rs[r], mask);
#pragma unroll
    for (int r = 0; r < 4; ++r) {
      l_run[r] = l_run[r] * al[r] + rs[r];
      m_run[r] = mn[r];
      o0[r] *= al[r];
      o1[r] *= al[r];
    }
#pragma unroll
    for (int kt = 0; kt < 8; ++kt)
#pragma unroll
      for (int r = 0; r < 4; ++r)
        P_lds[wv][(l >> 4) * 4 + r][kt * 16 + (l & 15)] = (short)f2bf(s[kt][r]);
#pragma unroll
    for (int kc = 0; kc < 4; ++kc) {
      short8 ap = *(const short8*)&P_lds[wv][l & 15][kc * 32 + (l >> 4) * 8];
      short8 b0 = *(const short8*)&Vh[(size_t)(l & 15) * 2048 + k0 + kc * 32 + (l >> 4) * 8];
      short8 b1 = *(const short8*)&Vh[(size_t)(16 + (l & 15)) * 2048 + k0 + kc * 32 + (l >> 4) * 8];
      mfma_bf16(o0, ap, b0);
      mfma_bf16(o1, ap, b1);
    }
  }
  asm volatile("s_nop 7\n\ts_nop 7" ::);
#pragma unroll
  for (int r = 0; r < 4; ++r) {
    float inv = 1.f / l_run[r];
    int qr = q0 + (l >> 4) * 4 + r;
    Ob[(size_t)qr * 256 + h * 32 + (l & 15)] = (short)f2bf(o0[r] * inv);
    Ob[(size_t)qr * 256 + h * 32 + 16 + (l & 15)] = (short)f2bf(o1[r] * inv);
  }
}

// MFMA out-projection + scatter. grid (128 j-tiles, 4 co-tiles of 64).
__global__ __launch_bounds__(256) void k_outprojM(const short* __restrict__ Ob,
                                                  const short* __restrict__ wBo,
                                                  const float* __restrict__ ob,
                                                  const int* __restrict__ idx,
                                                  float* __restrict__ out) {
  __shared__ short a_s[16 * 264];
  __shared__ int jp[16];
  unsigned* a_s32 = (unsigned*)a_s;
  const unsigned* s32 = (const unsigned*)Ob;
  int t = threadIdx.x, l = t & 63, wv = t >> 6;
  int j0 = blockIdx.x * 16;
  if (t < 16) jp[t] = idx[j0 + t];
  for (int i = t; i < 2048; i += 256) {
    int row = i >> 7, c2 = i & 127;
    a_s32[row * 132 + c2] = s32[(size_t)(j0 + row) * 128 + c2];
  }
  __syncthreads();
  int co = blockIdx.y * 64 + wv * 16 + (l & 15);
  f32x4 acc = {0.f, 0.f, 0.f, 0.f};
  const short* brow = wBo + (size_t)co * 256 + (l >> 4) * 8;
  const short* arow = a_s + (l & 15) * 264 + (l >> 4) * 8;
#pragma unroll
  for (int kc = 0; kc < 8; ++kc) {
    short8 a = *(const short8*)(arow + kc * 32);
    short8 b = *(const short8*)(brow + kc * 32);
    mfma_bf16(acc, a, b);
  }
  asm volatile("s_nop 7\n\ts_nop 7" ::);
  float bv = ob[co];
#pragma unroll
  for (int r = 0; r < 4; ++r) {
    int jl = (l >> 4) * 4 + r;
    out[(size_t)co * HWP + jp[jl]] = acc[r] + bv;
  }
}

extern "C" void kernel_launch(void* const* d_in, const int* in_sizes, int n_in,
                              void* d_out, int out_size, void* d_ws, size_t ws_size,
                              hipStream_t stream) {
  const float* down  = (const float*)d_in[0];
  const float* swint = (const float*)d_in[1];
  const float* wt_w  = (const float*)d_in[2];
  const float* wt_b  = (const float*)d_in[3];
  const float* up_dw = (const float*)d_in[4];
  const float* up_db = (const float*)d_in[5];
  const float* up_cw = (const float*)d_in[6];
  const float* up_cb = (const float*)d_in[7];
  const float* gate_w = (const float*)d_in[8];
  const float* in_w  = (const float*)d_in[10];
  const float* in_b  = (const float*)d_in[11];
  const float* out_w = (const float*)d_in[12];
  const float* out_b = (const float*)d_in[13];
  float* out = (float*)d_out;
  char* ws = (char*)d_ws;

  unsigned* actA = (unsigned*)ws;
  unsigned* actB = (unsigned*)(ws + BUF_B_OFF);
  unsigned int* keys = (unsigned int*)(ws + KEYS_OFF);
  unsigned int* hist = (unsigned int*)(ws + HIST_OFF);
  int* idx = (int*)(ws + IDX_OFF);
  int* eq = (int*)(ws + EQ_OFF);
  short* Ob = (short*)(ws + OB_OFF);
  short* wBi = (short*)(ws + WBI_OFF);
  short* wBo = (short*)(ws + WBO_OFF);
  short* srowsb = (short*)(ws + SROWS_OFF);
  short* dq = (short*)(ws + DQ_OFF);
  float* gpart = (float*)(ws + GPART_OFF);
  short* wB5 = (short*)(ws + WT5_OFF);
  short* Qb = (short*)(ws + QB_OFF);
  short* Kb = (short*)(ws + KB_OFF);
  short* Vt = (short*)(ws + VT_OFF);
  short* cpk = (short*)(ws + CPK_OFF);
  short* dpk = (short*)(ws + DPK_OFF);
  short* wBt = (short*)(ws + WTW_OFF);
  float* wpart = (float*)(ws + WPART_OFF);
  short* xq0 = (short*)(ws + XQ0_OFF);

  // gate partials + copy (zeroes hist), keys + fused r0 hist, 1-block select, gather
  k_gatecopy2<<<dim3(256, 8), 256, 0, stream>>>(down, gate_w, out, gpart, hist);
  k_gkey<<<256, 256, 0, stream>>>(gpart, keys, hist);
  k_select2<<<1, 1024, 0, stream>>>(keys, hist, idx, eq);
  k_gatherq<<<2048, 256, 0, stream>>>(down, idx, dq);

  // all weight packs in one launch (conv3 x4, deconv x5, conv5, in_w, out_w, wt_w)
  k_packall<<<3840, 256, 0, stream>>>(up_cw, up_dw, in_w, out_w, wt_w,
                                      cpk, dpk, wB5, wBi, wBo, wBt);

  // stage 0: K-split MFMA 1x1 conv (parallel weight fetch) + reduce, then deconv 8->16
  k_wtconvP<<<dim3(4, 8), 256, 0, stream>>>(swint, wBt, wpart);
  k_wtred<<<64, 256, 0, stream>>>(wpart, wt_b, xq0);
  k_deconv8M<<<dim3(4, 4), 256, 0, stream>>>(xq0, dpk, up_db, actB);

  // upsampler chain: MFMA bf16 implicit-GEMM, packed-bf16 activations (A/B ping-pong)
  k_conv3u<16, 2><<<dim3(8, 4), 256, 0, stream>>>(actB, cpk, up_cb, actA);
  k_deconvu<16, 2><<<dim3(8, 4, 2), 256, 0, stream>>>(actA, dpk + 1048576, up_db + 256, actB);
  k_conv3u<32, 2><<<dim3(16, 4), 256, 0, stream>>>(actB, cpk + 589824, up_cb + 256, actA);
  k_deconvu<32, 2><<<dim3(16, 4, 2), 256, 0, stream>>>(actA, dpk + 2 * 1048576, up_db + 512, actB);
  k_conv3v64<<<dim3(64, 4), 512, 0, stream>>>(actB, cpk + 2 * 589824, up_cb + 512, actA);
  k_deconvw64<<<dim3(64, 4, 2), 512, 0, stream>>>(actA, dpk + 3 * 1048576, up_db + 768, actB);
  k_conv3v<<<dim3(128, 4), 512, 0, stream>>>(actB, cpk + 3 * 589824, up_cb + 768, actA);
  k_deconvw<<<dim3(64, 4, 2), 512, 0, stream>>>(actA, dpk + 4 * 1048576, up_db + 1024, actB);

  // final conv3 via MFMA at the 2048 gathered positions -> bf16 srows
  k_conv3sM<<<dim3(128, 2), 256, 0, stream>>>(actB, wB5, up_cb + 1024, idx, srowsb);

  // attention path: MFMA in-projection, fused flash attention, MFMA out-projection
  k_qkv3<<<dim3(128, 12), 256, 0, stream>>>(dq, srowsb, wBi, in_b, Qb, Kb, Vt);
  k_fattn<<<dim3(32, 8), 256, 0, stream>>>(Qb, Kb, Vt, Ob);
  k_outprojM<<<dim3(128, 4), 256, 0, stream>>>(Ob, wBo, out_b, idx, out);
}